// Round 2
// baseline (639.906 us; speedup 1.0000x reference)
//
#include <hip/hip_runtime.h>
#include <math.h>

#define N_NODES 50000
#define N_EDGES 800000
#define IN_DIM  256
#define F1      128   // HEADS*HID
#define HEADS   4
#define OUT_DIM 40
#define NEG     0.2f

// ---------------- CSR build (by destination) ----------------
__global__ void hist_kernel(const int* __restrict__ ei, int* __restrict__ cnt) {
  int i = blockIdx.x * blockDim.x + threadIdx.x;
  if (i < N_EDGES) atomicAdd(&cnt[ei[N_EDGES + i]], 1);
}

// serial-per-thread + single LDS scan of the 1024 partials
__global__ __launch_bounds__(1024) void scan_kernel(const int* __restrict__ cnt,
                                                    int* __restrict__ row_ptr,
                                                    int* __restrict__ cursor) {
  __shared__ int lds[1024];
  int tid = threadIdx.x;
  const int PER = (N_NODES + 1023) / 1024;  // 49
  int base = tid * PER;
  int sum = 0;
  for (int j = 0; j < PER; j++) {
    int i = base + j;
    if (i < N_NODES) sum += cnt[i];
  }
  lds[tid] = sum;
  __syncthreads();
  for (int off = 1; off < 1024; off <<= 1) {
    int t = (tid >= off) ? lds[tid - off] : 0;
    __syncthreads();
    lds[tid] += t;
    __syncthreads();
  }
  int run = lds[tid] - sum;  // exclusive prefix for this thread's span
  for (int j = 0; j < PER; j++) {
    int i = base + j;
    if (i < N_NODES) {
      row_ptr[i] = run;
      cursor[i] = run;
      run += cnt[i];
    }
  }
  if (tid == 1023) row_ptr[N_NODES] = lds[1023];
}

__global__ void scatter_kernel(const int* __restrict__ ei, int* __restrict__ cursor,
                               int* __restrict__ col, int* __restrict__ dstc) {
  int i = blockIdx.x * blockDim.x + threadIdx.x;
  if (i < N_EDGES) {
    int d = ei[N_EDGES + i];
    int p = atomicAdd(&cursor[d], 1);
    col[p] = ei[i];
    dstc[p] = d;
  }
}

// ---------------- GEMM1: h1 = x @ W1  [50000,256]x[256,128] ----------------
#define BM 64
#define BN 64
#define BK 32

__global__ __launch_bounds__(256) void gemm1_kernel(
    const float* __restrict__ A, const float* __restrict__ B, float* __restrict__ C) {
  __shared__ float As[BK][BM + 4];
  __shared__ float Bs[BK][BN + 4];
  int tid = threadIdx.x;
  int bm = blockIdx.x * BM;
  int bn = blockIdx.y * BN;
  int tx = tid & 15;
  int ty = tid >> 4;
  float acc[4][4] = {{0.f}};
  for (int k0 = 0; k0 < IN_DIM; k0 += BK) {
#pragma unroll
    for (int l = 0; l < 2; l++) {
      int idx = tid + l * 256;
      int r = idx >> 3;
      int c4 = (idx & 7) << 2;
      int grow = bm + r;
      float4 v = make_float4(0.f, 0.f, 0.f, 0.f);
      if (grow < N_NODES) v = *(const float4*)&A[(size_t)grow * IN_DIM + k0 + c4];
      As[c4 + 0][r] = v.x;
      As[c4 + 1][r] = v.y;
      As[c4 + 2][r] = v.z;
      As[c4 + 3][r] = v.w;
    }
#pragma unroll
    for (int l = 0; l < 2; l++) {
      int idx = tid + l * 256;
      int r = idx >> 4;
      int c4 = (idx & 15) << 2;
      *(float4*)&Bs[r][c4] = *(const float4*)&B[(size_t)(k0 + r) * F1 + bn + c4];
    }
    __syncthreads();
#pragma unroll
    for (int kk = 0; kk < BK; kk++) {
      float a[4], b[4];
      *(float4*)a = *(const float4*)&As[kk][ty * 4];
      *(float4*)b = *(const float4*)&Bs[kk][tx * 4];
#pragma unroll
      for (int i = 0; i < 4; i++)
#pragma unroll
        for (int j = 0; j < 4; j++)
          acc[i][j] += a[i] * b[j];
    }
    __syncthreads();
  }
#pragma unroll
  for (int i = 0; i < 4; i++) {
    int grow = bm + ty * 4 + i;
    if (grow < N_NODES) {
      float4 v = make_float4(acc[i][0], acc[i][1], acc[i][2], acc[i][3]);
      *(float4*)&C[(size_t)grow * F1 + bn + tx * 4] = v;
    }
  }
}

// ---------------- alpha1: per-(node,head) dot products ----------------
__global__ __launch_bounds__(256) void alpha1_kernel(
    const float* __restrict__ h1, const float* __restrict__ a_src,
    const float* __restrict__ a_dst, float* __restrict__ as1, float* __restrict__ ad1) {
  int t = blockIdx.x * blockDim.x + threadIdx.x;   // t = n*HEADS + h
  if (t >= N_NODES * HEADS) return;
  int h = t & (HEADS - 1);
  const float4* hp = (const float4*)(h1 + (size_t)t * 32);
  const float4* ap = (const float4*)(a_src + h * 32);
  const float4* dp = (const float4*)(a_dst + h * 32);
  float sa = 0.f, sd = 0.f;
#pragma unroll
  for (int j = 0; j < 8; j++) {
    float4 v = hp[j], a = ap[j], d = dp[j];
    sa += v.x * a.x + v.y * a.y + v.z * a.z + v.w * a.w;
    sd += v.x * d.x + v.y * d.y + v.z * d.z + v.w * d.w;
  }
  as1[t] = sa;
  ad1[t] = sd;
}

__device__ __forceinline__ void online_upd(float& m, float& s, float e) {
  float mn = fmaxf(m, e);
  s = s * __expf(m - mn) + __expf(e - mn);
  m = mn;
}
__device__ __forceinline__ float lrelu(float e) { return e > 0.f ? e : e * NEG; }

// ---------------- layer-1 softmax stats (wave per node) ----------------
__global__ __launch_bounds__(64) void ms1_kernel(
    const float* __restrict__ as1, const float* __restrict__ ad1,
    const int* __restrict__ row_ptr, const int* __restrict__ col,
    float* __restrict__ m1v, float* __restrict__ rs1v, float* __restrict__ wself1) {
  int n = blockIdx.x;
  int lane = threadIdx.x;
  int start = row_ptr[n];
  int deg = row_ptr[n + 1] - start;
  float4 ad = *(const float4*)&ad1[n * 4];
  float m[4] = {-1e30f, -1e30f, -1e30f, -1e30f};
  float s[4] = {0.f, 0.f, 0.f, 0.f};
  for (int i = lane; i < deg + 1; i += 64) {
    int src = (i < deg) ? col[start + i] : n;
    float4 as = *(const float4*)&as1[src * 4];
    online_upd(m[0], s[0], lrelu(as.x + ad.x));
    online_upd(m[1], s[1], lrelu(as.y + ad.y));
    online_upd(m[2], s[2], lrelu(as.z + ad.z));
    online_upd(m[3], s[3], lrelu(as.w + ad.w));
  }
#pragma unroll
  for (int off = 32; off > 0; off >>= 1) {
#pragma unroll
    for (int h = 0; h < 4; h++) {
      float m2 = __shfl_xor(m[h], off);
      float s2 = __shfl_xor(s[h], off);
      float mn = fmaxf(m[h], m2);
      s[h] = s[h] * __expf(m[h] - mn) + s2 * __expf(m2 - mn);
      m[h] = mn;
    }
  }
  if (lane == 0) {
    float4 as = *(const float4*)&as1[n * 4];
    float es[4] = {lrelu(as.x + ad.x), lrelu(as.y + ad.y), lrelu(as.z + ad.z), lrelu(as.w + ad.w)};
    float4 mv, rv, wv;
    float rs0 = 1.f / (s[0] + 1e-16f), rs1 = 1.f / (s[1] + 1e-16f);
    float rs2 = 1.f / (s[2] + 1e-16f), rs3 = 1.f / (s[3] + 1e-16f);
    mv = make_float4(m[0], m[1], m[2], m[3]);
    rv = make_float4(rs0, rs1, rs2, rs3);
    wv = make_float4(__expf(es[0] - m[0]) * rs0, __expf(es[1] - m[1]) * rs1,
                     __expf(es[2] - m[2]) * rs2, __expf(es[3] - m[3]) * rs3);
    *(float4*)&m1v[n * 4] = mv;
    *(float4*)&rs1v[n * 4] = rv;
    *(float4*)&wself1[n * 4] = wv;
  }
}

// ---------------- layer-1 edge weights (edge-parallel) ----------------
__global__ __launch_bounds__(256) void weight1_kernel(
    const float* __restrict__ as1, const float* __restrict__ ad1,
    const float* __restrict__ m1v, const float* __restrict__ rs1v,
    const int* __restrict__ col, const int* __restrict__ dstc,
    float* __restrict__ w1) {
  int p = blockIdx.x * blockDim.x + threadIdx.x;
  if (p >= N_EDGES) return;
  int src = col[p], dst = dstc[p];
  float4 as = *(const float4*)&as1[src * 4];
  float4 ad = *(const float4*)&ad1[dst * 4];
  float4 m = *(const float4*)&m1v[dst * 4];
  float4 rs = *(const float4*)&rs1v[dst * 4];
  float4 w;
  w.x = __expf(lrelu(as.x + ad.x) - m.x) * rs.x;
  w.y = __expf(lrelu(as.y + ad.y) - m.y) * rs.y;
  w.z = __expf(lrelu(as.z + ad.z) - m.z) * rs.z;
  w.w = __expf(lrelu(as.w + ad.w) - m.w) * rs.w;
  *(float4*)&w1[(size_t)p * 4] = w;
}

// ---------------- layer-1 gather (8 edge-groups x 32 lanes) ----------------
__global__ __launch_bounds__(256) void gather1_kernel(
    const float* __restrict__ h1, const float* __restrict__ w1,
    const float* __restrict__ wself1, const float* __restrict__ b1,
    const int* __restrict__ row_ptr, const int* __restrict__ col,
    float* __restrict__ x2) {
  int n = blockIdx.x;
  int tid = threadIdx.x;
  int g = tid >> 5;
  int lane = tid & 31;
  int start = row_ptr[n];
  int deg = row_ptr[n + 1] - start;
  int head = lane >> 3;       // channel block lane*4.. sits in head lane>>3
  float4 acc = make_float4(0.f, 0.f, 0.f, 0.f);
  for (int i = g; i < deg; i += 8) {
    int src = col[start + i];
    float w = w1[(size_t)(start + i) * 4 + head];
    float4 h = *(const float4*)&h1[(size_t)src * F1 + lane * 4];
    acc.x += w * h.x; acc.y += w * h.y; acc.z += w * h.z; acc.w += w * h.w;
  }
  if (g == (deg & 7)) {   // self-loop
    float w = wself1[n * 4 + head];
    float4 h = *(const float4*)&h1[(size_t)n * F1 + lane * 4];
    acc.x += w * h.x; acc.y += w * h.y; acc.z += w * h.z; acc.w += w * h.w;
  }
  __shared__ float4 red[8][32];
  red[g][lane] = acc;
  __syncthreads();
  if (tid < 32) {
    float4 t = red[0][tid];
#pragma unroll
    for (int gg = 1; gg < 8; gg++) {
      float4 r = red[gg][tid];
      t.x += r.x; t.y += r.y; t.z += r.z; t.w += r.w;
    }
    float4 bb = *(const float4*)&b1[tid * 4];
    t.x = fmaxf(t.x + bb.x, 0.f);
    t.y = fmaxf(t.y + bb.y, 0.f);
    t.z = fmaxf(t.z + bb.z, 0.f);
    t.w = fmaxf(t.w + bb.w, 0.f);
    *(float4*)&x2[(size_t)n * F1 + tid * 4] = t;
  }
}

// ---------------- GEMM2 + alpha2 fused (wave per row) ----------------
__global__ __launch_bounds__(64) void gemm2_kernel(
    const float* __restrict__ x2, const float* __restrict__ W2,
    const float* __restrict__ asv, const float* __restrict__ adv,
    float* __restrict__ h2, float* __restrict__ as2, float* __restrict__ ad2) {
  int n = blockIdx.x;
  int tid = threadIdx.x;
  __shared__ float xs[F1];
  xs[tid] = x2[(size_t)n * F1 + tid];
  xs[tid + 64] = x2[(size_t)n * F1 + 64 + tid];
  __syncthreads();
  float acc = 0.f;
  if (tid < OUT_DIM) {
#pragma unroll 8
    for (int k = 0; k < F1; k++) acc += xs[k] * W2[k * OUT_DIM + tid];
  }
  float pa = (tid < OUT_DIM) ? acc * asv[tid] : 0.f;
  float pd = (tid < OUT_DIM) ? acc * adv[tid] : 0.f;
#pragma unroll
  for (int off = 32; off > 0; off >>= 1) {
    pa += __shfl_xor(pa, off);
    pd += __shfl_xor(pd, off);
  }
  if (tid < OUT_DIM) h2[(size_t)n * OUT_DIM + tid] = acc;
  if (tid == 0) { as2[n] = pa; ad2[n] = pd; }
}

// ---------------- layer-2 softmax stats (wave per node) ----------------
__global__ __launch_bounds__(64) void ms2_kernel(
    const float* __restrict__ as2, const float* __restrict__ ad2,
    const int* __restrict__ row_ptr, const int* __restrict__ col,
    float* __restrict__ m2v, float* __restrict__ rs2v, float* __restrict__ wself2) {
  int n = blockIdx.x;
  int lane = threadIdx.x;
  int start = row_ptr[n];
  int deg = row_ptr[n + 1] - start;
  float ad = ad2[n];
  float m = -1e30f, s = 0.f;
  for (int i = lane; i < deg + 1; i += 64) {
    int src = (i < deg) ? col[start + i] : n;
    online_upd(m, s, lrelu(as2[src] + ad));
  }
#pragma unroll
  for (int off = 32; off > 0; off >>= 1) {
    float m2 = __shfl_xor(m, off);
    float s2 = __shfl_xor(s, off);
    float mn = fmaxf(m, m2);
    s = s * __expf(m - mn) + s2 * __expf(m2 - mn);
    m = mn;
  }
  if (lane == 0) {
    float rs = 1.f / (s + 1e-16f);
    m2v[n] = m;
    rs2v[n] = rs;
    wself2[n] = __expf(lrelu(as2[n] + ad) - m) * rs;
  }
}

__global__ __launch_bounds__(256) void weight2_kernel(
    const float* __restrict__ as2, const float* __restrict__ ad2,
    const float* __restrict__ m2v, const float* __restrict__ rs2v,
    const int* __restrict__ col, const int* __restrict__ dstc,
    float* __restrict__ w2e) {
  int p = blockIdx.x * blockDim.x + threadIdx.x;
  if (p >= N_EDGES) return;
  int src = col[p], dst = dstc[p];
  w2e[p] = __expf(lrelu(as2[src] + ad2[dst]) - m2v[dst]) * rs2v[dst];
}

// ---------------- layer-2 gather + log_softmax (4 edge-groups x 64 lanes) ----------------
__global__ __launch_bounds__(256) void gather2_kernel(
    const float* __restrict__ h2, const float* __restrict__ w2e,
    const float* __restrict__ wself2, const float* __restrict__ b2,
    const int* __restrict__ row_ptr, const int* __restrict__ col,
    float* __restrict__ out) {
  int n = blockIdx.x;
  int tid = threadIdx.x;
  int g = tid >> 6;
  int lane = tid & 63;
  int start = row_ptr[n];
  int deg = row_ptr[n + 1] - start;
  float acc = 0.f;
  for (int i = g; i < deg; i += 4) {
    int src = col[start + i];
    float w = w2e[start + i];
    if (lane < OUT_DIM) acc += w * h2[(size_t)src * OUT_DIM + lane];
  }
  if (g == (deg & 3)) {
    float w = wself2[n];
    if (lane < OUT_DIM) acc += w * h2[(size_t)n * OUT_DIM + lane];
  }
  __shared__ float red[4][64];
  red[g][lane] = acc;
  __syncthreads();
  if (tid < 64) {
    float val = red[0][tid] + red[1][tid] + red[2][tid] + red[3][tid];
    val = (tid < OUT_DIM) ? (val + b2[tid]) : -1e30f;
    float mx = val;
#pragma unroll
    for (int off = 32; off > 0; off >>= 1) mx = fmaxf(mx, __shfl_xor(mx, off));
    float ex = (tid < OUT_DIM) ? __expf(val - mx) : 0.f;
    float sum = ex;
#pragma unroll
    for (int off = 32; off > 0; off >>= 1) sum += __shfl_xor(sum, off);
    if (tid < OUT_DIM) out[(size_t)n * OUT_DIM + tid] = val - mx - __logf(sum);
  }
}

extern "C" void kernel_launch(void* const* d_in, const int* in_sizes, int n_in,
                              void* d_out, int out_size, void* d_ws, size_t ws_size,
                              hipStream_t stream) {
  const float* x      = (const float*)d_in[0];
  const int*   ei     = (const int*)d_in[1];
  const float* W1     = (const float*)d_in[2];
  const float* a_src1 = (const float*)d_in[3];
  const float* a_dst1 = (const float*)d_in[4];
  const float* b1     = (const float*)d_in[5];
  const float* W2     = (const float*)d_in[6];
  const float* a_src2 = (const float*)d_in[7];
  const float* a_dst2 = (const float*)d_in[8];
  const float* b2     = (const float*)d_in[9];
  float* out = (float*)d_out;

  char* ws = (char*)d_ws;
  size_t off = 0;
  auto alloc = [&](size_t bytes) -> void* {
    void* p = ws + off;
    off += (bytes + 255) & ~(size_t)255;
    return p;
  };
  float* h1     = (float*)alloc((size_t)N_NODES * F1 * 4);
  float* as1    = (float*)alloc((size_t)N_NODES * HEADS * 4);
  float* ad1    = (float*)alloc((size_t)N_NODES * HEADS * 4);
  float* x2     = (float*)alloc((size_t)N_NODES * F1 * 4);
  float* h2     = (float*)alloc((size_t)N_NODES * OUT_DIM * 4);
  float* as2    = (float*)alloc((size_t)N_NODES * 4);
  float* ad2    = (float*)alloc((size_t)N_NODES * 4);
  float* m1v    = (float*)alloc((size_t)N_NODES * HEADS * 4);
  float* rs1v   = (float*)alloc((size_t)N_NODES * HEADS * 4);
  float* wself1 = (float*)alloc((size_t)N_NODES * HEADS * 4);
  float* m2v    = (float*)alloc((size_t)N_NODES * 4);
  float* rs2v   = (float*)alloc((size_t)N_NODES * 4);
  float* wself2 = (float*)alloc((size_t)N_NODES * 4);
  float* w1     = (float*)alloc((size_t)N_EDGES * HEADS * 4);  // 12.8 MB
  float* w2e    = (float*)alloc((size_t)N_EDGES * 4);
  int* row_ptr  = (int*)alloc((size_t)(N_NODES + 1) * 4);
  int* cursor   = (int*)alloc((size_t)N_NODES * 4);
  int* cnt      = (int*)alloc((size_t)N_NODES * 4);
  int* col      = (int*)alloc((size_t)N_EDGES * 4);
  int* dstc     = (int*)alloc((size_t)N_EDGES * 4);

  hipMemsetAsync(cnt, 0, (size_t)N_NODES * 4, stream);
  hist_kernel<<<(N_EDGES + 255) / 256, 256, 0, stream>>>(ei, cnt);
  scan_kernel<<<1, 1024, 0, stream>>>(cnt, row_ptr, cursor);
  scatter_kernel<<<(N_EDGES + 255) / 256, 256, 0, stream>>>(ei, cursor, col, dstc);

  gemm1_kernel<<<dim3((N_NODES + BM - 1) / BM, F1 / BN), 256, 0, stream>>>(x, W1, h1);
  alpha1_kernel<<<(N_NODES * HEADS + 255) / 256, 256, 0, stream>>>(h1, a_src1, a_dst1, as1, ad1);
  ms1_kernel<<<N_NODES, 64, 0, stream>>>(as1, ad1, row_ptr, col, m1v, rs1v, wself1);
  weight1_kernel<<<(N_EDGES + 255) / 256, 256, 0, stream>>>(as1, ad1, m1v, rs1v, col, dstc, w1);
  gather1_kernel<<<N_NODES, 256, 0, stream>>>(h1, w1, wself1, b1, row_ptr, col, x2);

  gemm2_kernel<<<N_NODES, 64, 0, stream>>>(x2, W2, a_src2, a_dst2, h2, as2, ad2);
  ms2_kernel<<<N_NODES, 64, 0, stream>>>(as2, ad2, row_ptr, col, m2v, rs2v, wself2);
  weight2_kernel<<<(N_EDGES + 255) / 256, 256, 0, stream>>>(as2, ad2, m2v, rs2v, col, dstc, w2e);
  gather2_kernel<<<N_NODES, 256, 0, stream>>>(h2, w2e, wself2, b2, row_ptr, col, out);
}

// Round 3
// 517.965 us; speedup vs baseline: 1.2354x; 1.2354x over previous
//
#include <hip/hip_runtime.h>
#include <math.h>

#define N_NODES 50000
#define N_EDGES 800000
#define IN_DIM  256
#define F1      128   // HEADS*HID
#define HEADS   4
#define OUT_DIM 40
#define NEG     0.2f

#define SCAN_CHUNK 256
#define SCAN_NBLK  ((N_NODES + SCAN_CHUNK - 1) / SCAN_CHUNK)   // 196

// ---------------- CSR build (by destination) ----------------
__global__ void hist_kernel(const int* __restrict__ ei, int* __restrict__ cnt) {
  int i = blockIdx.x * blockDim.x + threadIdx.x;
  if (i < N_EDGES) atomicAdd(&cnt[ei[N_EDGES + i]], 1);
}

// Phase 1: per-block sums of cnt
__global__ __launch_bounds__(256) void blksum_kernel(const int* __restrict__ cnt,
                                                     int* __restrict__ blk_sum) {
  __shared__ int lds[256];
  int b = blockIdx.x;
  int tid = threadIdx.x;
  int i = b * SCAN_CHUNK + tid;
  lds[tid] = (i < N_NODES) ? cnt[i] : 0;
  __syncthreads();
#pragma unroll
  for (int off = 128; off > 0; off >>= 1) {
    if (tid < off) lds[tid] += lds[tid + off];
    __syncthreads();
  }
  if (tid == 0) blk_sum[b] = lds[0];
}

// Phase 2: scan the 196 block sums (one block)
__global__ __launch_bounds__(256) void blkscan_kernel(const int* __restrict__ blk_sum,
                                                      int* __restrict__ blk_off,
                                                      int* __restrict__ row_ptr) {
  __shared__ int lds[256];
  int tid = threadIdx.x;
  int v = (tid < SCAN_NBLK) ? blk_sum[tid] : 0;
  lds[tid] = v;
  __syncthreads();
#pragma unroll
  for (int off = 1; off < 256; off <<= 1) {
    int t = (tid >= off) ? lds[tid - off] : 0;
    __syncthreads();
    lds[tid] += t;
    __syncthreads();
  }
  if (tid < SCAN_NBLK) blk_off[tid] = lds[tid] - v;   // exclusive
  if (tid == 255) row_ptr[N_NODES] = lds[255];        // total
}

// Phase 3: per-chunk inclusive scan + block offset -> exclusive row_ptr
__global__ __launch_bounds__(256) void finalscan_kernel(const int* __restrict__ cnt,
                                                        const int* __restrict__ blk_off,
                                                        int* __restrict__ row_ptr,
                                                        int* __restrict__ cursor) {
  __shared__ int lds[256];
  int b = blockIdx.x;
  int tid = threadIdx.x;
  int i = b * SCAN_CHUNK + tid;
  int v = (i < N_NODES) ? cnt[i] : 0;
  lds[tid] = v;
  __syncthreads();
#pragma unroll
  for (int off = 1; off < 256; off <<= 1) {
    int t = (tid >= off) ? lds[tid - off] : 0;
    __syncthreads();
    lds[tid] += t;
    __syncthreads();
  }
  if (i < N_NODES) {
    int excl = lds[tid] - v + blk_off[b];
    row_ptr[i] = excl;
    cursor[i] = excl;
  }
}

__global__ void scatter_kernel(const int* __restrict__ ei, int* __restrict__ cursor,
                               int* __restrict__ col, int* __restrict__ dstc) {
  int i = blockIdx.x * blockDim.x + threadIdx.x;
  if (i < N_EDGES) {
    int d = ei[N_EDGES + i];
    int p = atomicAdd(&cursor[d], 1);
    col[p] = ei[i];
    dstc[p] = d;
  }
}

// ---------------- GEMM1: h1 = x @ W1  [50000,256]x[256,128] ----------------
#define BM 64
#define BN 64
#define BK 32

__global__ __launch_bounds__(256) void gemm1_kernel(
    const float* __restrict__ A, const float* __restrict__ B, float* __restrict__ C) {
  __shared__ float As[BK][BM + 4];
  __shared__ float Bs[BK][BN + 4];
  int tid = threadIdx.x;
  int bm = blockIdx.x * BM;
  int bn = blockIdx.y * BN;
  int tx = tid & 15;
  int ty = tid >> 4;
  float acc[4][4] = {{0.f}};
  for (int k0 = 0; k0 < IN_DIM; k0 += BK) {
#pragma unroll
    for (int l = 0; l < 2; l++) {
      int idx = tid + l * 256;
      int r = idx >> 3;
      int c4 = (idx & 7) << 2;
      int grow = bm + r;
      float4 v = make_float4(0.f, 0.f, 0.f, 0.f);
      if (grow < N_NODES) v = *(const float4*)&A[(size_t)grow * IN_DIM + k0 + c4];
      As[c4 + 0][r] = v.x;
      As[c4 + 1][r] = v.y;
      As[c4 + 2][r] = v.z;
      As[c4 + 3][r] = v.w;
    }
#pragma unroll
    for (int l = 0; l < 2; l++) {
      int idx = tid + l * 256;
      int r = idx >> 4;
      int c4 = (idx & 15) << 2;
      *(float4*)&Bs[r][c4] = *(const float4*)&B[(size_t)(k0 + r) * F1 + bn + c4];
    }
    __syncthreads();
#pragma unroll
    for (int kk = 0; kk < BK; kk++) {
      float a[4], b[4];
      *(float4*)a = *(const float4*)&As[kk][ty * 4];
      *(float4*)b = *(const float4*)&Bs[kk][tx * 4];
#pragma unroll
      for (int i = 0; i < 4; i++)
#pragma unroll
        for (int j = 0; j < 4; j++)
          acc[i][j] += a[i] * b[j];
    }
    __syncthreads();
  }
#pragma unroll
  for (int i = 0; i < 4; i++) {
    int grow = bm + ty * 4 + i;
    if (grow < N_NODES) {
      float4 v = make_float4(acc[i][0], acc[i][1], acc[i][2], acc[i][3]);
      *(float4*)&C[(size_t)grow * F1 + bn + tx * 4] = v;
    }
  }
}

// ---------------- alpha1: per-(node,head) dot products ----------------
__global__ __launch_bounds__(256) void alpha1_kernel(
    const float* __restrict__ h1, const float* __restrict__ a_src,
    const float* __restrict__ a_dst, float* __restrict__ as1, float* __restrict__ ad1) {
  int t = blockIdx.x * blockDim.x + threadIdx.x;   // t = n*HEADS + h
  if (t >= N_NODES * HEADS) return;
  int h = t & (HEADS - 1);
  const float4* hp = (const float4*)(h1 + (size_t)t * 32);
  const float4* ap = (const float4*)(a_src + h * 32);
  const float4* dp = (const float4*)(a_dst + h * 32);
  float sa = 0.f, sd = 0.f;
#pragma unroll
  for (int j = 0; j < 8; j++) {
    float4 v = hp[j], a = ap[j], d = dp[j];
    sa += v.x * a.x + v.y * a.y + v.z * a.z + v.w * a.w;
    sd += v.x * d.x + v.y * d.y + v.z * d.z + v.w * d.w;
  }
  as1[t] = sa;
  ad1[t] = sd;
}

__device__ __forceinline__ void online_upd(float& m, float& s, float e) {
  float mn = fmaxf(m, e);
  s = s * __expf(m - mn) + __expf(e - mn);
  m = mn;
}
__device__ __forceinline__ float lrelu(float e) { return e > 0.f ? e : e * NEG; }

// ---------------- layer-1 softmax stats (wave per node) ----------------
__global__ __launch_bounds__(64) void ms1_kernel(
    const float* __restrict__ as1, const float* __restrict__ ad1,
    const int* __restrict__ row_ptr, const int* __restrict__ col,
    float* __restrict__ m1v, float* __restrict__ rs1v, float* __restrict__ wself1) {
  int n = blockIdx.x;
  int lane = threadIdx.x;
  int start = row_ptr[n];
  int deg = row_ptr[n + 1] - start;
  float4 ad = *(const float4*)&ad1[n * 4];
  float m[4] = {-1e30f, -1e30f, -1e30f, -1e30f};
  float s[4] = {0.f, 0.f, 0.f, 0.f};
  for (int i = lane; i < deg + 1; i += 64) {
    int src = (i < deg) ? col[start + i] : n;
    float4 as = *(const float4*)&as1[src * 4];
    online_upd(m[0], s[0], lrelu(as.x + ad.x));
    online_upd(m[1], s[1], lrelu(as.y + ad.y));
    online_upd(m[2], s[2], lrelu(as.z + ad.z));
    online_upd(m[3], s[3], lrelu(as.w + ad.w));
  }
#pragma unroll
  for (int off = 32; off > 0; off >>= 1) {
#pragma unroll
    for (int h = 0; h < 4; h++) {
      float m2 = __shfl_xor(m[h], off);
      float s2 = __shfl_xor(s[h], off);
      float mn = fmaxf(m[h], m2);
      s[h] = s[h] * __expf(m[h] - mn) + s2 * __expf(m2 - mn);
      m[h] = mn;
    }
  }
  if (lane == 0) {
    float4 as = *(const float4*)&as1[n * 4];
    float es[4] = {lrelu(as.x + ad.x), lrelu(as.y + ad.y), lrelu(as.z + ad.z), lrelu(as.w + ad.w)};
    float rs0 = 1.f / (s[0] + 1e-16f), rs1 = 1.f / (s[1] + 1e-16f);
    float rs2 = 1.f / (s[2] + 1e-16f), rs3 = 1.f / (s[3] + 1e-16f);
    *(float4*)&m1v[n * 4] = make_float4(m[0], m[1], m[2], m[3]);
    *(float4*)&rs1v[n * 4] = make_float4(rs0, rs1, rs2, rs3);
    *(float4*)&wself1[n * 4] =
        make_float4(__expf(es[0] - m[0]) * rs0, __expf(es[1] - m[1]) * rs1,
                    __expf(es[2] - m[2]) * rs2, __expf(es[3] - m[3]) * rs3);
  }
}

// ---------------- layer-1 edge weights (edge-parallel) ----------------
__global__ __launch_bounds__(256) void weight1_kernel(
    const float* __restrict__ as1, const float* __restrict__ ad1,
    const float* __restrict__ m1v, const float* __restrict__ rs1v,
    const int* __restrict__ col, const int* __restrict__ dstc,
    float* __restrict__ w1) {
  int p = blockIdx.x * blockDim.x + threadIdx.x;
  if (p >= N_EDGES) return;
  int src = col[p], dst = dstc[p];
  float4 as = *(const float4*)&as1[src * 4];
  float4 ad = *(const float4*)&ad1[dst * 4];
  float4 m = *(const float4*)&m1v[dst * 4];
  float4 rs = *(const float4*)&rs1v[dst * 4];
  float4 w;
  w.x = __expf(lrelu(as.x + ad.x) - m.x) * rs.x;
  w.y = __expf(lrelu(as.y + ad.y) - m.y) * rs.y;
  w.z = __expf(lrelu(as.z + ad.z) - m.z) * rs.z;
  w.w = __expf(lrelu(as.w + ad.w) - m.w) * rs.w;
  *(float4*)&w1[(size_t)p * 4] = w;
}

// ---------------- layer-1 gather (8 edge-groups x 32 lanes) ----------------
__global__ __launch_bounds__(256) void gather1_kernel(
    const float* __restrict__ h1, const float* __restrict__ w1,
    const float* __restrict__ wself1, const float* __restrict__ b1,
    const int* __restrict__ row_ptr, const int* __restrict__ col,
    float* __restrict__ x2) {
  int n = blockIdx.x;
  int tid = threadIdx.x;
  int g = tid >> 5;
  int lane = tid & 31;
  int start = row_ptr[n];
  int deg = row_ptr[n + 1] - start;
  int head = lane >> 3;
  float4 acc = make_float4(0.f, 0.f, 0.f, 0.f);
  for (int i = g; i < deg; i += 8) {
    int src = col[start + i];
    float w = w1[(size_t)(start + i) * 4 + head];
    float4 h = *(const float4*)&h1[(size_t)src * F1 + lane * 4];
    acc.x += w * h.x; acc.y += w * h.y; acc.z += w * h.z; acc.w += w * h.w;
  }
  if (g == (deg & 7)) {   // self-loop
    float w = wself1[n * 4 + head];
    float4 h = *(const float4*)&h1[(size_t)n * F1 + lane * 4];
    acc.x += w * h.x; acc.y += w * h.y; acc.z += w * h.z; acc.w += w * h.w;
  }
  __shared__ float4 red[8][32];
  red[g][lane] = acc;
  __syncthreads();
  if (tid < 32) {
    float4 t = red[0][tid];
#pragma unroll
    for (int gg = 1; gg < 8; gg++) {
      float4 r = red[gg][tid];
      t.x += r.x; t.y += r.y; t.z += r.z; t.w += r.w;
    }
    float4 bb = *(const float4*)&b1[tid * 4];
    t.x = fmaxf(t.x + bb.x, 0.f);
    t.y = fmaxf(t.y + bb.y, 0.f);
    t.z = fmaxf(t.z + bb.z, 0.f);
    t.w = fmaxf(t.w + bb.w, 0.f);
    *(float4*)&x2[(size_t)n * F1 + tid * 4] = t;
  }
}

// ---------------- GEMM2 + alpha2 fused (wave per row) ----------------
__global__ __launch_bounds__(64) void gemm2_kernel(
    const float* __restrict__ x2, const float* __restrict__ W2,
    const float* __restrict__ asv, const float* __restrict__ adv,
    float* __restrict__ h2, float* __restrict__ as2, float* __restrict__ ad2) {
  int n = blockIdx.x;
  int tid = threadIdx.x;
  __shared__ float xs[F1];
  xs[tid] = x2[(size_t)n * F1 + tid];
  xs[tid + 64] = x2[(size_t)n * F1 + 64 + tid];
  __syncthreads();
  float acc = 0.f;
  if (tid < OUT_DIM) {
#pragma unroll 8
    for (int k = 0; k < F1; k++) acc += xs[k] * W2[k * OUT_DIM + tid];
  }
  float pa = (tid < OUT_DIM) ? acc * asv[tid] : 0.f;
  float pd = (tid < OUT_DIM) ? acc * adv[tid] : 0.f;
#pragma unroll
  for (int off = 32; off > 0; off >>= 1) {
    pa += __shfl_xor(pa, off);
    pd += __shfl_xor(pd, off);
  }
  if (tid < OUT_DIM) h2[(size_t)n * OUT_DIM + tid] = acc;
  if (tid == 0) { as2[n] = pa; ad2[n] = pd; }
}

// ---------------- layer-2 softmax stats (wave per node) ----------------
__global__ __launch_bounds__(64) void ms2_kernel(
    const float* __restrict__ as2, const float* __restrict__ ad2,
    const int* __restrict__ row_ptr, const int* __restrict__ col,
    float* __restrict__ m2v, float* __restrict__ rs2v, float* __restrict__ wself2) {
  int n = blockIdx.x;
  int lane = threadIdx.x;
  int start = row_ptr[n];
  int deg = row_ptr[n + 1] - start;
  float ad = ad2[n];
  float m = -1e30f, s = 0.f;
  for (int i = lane; i < deg + 1; i += 64) {
    int src = (i < deg) ? col[start + i] : n;
    online_upd(m, s, lrelu(as2[src] + ad));
  }
#pragma unroll
  for (int off = 32; off > 0; off >>= 1) {
    float m2 = __shfl_xor(m, off);
    float s2 = __shfl_xor(s, off);
    float mn = fmaxf(m, m2);
    s = s * __expf(m - mn) + s2 * __expf(m2 - mn);
    m = mn;
  }
  if (lane == 0) {
    float rs = 1.f / (s + 1e-16f);
    m2v[n] = m;
    rs2v[n] = rs;
    wself2[n] = __expf(lrelu(as2[n] + ad) - m) * rs;
  }
}

__global__ __launch_bounds__(256) void weight2_kernel(
    const float* __restrict__ as2, const float* __restrict__ ad2,
    const float* __restrict__ m2v, const float* __restrict__ rs2v,
    const int* __restrict__ col, const int* __restrict__ dstc,
    float* __restrict__ w2e) {
  int p = blockIdx.x * blockDim.x + threadIdx.x;
  if (p >= N_EDGES) return;
  int src = col[p], dst = dstc[p];
  w2e[p] = __expf(lrelu(as2[src] + ad2[dst]) - m2v[dst]) * rs2v[dst];
}

// ---------------- layer-2 gather + log_softmax (4 edge-groups x 64 lanes) ----------------
__global__ __launch_bounds__(256) void gather2_kernel(
    const float* __restrict__ h2, const float* __restrict__ w2e,
    const float* __restrict__ wself2, const float* __restrict__ b2,
    const int* __restrict__ row_ptr, const int* __restrict__ col,
    float* __restrict__ out) {
  int n = blockIdx.x;
  int tid = threadIdx.x;
  int g = tid >> 6;
  int lane = tid & 63;
  int start = row_ptr[n];
  int deg = row_ptr[n + 1] - start;
  float acc = 0.f;
  for (int i = g; i < deg; i += 4) {
    int src = col[start + i];
    float w = w2e[start + i];
    if (lane < OUT_DIM) acc += w * h2[(size_t)src * OUT_DIM + lane];
  }
  if (g == (deg & 3)) {
    float w = wself2[n];
    if (lane < OUT_DIM) acc += w * h2[(size_t)n * OUT_DIM + lane];
  }
  __shared__ float red[4][64];
  red[g][lane] = acc;
  __syncthreads();
  if (tid < 64) {
    float val = red[0][tid] + red[1][tid] + red[2][tid] + red[3][tid];
    val = (tid < OUT_DIM) ? (val + b2[tid]) : -1e30f;
    float mx = val;
#pragma unroll
    for (int off = 32; off > 0; off >>= 1) mx = fmaxf(mx, __shfl_xor(mx, off));
    float ex = (tid < OUT_DIM) ? __expf(val - mx) : 0.f;
    float sum = ex;
#pragma unroll
    for (int off = 32; off > 0; off >>= 1) sum += __shfl_xor(sum, off);
    if (tid < OUT_DIM) out[(size_t)n * OUT_DIM + tid] = val - mx - __logf(sum);
  }
}

extern "C" void kernel_launch(void* const* d_in, const int* in_sizes, int n_in,
                              void* d_out, int out_size, void* d_ws, size_t ws_size,
                              hipStream_t stream) {
  const float* x      = (const float*)d_in[0];
  const int*   ei     = (const int*)d_in[1];
  const float* W1     = (const float*)d_in[2];
  const float* a_src1 = (const float*)d_in[3];
  const float* a_dst1 = (const float*)d_in[4];
  const float* b1     = (const float*)d_in[5];
  const float* W2     = (const float*)d_in[6];
  const float* a_src2 = (const float*)d_in[7];
  const float* a_dst2 = (const float*)d_in[8];
  const float* b2     = (const float*)d_in[9];
  float* out = (float*)d_out;

  char* ws = (char*)d_ws;
  size_t off = 0;
  auto alloc = [&](size_t bytes) -> void* {
    void* p = ws + off;
    off += (bytes + 255) & ~(size_t)255;
    return p;
  };
  float* h1     = (float*)alloc((size_t)N_NODES * F1 * 4);
  float* as1    = (float*)alloc((size_t)N_NODES * HEADS * 4);
  float* ad1    = (float*)alloc((size_t)N_NODES * HEADS * 4);
  float* x2     = (float*)alloc((size_t)N_NODES * F1 * 4);
  float* h2     = (float*)alloc((size_t)N_NODES * OUT_DIM * 4);
  float* as2    = (float*)alloc((size_t)N_NODES * 4);
  float* ad2    = (float*)alloc((size_t)N_NODES * 4);
  float* m1v    = (float*)alloc((size_t)N_NODES * HEADS * 4);
  float* rs1v   = (float*)alloc((size_t)N_NODES * HEADS * 4);
  float* wself1 = (float*)alloc((size_t)N_NODES * HEADS * 4);
  float* m2v    = (float*)alloc((size_t)N_NODES * 4);
  float* rs2v   = (float*)alloc((size_t)N_NODES * 4);
  float* wself2 = (float*)alloc((size_t)N_NODES * 4);
  float* w1     = (float*)alloc((size_t)N_EDGES * HEADS * 4);
  float* w2e    = (float*)alloc((size_t)N_EDGES * 4);
  int* row_ptr  = (int*)alloc((size_t)(N_NODES + 1) * 4);
  int* cursor   = (int*)alloc((size_t)N_NODES * 4);
  int* cnt      = (int*)alloc((size_t)N_NODES * 4);
  int* blk_sum  = (int*)alloc((size_t)SCAN_NBLK * 4);
  int* blk_off  = (int*)alloc((size_t)SCAN_NBLK * 4);
  int* col      = (int*)alloc((size_t)N_EDGES * 4);
  int* dstc     = (int*)alloc((size_t)N_EDGES * 4);

  hipMemsetAsync(cnt, 0, (size_t)N_NODES * 4, stream);
  hist_kernel<<<(N_EDGES + 255) / 256, 256, 0, stream>>>(ei, cnt);
  blksum_kernel<<<SCAN_NBLK, 256, 0, stream>>>(cnt, blk_sum);
  blkscan_kernel<<<1, 256, 0, stream>>>(blk_sum, blk_off, row_ptr);
  finalscan_kernel<<<SCAN_NBLK, 256, 0, stream>>>(cnt, blk_off, row_ptr, cursor);
  scatter_kernel<<<(N_EDGES + 255) / 256, 256, 0, stream>>>(ei, cursor, col, dstc);

  gemm1_kernel<<<dim3((N_NODES + BM - 1) / BM, F1 / BN), 256, 0, stream>>>(x, W1, h1);
  alpha1_kernel<<<(N_NODES * HEADS + 255) / 256, 256, 0, stream>>>(h1, a_src1, a_dst1, as1, ad1);
  ms1_kernel<<<N_NODES, 64, 0, stream>>>(as1, ad1, row_ptr, col, m1v, rs1v, wself1);
  weight1_kernel<<<(N_EDGES + 255) / 256, 256, 0, stream>>>(as1, ad1, m1v, rs1v, col, dstc, w1);
  gather1_kernel<<<N_NODES, 256, 0, stream>>>(h1, w1, wself1, b1, row_ptr, col, x2);

  gemm2_kernel<<<N_NODES, 64, 0, stream>>>(x2, W2, a_src2, a_dst2, h2, as2, ad2);
  ms2_kernel<<<N_NODES, 64, 0, stream>>>(as2, ad2, row_ptr, col, m2v, rs2v, wself2);
  weight2_kernel<<<(N_EDGES + 255) / 256, 256, 0, stream>>>(as2, ad2, m2v, rs2v, col, dstc, w2e);
  gather2_kernel<<<N_NODES, 256, 0, stream>>>(h2, w2e, wself2, b2, row_ptr, col, out);
}

// Round 4
// 474.988 us; speedup vs baseline: 1.3472x; 1.0905x over previous
//
#include <hip/hip_runtime.h>
#include <math.h>

#define N_NODES 50000
#define N_EDGES 800000
#define IN_DIM  256
#define F1      128   // HEADS*HID
#define HEADS   4
#define OUT_DIM 40
#define NEG     0.2f

#define SCAN_CHUNK 256
#define SCAN_NBLK  ((N_NODES + SCAN_CHUNK - 1) / SCAN_CHUNK)   // 196

// ---------------- CSR build (by destination) ----------------
__global__ void hist_kernel(const int* __restrict__ ei, int* __restrict__ cnt) {
  int i = blockIdx.x * blockDim.x + threadIdx.x;
  if (i < N_EDGES) atomicAdd(&cnt[ei[N_EDGES + i]], 1);
}

__global__ __launch_bounds__(256) void blksum_kernel(const int* __restrict__ cnt,
                                                     int* __restrict__ blk_sum) {
  __shared__ int lds[256];
  int b = blockIdx.x;
  int tid = threadIdx.x;
  int i = b * SCAN_CHUNK + tid;
  lds[tid] = (i < N_NODES) ? cnt[i] : 0;
  __syncthreads();
#pragma unroll
  for (int off = 128; off > 0; off >>= 1) {
    if (tid < off) lds[tid] += lds[tid + off];
    __syncthreads();
  }
  if (tid == 0) blk_sum[b] = lds[0];
}

__global__ __launch_bounds__(256) void blkscan_kernel(const int* __restrict__ blk_sum,
                                                      int* __restrict__ blk_off,
                                                      int* __restrict__ row_ptr) {
  __shared__ int lds[256];
  int tid = threadIdx.x;
  int v = (tid < SCAN_NBLK) ? blk_sum[tid] : 0;
  lds[tid] = v;
  __syncthreads();
#pragma unroll
  for (int off = 1; off < 256; off <<= 1) {
    int t = (tid >= off) ? lds[tid - off] : 0;
    __syncthreads();
    lds[tid] += t;
    __syncthreads();
  }
  if (tid < SCAN_NBLK) blk_off[tid] = lds[tid] - v;
  if (tid == 255) row_ptr[N_NODES] = lds[255];
}

__global__ __launch_bounds__(256) void finalscan_kernel(const int* __restrict__ cnt,
                                                        const int* __restrict__ blk_off,
                                                        int* __restrict__ row_ptr,
                                                        int* __restrict__ cursor) {
  __shared__ int lds[256];
  int b = blockIdx.x;
  int tid = threadIdx.x;
  int i = b * SCAN_CHUNK + tid;
  int v = (i < N_NODES) ? cnt[i] : 0;
  lds[tid] = v;
  __syncthreads();
#pragma unroll
  for (int off = 1; off < 256; off <<= 1) {
    int t = (tid >= off) ? lds[tid - off] : 0;
    __syncthreads();
    lds[tid] += t;
    __syncthreads();
  }
  if (i < N_NODES) {
    int excl = lds[tid] - v + blk_off[b];
    row_ptr[i] = excl;
    cursor[i] = excl;
  }
}

__global__ void scatter_kernel(const int* __restrict__ ei, int* __restrict__ cursor,
                               int* __restrict__ col) {
  int i = blockIdx.x * blockDim.x + threadIdx.x;
  if (i < N_EDGES) {
    int d = ei[N_EDGES + i];
    int p = atomicAdd(&cursor[d], 1);
    col[p] = ei[i];
  }
}

// ---------------- GEMM1: h1 = x @ W1  [50000,256]x[256,128] ----------------
#define BM 64
#define BN 64
#define BK 32

__global__ __launch_bounds__(256) void gemm1_kernel(
    const float* __restrict__ A, const float* __restrict__ B, float* __restrict__ C) {
  __shared__ float As[BK][BM + 4];
  __shared__ float Bs[BK][BN + 4];
  int tid = threadIdx.x;
  int bm = blockIdx.x * BM;
  int bn = blockIdx.y * BN;
  int tx = tid & 15;
  int ty = tid >> 4;
  float acc[4][4] = {{0.f}};
  for (int k0 = 0; k0 < IN_DIM; k0 += BK) {
#pragma unroll
    for (int l = 0; l < 2; l++) {
      int idx = tid + l * 256;
      int r = idx >> 3;
      int c4 = (idx & 7) << 2;
      int grow = bm + r;
      float4 v = make_float4(0.f, 0.f, 0.f, 0.f);
      if (grow < N_NODES) v = *(const float4*)&A[(size_t)grow * IN_DIM + k0 + c4];
      As[c4 + 0][r] = v.x;
      As[c4 + 1][r] = v.y;
      As[c4 + 2][r] = v.z;
      As[c4 + 3][r] = v.w;
    }
#pragma unroll
    for (int l = 0; l < 2; l++) {
      int idx = tid + l * 256;
      int r = idx >> 4;
      int c4 = (idx & 15) << 2;
      *(float4*)&Bs[r][c4] = *(const float4*)&B[(size_t)(k0 + r) * F1 + bn + c4];
    }
    __syncthreads();
#pragma unroll
    for (int kk = 0; kk < BK; kk++) {
      float a[4], b[4];
      *(float4*)a = *(const float4*)&As[kk][ty * 4];
      *(float4*)b = *(const float4*)&Bs[kk][tx * 4];
#pragma unroll
      for (int i = 0; i < 4; i++)
#pragma unroll
        for (int j = 0; j < 4; j++)
          acc[i][j] += a[i] * b[j];
    }
    __syncthreads();
  }
#pragma unroll
  for (int i = 0; i < 4; i++) {
    int grow = bm + ty * 4 + i;
    if (grow < N_NODES) {
      float4 v = make_float4(acc[i][0], acc[i][1], acc[i][2], acc[i][3]);
      *(float4*)&C[(size_t)grow * F1 + bn + tx * 4] = v;
    }
  }
}

// ---------------- alpha1: per-(node,head) dot products ----------------
__global__ __launch_bounds__(256) void alpha1_kernel(
    const float* __restrict__ h1, const float* __restrict__ a_src,
    const float* __restrict__ a_dst, float* __restrict__ as1, float* __restrict__ ad1) {
  int t = blockIdx.x * blockDim.x + threadIdx.x;
  if (t >= N_NODES * HEADS) return;
  int h = t & (HEADS - 1);
  const float4* hp = (const float4*)(h1 + (size_t)t * 32);
  const float4* ap = (const float4*)(a_src + h * 32);
  const float4* dp = (const float4*)(a_dst + h * 32);
  float sa = 0.f, sd = 0.f;
#pragma unroll
  for (int j = 0; j < 8; j++) {
    float4 v = hp[j], a = ap[j], d = dp[j];
    sa += v.x * a.x + v.y * a.y + v.z * a.z + v.w * a.w;
    sd += v.x * d.x + v.y * d.y + v.z * d.z + v.w * d.w;
  }
  as1[t] = sa;
  ad1[t] = sd;
}

__device__ __forceinline__ void online_upd(float& m, float& s, float e) {
  float mn = fmaxf(m, e);
  s = s * __expf(m - mn) + __expf(e - mn);
  m = mn;
}
__device__ __forceinline__ float lrelu(float e) { return e > 0.f ? e : e * NEG; }

// ---------------- layer-1 softmax stats (wave per node) ----------------
__global__ __launch_bounds__(64) void ms1_kernel(
    const float* __restrict__ as1, const float* __restrict__ ad1,
    const int* __restrict__ row_ptr, const int* __restrict__ col,
    float* __restrict__ m1v, float* __restrict__ rs1v, float* __restrict__ wself1) {
  int n = blockIdx.x;
  int lane = threadIdx.x;
  int start = row_ptr[n];
  int deg = row_ptr[n + 1] - start;
  float4 ad = *(const float4*)&ad1[n * 4];
  float m[4] = {-1e30f, -1e30f, -1e30f, -1e30f};
  float s[4] = {0.f, 0.f, 0.f, 0.f};
  for (int i = lane; i < deg + 1; i += 64) {
    int src = (i < deg) ? col[start + i] : n;
    float4 as = *(const float4*)&as1[src * 4];
    online_upd(m[0], s[0], lrelu(as.x + ad.x));
    online_upd(m[1], s[1], lrelu(as.y + ad.y));
    online_upd(m[2], s[2], lrelu(as.z + ad.z));
    online_upd(m[3], s[3], lrelu(as.w + ad.w));
  }
#pragma unroll
  for (int off = 32; off > 0; off >>= 1) {
#pragma unroll
    for (int h = 0; h < 4; h++) {
      float m2 = __shfl_xor(m[h], off);
      float s2 = __shfl_xor(s[h], off);
      float mn = fmaxf(m[h], m2);
      s[h] = s[h] * __expf(m[h] - mn) + s2 * __expf(m2 - mn);
      m[h] = mn;
    }
  }
  if (lane == 0) {
    float4 as = *(const float4*)&as1[n * 4];
    float es[4] = {lrelu(as.x + ad.x), lrelu(as.y + ad.y), lrelu(as.z + ad.z), lrelu(as.w + ad.w)};
    float rs0 = 1.f / (s[0] + 1e-16f), rs1 = 1.f / (s[1] + 1e-16f);
    float rs2 = 1.f / (s[2] + 1e-16f), rs3 = 1.f / (s[3] + 1e-16f);
    *(float4*)&m1v[n * 4] = make_float4(m[0], m[1], m[2], m[3]);
    *(float4*)&rs1v[n * 4] = make_float4(rs0, rs1, rs2, rs3);
    *(float4*)&wself1[n * 4] =
        make_float4(__expf(es[0] - m[0]) * rs0, __expf(es[1] - m[1]) * rs1,
                    __expf(es[2] - m[2]) * rs2, __expf(es[3] - m[3]) * rs3);
  }
}

// ---------------- layer-1 gather, fused weights (8 groups x 32 lanes, unroll 2) ----------------
__global__ __launch_bounds__(256) void gather1_kernel(
    const float* __restrict__ h1, const float* __restrict__ as1,
    const float* __restrict__ ad1, const float* __restrict__ m1v,
    const float* __restrict__ rs1v, const float* __restrict__ wself1,
    const float* __restrict__ b1,
    const int* __restrict__ row_ptr, const int* __restrict__ col,
    float* __restrict__ x2) {
  int n = blockIdx.x;
  int tid = threadIdx.x;
  int g = tid >> 5;
  int lane = tid & 31;
  int start = row_ptr[n];
  int deg = row_ptr[n + 1] - start;
  int head = lane >> 3;
  float adh = ad1[n * 4 + head];
  float mh  = m1v[n * 4 + head];
  float rsh = rs1v[n * 4 + head];
  float4 acc0 = make_float4(0.f, 0.f, 0.f, 0.f);
  float4 acc1 = make_float4(0.f, 0.f, 0.f, 0.f);
  int i = g;
  for (; i + 8 < deg; i += 16) {
    int s0 = col[start + i];
    int s1 = col[start + i + 8];
    float a0 = as1[s0 * 4 + head];
    float a1 = as1[s1 * 4 + head];
    float4 hv0 = *(const float4*)&h1[(size_t)s0 * F1 + lane * 4];
    float4 hv1 = *(const float4*)&h1[(size_t)s1 * F1 + lane * 4];
    float w0 = __expf(lrelu(a0 + adh) - mh) * rsh;
    float w1 = __expf(lrelu(a1 + adh) - mh) * rsh;
    acc0.x += w0 * hv0.x; acc0.y += w0 * hv0.y; acc0.z += w0 * hv0.z; acc0.w += w0 * hv0.w;
    acc1.x += w1 * hv1.x; acc1.y += w1 * hv1.y; acc1.z += w1 * hv1.z; acc1.w += w1 * hv1.w;
  }
  if (i < deg) {
    int s0 = col[start + i];
    float a0 = as1[s0 * 4 + head];
    float4 hv0 = *(const float4*)&h1[(size_t)s0 * F1 + lane * 4];
    float w0 = __expf(lrelu(a0 + adh) - mh) * rsh;
    acc0.x += w0 * hv0.x; acc0.y += w0 * hv0.y; acc0.z += w0 * hv0.z; acc0.w += w0 * hv0.w;
  }
  if (g == (deg & 7)) {   // self-loop (virtual edge index = deg)
    float w = wself1[n * 4 + head];
    float4 hv = *(const float4*)&h1[(size_t)n * F1 + lane * 4];
    acc0.x += w * hv.x; acc0.y += w * hv.y; acc0.z += w * hv.z; acc0.w += w * hv.w;
  }
  acc0.x += acc1.x; acc0.y += acc1.y; acc0.z += acc1.z; acc0.w += acc1.w;
  __shared__ float4 red[8][32];
  red[g][lane] = acc0;
  __syncthreads();
  if (tid < 32) {
    float4 t = red[0][tid];
#pragma unroll
    for (int gg = 1; gg < 8; gg++) {
      float4 r = red[gg][tid];
      t.x += r.x; t.y += r.y; t.z += r.z; t.w += r.w;
    }
    float4 bb = *(const float4*)&b1[tid * 4];
    t.x = fmaxf(t.x + bb.x, 0.f);
    t.y = fmaxf(t.y + bb.y, 0.f);
    t.z = fmaxf(t.z + bb.z, 0.f);
    t.w = fmaxf(t.w + bb.w, 0.f);
    *(float4*)&x2[(size_t)n * F1 + tid * 4] = t;
  }
}

// ---------------- GEMM2 + alpha2 fused (wave per row) ----------------
__global__ __launch_bounds__(64) void gemm2_kernel(
    const float* __restrict__ x2, const float* __restrict__ W2,
    const float* __restrict__ asv, const float* __restrict__ adv,
    float* __restrict__ h2, float* __restrict__ as2, float* __restrict__ ad2) {
  int n = blockIdx.x;
  int tid = threadIdx.x;
  __shared__ float xs[F1];
  xs[tid] = x2[(size_t)n * F1 + tid];
  xs[tid + 64] = x2[(size_t)n * F1 + 64 + tid];
  __syncthreads();
  float acc = 0.f;
  if (tid < OUT_DIM) {
#pragma unroll 8
    for (int k = 0; k < F1; k++) acc += xs[k] * W2[k * OUT_DIM + tid];
  }
  float pa = (tid < OUT_DIM) ? acc * asv[tid] : 0.f;
  float pd = (tid < OUT_DIM) ? acc * adv[tid] : 0.f;
#pragma unroll
  for (int off = 32; off > 0; off >>= 1) {
    pa += __shfl_xor(pa, off);
    pd += __shfl_xor(pd, off);
  }
  if (tid < OUT_DIM) h2[(size_t)n * OUT_DIM + tid] = acc;
  if (tid == 0) { as2[n] = pa; ad2[n] = pd; }
}

// ---------------- layer-2 softmax stats (wave per node) ----------------
__global__ __launch_bounds__(64) void ms2_kernel(
    const float* __restrict__ as2, const float* __restrict__ ad2,
    const int* __restrict__ row_ptr, const int* __restrict__ col,
    float* __restrict__ m2v, float* __restrict__ rs2v, float* __restrict__ wself2) {
  int n = blockIdx.x;
  int lane = threadIdx.x;
  int start = row_ptr[n];
  int deg = row_ptr[n + 1] - start;
  float ad = ad2[n];
  float m = -1e30f, s = 0.f;
  for (int i = lane; i < deg + 1; i += 64) {
    int src = (i < deg) ? col[start + i] : n;
    online_upd(m, s, lrelu(as2[src] + ad));
  }
#pragma unroll
  for (int off = 32; off > 0; off >>= 1) {
    float m2 = __shfl_xor(m, off);
    float s2 = __shfl_xor(s, off);
    float mn = fmaxf(m, m2);
    s = s * __expf(m - mn) + s2 * __expf(m2 - mn);
    m = mn;
  }
  if (lane == 0) {
    float rs = 1.f / (s + 1e-16f);
    m2v[n] = m;
    rs2v[n] = rs;
    wself2[n] = __expf(lrelu(as2[n] + ad) - m) * rs;
  }
}

// ---------------- layer-2 gather + log_softmax ----------------
// 256 thr = 4 waves; wave = 6 edge-slots x 10 lanes (float4 over 40 channels)
__global__ __launch_bounds__(256) void gather2_kernel(
    const float* __restrict__ h2, const float* __restrict__ as2,
    const float* __restrict__ ad2, const float* __restrict__ m2v,
    const float* __restrict__ rs2v, const float* __restrict__ wself2,
    const float* __restrict__ b2,
    const int* __restrict__ row_ptr, const int* __restrict__ col,
    float* __restrict__ out) {
  int n = blockIdx.x;
  int tid = threadIdx.x;
  int w = tid >> 6;
  int lane = tid & 63;
  int e_loc = lane / 10;      // 0..6 (6 = idle lanes 60..63)
  int c4 = lane - e_loc * 10; // 0..9
  int start = row_ptr[n];
  int deg = row_ptr[n + 1] - start;
  float adh = ad2[n];
  float mh  = m2v[n];
  float rsh = rs2v[n];
  float4 acc = make_float4(0.f, 0.f, 0.f, 0.f);
  if (e_loc < 6) {
    int slot = w * 6 + e_loc;   // 0..23
    for (int i = slot; i <= deg; i += 24) {
      int src;
      float wgt;
      if (i < deg) {
        src = col[start + i];
        wgt = __expf(lrelu(as2[src] + adh) - mh) * rsh;
      } else {
        src = n;
        wgt = wself2[n];
      }
      float4 hv = *(const float4*)&h2[(size_t)src * OUT_DIM + c4 * 4];
      acc.x += wgt * hv.x; acc.y += wgt * hv.y; acc.z += wgt * hv.z; acc.w += wgt * hv.w;
    }
  }
  __shared__ float4 red[24][10];
  if (e_loc < 6) red[w * 6 + e_loc][c4] = acc;
  __syncthreads();
  if (tid < 64) {
    float val = 0.f;
    if (tid < OUT_DIM) {
      const float* redf = (const float*)red;
#pragma unroll
      for (int s = 0; s < 24; s++) val += redf[s * 40 + tid];
      val += b2[tid];
    } else {
      val = -1e30f;
    }
    float mx = val;
#pragma unroll
    for (int off = 32; off > 0; off >>= 1) mx = fmaxf(mx, __shfl_xor(mx, off));
    float ex = (tid < OUT_DIM) ? __expf(val - mx) : 0.f;
    float sum = ex;
#pragma unroll
    for (int off = 32; off > 0; off >>= 1) sum += __shfl_xor(sum, off);
    if (tid < OUT_DIM) out[(size_t)n * OUT_DIM + tid] = val - mx - __logf(sum);
  }
}

extern "C" void kernel_launch(void* const* d_in, const int* in_sizes, int n_in,
                              void* d_out, int out_size, void* d_ws, size_t ws_size,
                              hipStream_t stream) {
  const float* x      = (const float*)d_in[0];
  const int*   ei     = (const int*)d_in[1];
  const float* W1     = (const float*)d_in[2];
  const float* a_src1 = (const float*)d_in[3];
  const float* a_dst1 = (const float*)d_in[4];
  const float* b1     = (const float*)d_in[5];
  const float* W2     = (const float*)d_in[6];
  const float* a_src2 = (const float*)d_in[7];
  const float* a_dst2 = (const float*)d_in[8];
  const float* b2     = (const float*)d_in[9];
  float* out = (float*)d_out;

  char* ws = (char*)d_ws;
  size_t off = 0;
  auto alloc = [&](size_t bytes) -> void* {
    void* p = ws + off;
    off += (bytes + 255) & ~(size_t)255;
    return p;
  };
  float* h1     = (float*)alloc((size_t)N_NODES * F1 * 4);
  float* as1    = (float*)alloc((size_t)N_NODES * HEADS * 4);
  float* ad1    = (float*)alloc((size_t)N_NODES * HEADS * 4);
  float* x2     = (float*)alloc((size_t)N_NODES * F1 * 4);
  float* h2     = (float*)alloc((size_t)N_NODES * OUT_DIM * 4);
  float* as2    = (float*)alloc((size_t)N_NODES * 4);
  float* ad2    = (float*)alloc((size_t)N_NODES * 4);
  float* m1v    = (float*)alloc((size_t)N_NODES * HEADS * 4);
  float* rs1v   = (float*)alloc((size_t)N_NODES * HEADS * 4);
  float* wself1 = (float*)alloc((size_t)N_NODES * HEADS * 4);
  float* m2v    = (float*)alloc((size_t)N_NODES * 4);
  float* rs2v   = (float*)alloc((size_t)N_NODES * 4);
  float* wself2 = (float*)alloc((size_t)N_NODES * 4);
  int* row_ptr  = (int*)alloc((size_t)(N_NODES + 1) * 4);
  int* cursor   = (int*)alloc((size_t)N_NODES * 4);
  int* cnt      = (int*)alloc((size_t)N_NODES * 4);
  int* blk_sum  = (int*)alloc((size_t)SCAN_NBLK * 4);
  int* blk_off  = (int*)alloc((size_t)SCAN_NBLK * 4);
  int* col      = (int*)alloc((size_t)N_EDGES * 4);

  hipMemsetAsync(cnt, 0, (size_t)N_NODES * 4, stream);
  hist_kernel<<<(N_EDGES + 255) / 256, 256, 0, stream>>>(ei, cnt);
  blksum_kernel<<<SCAN_NBLK, 256, 0, stream>>>(cnt, blk_sum);
  blkscan_kernel<<<1, 256, 0, stream>>>(blk_sum, blk_off, row_ptr);
  finalscan_kernel<<<SCAN_NBLK, 256, 0, stream>>>(cnt, blk_off, row_ptr, cursor);
  scatter_kernel<<<(N_EDGES + 255) / 256, 256, 0, stream>>>(ei, cursor, col);

  gemm1_kernel<<<dim3((N_NODES + BM - 1) / BM, F1 / BN), 256, 0, stream>>>(x, W1, h1);
  alpha1_kernel<<<(N_NODES * HEADS + 255) / 256, 256, 0, stream>>>(h1, a_src1, a_dst1, as1, ad1);
  ms1_kernel<<<N_NODES, 64, 0, stream>>>(as1, ad1, row_ptr, col, m1v, rs1v, wself1);
  gather1_kernel<<<N_NODES, 256, 0, stream>>>(h1, as1, ad1, m1v, rs1v, wself1, b1, row_ptr, col, x2);

  gemm2_kernel<<<N_NODES, 64, 0, stream>>>(x2, W2, a_src2, a_dst2, h2, as2, ad2);
  ms2_kernel<<<N_NODES, 64, 0, stream>>>(as2, ad2, row_ptr, col, m2v, rs2v, wself2);
  gather2_kernel<<<N_NODES, 256, 0, stream>>>(h2, as2, ad2, m2v, rs2v, wself2, b2, row_ptr, col, out);
}

// Round 5
// 468.415 us; speedup vs baseline: 1.3661x; 1.0140x over previous
//
#include <hip/hip_runtime.h>
#include <math.h>

#define N_NODES 50000
#define N_EDGES 800000
#define IN_DIM  256
#define F1      128   // HEADS*HID
#define HEADS   4
#define OUT_DIM 40
#define NEG     0.2f

#define SCAN_CHUNK 256
#define SCAN_NBLK  ((N_NODES + SCAN_CHUNK - 1) / SCAN_CHUNK)   // 196

// ---- bf16 helpers (RNE pack, shift unpack) ----
__device__ __forceinline__ unsigned short f2bf(float f) {
  unsigned int u = __float_as_uint(f);
  u += 0x7FFF + ((u >> 16) & 1);
  return (unsigned short)(u >> 16);
}
__device__ __forceinline__ float bflo(unsigned int u) { return __uint_as_float(u << 16); }
__device__ __forceinline__ float bfhi(unsigned int u) { return __uint_as_float(u & 0xffff0000u); }

// ---------------- CSR build (by destination) ----------------
__global__ void hist_kernel(const int* __restrict__ ei, int* __restrict__ cnt) {
  int i = blockIdx.x * blockDim.x + threadIdx.x;
  if (i < N_EDGES) atomicAdd(&cnt[ei[N_EDGES + i]], 1);
}

__global__ __launch_bounds__(256) void blksum_kernel(const int* __restrict__ cnt,
                                                     int* __restrict__ blk_sum) {
  __shared__ int lds[256];
  int b = blockIdx.x;
  int tid = threadIdx.x;
  int i = b * SCAN_CHUNK + tid;
  lds[tid] = (i < N_NODES) ? cnt[i] : 0;
  __syncthreads();
#pragma unroll
  for (int off = 128; off > 0; off >>= 1) {
    if (tid < off) lds[tid] += lds[tid + off];
    __syncthreads();
  }
  if (tid == 0) blk_sum[b] = lds[0];
}

__global__ __launch_bounds__(256) void blkscan_kernel(const int* __restrict__ blk_sum,
                                                      int* __restrict__ blk_off,
                                                      int* __restrict__ row_ptr) {
  __shared__ int lds[256];
  int tid = threadIdx.x;
  int v = (tid < SCAN_NBLK) ? blk_sum[tid] : 0;
  lds[tid] = v;
  __syncthreads();
#pragma unroll
  for (int off = 1; off < 256; off <<= 1) {
    int t = (tid >= off) ? lds[tid - off] : 0;
    __syncthreads();
    lds[tid] += t;
    __syncthreads();
  }
  if (tid < SCAN_NBLK) blk_off[tid] = lds[tid] - v;
  if (tid == 255) row_ptr[N_NODES] = lds[255];
}

__global__ __launch_bounds__(256) void finalscan_kernel(const int* __restrict__ cnt,
                                                        const int* __restrict__ blk_off,
                                                        int* __restrict__ row_ptr,
                                                        int* __restrict__ cursor) {
  __shared__ int lds[256];
  int b = blockIdx.x;
  int tid = threadIdx.x;
  int i = b * SCAN_CHUNK + tid;
  int v = (i < N_NODES) ? cnt[i] : 0;
  lds[tid] = v;
  __syncthreads();
#pragma unroll
  for (int off = 1; off < 256; off <<= 1) {
    int t = (tid >= off) ? lds[tid - off] : 0;
    __syncthreads();
    lds[tid] += t;
    __syncthreads();
  }
  if (i < N_NODES) {
    int excl = lds[tid] - v + blk_off[b];
    row_ptr[i] = excl;
    cursor[i] = excl;
  }
}

__global__ void scatter_kernel(const int* __restrict__ ei, int* __restrict__ cursor,
                               int* __restrict__ col) {
  int i = blockIdx.x * blockDim.x + threadIdx.x;
  if (i < N_EDGES) {
    int d = ei[N_EDGES + i];
    int p = atomicAdd(&cursor[d], 1);
    col[p] = ei[i];
  }
}

// ---------------- GEMM1: h1b(bf16) = x @ W1  [50000,256]x[256,128] ----------------
#define BM 64
#define BN 64
#define BK 32

__global__ __launch_bounds__(256) void gemm1_kernel(
    const float* __restrict__ A, const float* __restrict__ B,
    unsigned short* __restrict__ Cb) {
  __shared__ float As[BK][BM + 4];
  __shared__ float Bs[BK][BN + 4];
  int tid = threadIdx.x;
  int bm = blockIdx.x * BM;
  int bn = blockIdx.y * BN;
  int tx = tid & 15;
  int ty = tid >> 4;
  float acc[4][4] = {{0.f}};
  for (int k0 = 0; k0 < IN_DIM; k0 += BK) {
#pragma unroll
    for (int l = 0; l < 2; l++) {
      int idx = tid + l * 256;
      int r = idx >> 3;
      int c4 = (idx & 7) << 2;
      int grow = bm + r;
      float4 v = make_float4(0.f, 0.f, 0.f, 0.f);
      if (grow < N_NODES) v = *(const float4*)&A[(size_t)grow * IN_DIM + k0 + c4];
      As[c4 + 0][r] = v.x;
      As[c4 + 1][r] = v.y;
      As[c4 + 2][r] = v.z;
      As[c4 + 3][r] = v.w;
    }
#pragma unroll
    for (int l = 0; l < 2; l++) {
      int idx = tid + l * 256;
      int r = idx >> 4;
      int c4 = (idx & 15) << 2;
      *(float4*)&Bs[r][c4] = *(const float4*)&B[(size_t)(k0 + r) * F1 + bn + c4];
    }
    __syncthreads();
#pragma unroll
    for (int kk = 0; kk < BK; kk++) {
      float a[4], b[4];
      *(float4*)a = *(const float4*)&As[kk][ty * 4];
      *(float4*)b = *(const float4*)&Bs[kk][tx * 4];
#pragma unroll
      for (int i = 0; i < 4; i++)
#pragma unroll
        for (int j = 0; j < 4; j++)
          acc[i][j] += a[i] * b[j];
    }
    __syncthreads();
  }
#pragma unroll
  for (int i = 0; i < 4; i++) {
    int grow = bm + ty * 4 + i;
    if (grow < N_NODES) {
      unsigned int p0 = ((unsigned int)f2bf(acc[i][1]) << 16) | f2bf(acc[i][0]);
      unsigned int p1 = ((unsigned int)f2bf(acc[i][3]) << 16) | f2bf(acc[i][2]);
      *(uint2*)&Cb[(size_t)grow * F1 + bn + tx * 4] = make_uint2(p0, p1);
    }
  }
}

// ---------------- alpha1: per-(node,head) dot products (bf16 h1) ----------------
__global__ __launch_bounds__(256) void alpha1_kernel(
    const unsigned short* __restrict__ h1b, const float* __restrict__ a_src,
    const float* __restrict__ a_dst, float* __restrict__ as1, float* __restrict__ ad1) {
  int t = blockIdx.x * blockDim.x + threadIdx.x;   // t = n*HEADS + h
  if (t >= N_NODES * HEADS) return;
  int h = t & (HEADS - 1);
  const uint4* hp = (const uint4*)(h1b + (size_t)t * 32);   // 32 bf16 = 64 B
  const float* ap = a_src + h * 32;
  const float* dp = a_dst + h * 32;
  float sa = 0.f, sd = 0.f;
#pragma unroll
  for (int j = 0; j < 4; j++) {
    uint4 u = hp[j];
    float v[8] = {bflo(u.x), bfhi(u.x), bflo(u.y), bfhi(u.y),
                  bflo(u.z), bfhi(u.z), bflo(u.w), bfhi(u.w)};
#pragma unroll
    for (int k = 0; k < 8; k++) {
      sa += v[k] * ap[j * 8 + k];
      sd += v[k] * dp[j * 8 + k];
    }
  }
  as1[t] = sa;
  ad1[t] = sd;
}

__device__ __forceinline__ void online_upd(float& m, float& s, float e) {
  float mn = fmaxf(m, e);
  s = s * __expf(m - mn) + __expf(e - mn);
  m = mn;
}
__device__ __forceinline__ float lrelu(float e) { return e > 0.f ? e : e * NEG; }

// ---------------- layer-1 softmax stats (wave per node) ----------------
__global__ __launch_bounds__(64) void ms1_kernel(
    const float* __restrict__ as1, const float* __restrict__ ad1,
    const int* __restrict__ row_ptr, const int* __restrict__ col,
    float* __restrict__ m1v, float* __restrict__ rs1v, float* __restrict__ wself1) {
  int n = blockIdx.x;
  int lane = threadIdx.x;
  int start = row_ptr[n];
  int deg = row_ptr[n + 1] - start;
  float4 ad = *(const float4*)&ad1[n * 4];
  float m[4] = {-1e30f, -1e30f, -1e30f, -1e30f};
  float s[4] = {0.f, 0.f, 0.f, 0.f};
  for (int i = lane; i < deg + 1; i += 64) {
    int src = (i < deg) ? col[start + i] : n;
    float4 as = *(const float4*)&as1[src * 4];
    online_upd(m[0], s[0], lrelu(as.x + ad.x));
    online_upd(m[1], s[1], lrelu(as.y + ad.y));
    online_upd(m[2], s[2], lrelu(as.z + ad.z));
    online_upd(m[3], s[3], lrelu(as.w + ad.w));
  }
#pragma unroll
  for (int off = 32; off > 0; off >>= 1) {
#pragma unroll
    for (int h = 0; h < 4; h++) {
      float m2 = __shfl_xor(m[h], off);
      float s2 = __shfl_xor(s[h], off);
      float mn = fmaxf(m[h], m2);
      s[h] = s[h] * __expf(m[h] - mn) + s2 * __expf(m2 - mn);
      m[h] = mn;
    }
  }
  if (lane == 0) {
    float4 as = *(const float4*)&as1[n * 4];
    float es[4] = {lrelu(as.x + ad.x), lrelu(as.y + ad.y), lrelu(as.z + ad.z), lrelu(as.w + ad.w)};
    float rs0 = 1.f / (s[0] + 1e-16f), rs1 = 1.f / (s[1] + 1e-16f);
    float rs2 = 1.f / (s[2] + 1e-16f), rs3 = 1.f / (s[3] + 1e-16f);
    *(float4*)&m1v[n * 4] = make_float4(m[0], m[1], m[2], m[3]);
    *(float4*)&rs1v[n * 4] = make_float4(rs0, rs1, rs2, rs3);
    *(float4*)&wself1[n * 4] =
        make_float4(__expf(es[0] - m[0]) * rs0, __expf(es[1] - m[1]) * rs1,
                    __expf(es[2] - m[2]) * rs2, __expf(es[3] - m[3]) * rs3);
  }
}

// ---------------- layer-1 gather, bf16 rows, fused weights ----------------
// 256 thr = 16 edge-slots x 16 lanes; lane covers 8 channels via one 16B load
__global__ __launch_bounds__(256) void gather1_kernel(
    const unsigned short* __restrict__ h1b, const float* __restrict__ as1,
    const float* __restrict__ ad1, const float* __restrict__ m1v,
    const float* __restrict__ rs1v, const float* __restrict__ wself1,
    const float* __restrict__ b1,
    const int* __restrict__ row_ptr, const int* __restrict__ col,
    float* __restrict__ x2) {
  int n = blockIdx.x;
  int tid = threadIdx.x;
  int slot = tid >> 4;        // 0..15
  int lane16 = tid & 15;      // channel group: ch = lane16*8 .. +7
  int head = lane16 >> 2;
  int start = row_ptr[n];
  int deg = row_ptr[n + 1] - start;
  float adh = ad1[n * 4 + head];
  float mh  = m1v[n * 4 + head];
  float rsh = rs1v[n * 4 + head];
  float4 accA = make_float4(0.f, 0.f, 0.f, 0.f);
  float4 accB = make_float4(0.f, 0.f, 0.f, 0.f);
  for (int i = slot; i <= deg; i += 16) {
    int src;
    float w;
    if (i < deg) {
      src = col[start + i];
      w = __expf(lrelu(as1[src * 4 + head] + adh) - mh) * rsh;
    } else {
      src = n;
      w = wself1[n * 4 + head];
    }
    uint4 u = *(const uint4*)(h1b + (size_t)src * F1 + lane16 * 8);
    accA.x += w * bflo(u.x); accA.y += w * bfhi(u.x);
    accA.z += w * bflo(u.y); accA.w += w * bfhi(u.y);
    accB.x += w * bflo(u.z); accB.y += w * bfhi(u.z);
    accB.z += w * bflo(u.w); accB.w += w * bfhi(u.w);
  }
  __shared__ float red[16][132];
  *(float4*)&red[slot][lane16 * 8] = accA;
  *(float4*)&red[slot][lane16 * 8 + 4] = accB;
  __syncthreads();
  if (tid < F1) {
    float v = 0.f;
#pragma unroll
    for (int s = 0; s < 16; s++) v += red[s][tid];
    v = fmaxf(v + b1[tid], 0.f);
    x2[(size_t)n * F1 + tid] = v;
  }
}

// ---------------- GEMM2 + alpha2 fused (wave per row), bf16 h2 out ----------------
__global__ __launch_bounds__(64) void gemm2_kernel(
    const float* __restrict__ x2, const float* __restrict__ W2,
    const float* __restrict__ asv, const float* __restrict__ adv,
    unsigned short* __restrict__ h2b, float* __restrict__ as2, float* __restrict__ ad2) {
  int n = blockIdx.x;
  int tid = threadIdx.x;
  __shared__ float xs[F1];
  xs[tid] = x2[(size_t)n * F1 + tid];
  xs[tid + 64] = x2[(size_t)n * F1 + 64 + tid];
  __syncthreads();
  float acc = 0.f;
  if (tid < OUT_DIM) {
#pragma unroll 8
    for (int k = 0; k < F1; k++) acc += xs[k] * W2[k * OUT_DIM + tid];
  }
  float pa = (tid < OUT_DIM) ? acc * asv[tid] : 0.f;
  float pd = (tid < OUT_DIM) ? acc * adv[tid] : 0.f;
#pragma unroll
  for (int off = 32; off > 0; off >>= 1) {
    pa += __shfl_xor(pa, off);
    pd += __shfl_xor(pd, off);
  }
  if (tid < OUT_DIM) h2b[(size_t)n * OUT_DIM + tid] = f2bf(acc);
  if (tid == 0) { as2[n] = pa; ad2[n] = pd; }
}

// ---------------- layer-2 softmax stats (wave per node) ----------------
__global__ __launch_bounds__(64) void ms2_kernel(
    const float* __restrict__ as2, const float* __restrict__ ad2,
    const int* __restrict__ row_ptr, const int* __restrict__ col,
    float* __restrict__ m2v, float* __restrict__ rs2v, float* __restrict__ wself2) {
  int n = blockIdx.x;
  int lane = threadIdx.x;
  int start = row_ptr[n];
  int deg = row_ptr[n + 1] - start;
  float ad = ad2[n];
  float m = -1e30f, s = 0.f;
  for (int i = lane; i < deg + 1; i += 64) {
    int src = (i < deg) ? col[start + i] : n;
    online_upd(m, s, lrelu(as2[src] + ad));
  }
#pragma unroll
  for (int off = 32; off > 0; off >>= 1) {
    float m2 = __shfl_xor(m, off);
    float s2 = __shfl_xor(s, off);
    float mn = fmaxf(m, m2);
    s = s * __expf(m - mn) + s2 * __expf(m2 - mn);
    m = mn;
  }
  if (lane == 0) {
    float rs = 1.f / (s + 1e-16f);
    m2v[n] = m;
    rs2v[n] = rs;
    wself2[n] = __expf(lrelu(as2[n] + ad) - m) * rs;
  }
}

// ---------------- layer-2 gather + log_softmax, bf16 rows ----------------
// 256 thr = 4 waves; wave = 12 edge-slots x 5 lanes (16B bf16x8 loads, row=80B)
__global__ __launch_bounds__(256) void gather2_kernel(
    const unsigned short* __restrict__ h2b, const float* __restrict__ as2,
    const float* __restrict__ ad2, const float* __restrict__ m2v,
    const float* __restrict__ rs2v, const float* __restrict__ wself2,
    const float* __restrict__ b2,
    const int* __restrict__ row_ptr, const int* __restrict__ col,
    float* __restrict__ out) {
  int n = blockIdx.x;
  int tid = threadIdx.x;
  int w = tid >> 6;
  int lane = tid & 63;
  int e_loc = lane / 5;       // 0..12 (12 = idle lanes 60..63)
  int c = lane - e_loc * 5;   // 0..4, channels c*8..c*8+7
  int start = row_ptr[n];
  int deg = row_ptr[n + 1] - start;
  float adh = ad2[n];
  float mh  = m2v[n];
  float rsh = rs2v[n];
  float4 accA = make_float4(0.f, 0.f, 0.f, 0.f);
  float4 accB = make_float4(0.f, 0.f, 0.f, 0.f);
  int slot = w * 12 + e_loc;  // 0..47
  if (e_loc < 12) {
    for (int i = slot; i <= deg; i += 48) {
      int src;
      float wgt;
      if (i < deg) {
        src = col[start + i];
        wgt = __expf(lrelu(as2[src] + adh) - mh) * rsh;
      } else {
        src = n;
        wgt = wself2[n];
      }
      uint4 u = *(const uint4*)(h2b + (size_t)src * OUT_DIM + c * 8);
      accA.x += wgt * bflo(u.x); accA.y += wgt * bfhi(u.x);
      accA.z += wgt * bflo(u.y); accA.w += wgt * bfhi(u.y);
      accB.x += wgt * bflo(u.z); accB.y += wgt * bfhi(u.z);
      accB.z += wgt * bflo(u.w); accB.w += wgt * bfhi(u.w);
    }
  }
  __shared__ float red[48][44];
  if (e_loc < 12) {
    *(float4*)&red[slot][c * 8] = accA;
    *(float4*)&red[slot][c * 8 + 4] = accB;
  }
  __syncthreads();
  if (tid < 64) {
    float val = 0.f;
    if (tid < OUT_DIM) {
#pragma unroll
      for (int s = 0; s < 48; s++) val += red[s][tid];
      val += b2[tid];
    } else {
      val = -1e30f;
    }
    float mx = val;
#pragma unroll
    for (int off = 32; off > 0; off >>= 1) mx = fmaxf(mx, __shfl_xor(mx, off));
    float ex = (tid < OUT_DIM) ? __expf(val - mx) : 0.f;
    float sum = ex;
#pragma unroll
    for (int off = 32; off > 0; off >>= 1) sum += __shfl_xor(sum, off);
    if (tid < OUT_DIM) out[(size_t)n * OUT_DIM + tid] = val - mx - __logf(sum);
  }
}

extern "C" void kernel_launch(void* const* d_in, const int* in_sizes, int n_in,
                              void* d_out, int out_size, void* d_ws, size_t ws_size,
                              hipStream_t stream) {
  const float* x      = (const float*)d_in[0];
  const int*   ei     = (const int*)d_in[1];
  const float* W1     = (const float*)d_in[2];
  const float* a_src1 = (const float*)d_in[3];
  const float* a_dst1 = (const float*)d_in[4];
  const float* b1     = (const float*)d_in[5];
  const float* W2     = (const float*)d_in[6];
  const float* a_src2 = (const float*)d_in[7];
  const float* a_dst2 = (const float*)d_in[8];
  const float* b2     = (const float*)d_in[9];
  float* out = (float*)d_out;

  char* ws = (char*)d_ws;
  size_t off = 0;
  auto alloc = [&](size_t bytes) -> void* {
    void* p = ws + off;
    off += (bytes + 255) & ~(size_t)255;
    return p;
  };
  unsigned short* h1b = (unsigned short*)alloc((size_t)N_NODES * F1 * 2);       // 12.8 MB
  unsigned short* h2b = (unsigned short*)alloc((size_t)N_NODES * OUT_DIM * 2);  // 4 MB
  float* as1    = (float*)alloc((size_t)N_NODES * HEADS * 4);
  float* ad1    = (float*)alloc((size_t)N_NODES * HEADS * 4);
  float* x2     = (float*)alloc((size_t)N_NODES * F1 * 4);
  float* as2    = (float*)alloc((size_t)N_NODES * 4);
  float* ad2    = (float*)alloc((size_t)N_NODES * 4);
  float* m1v    = (float*)alloc((size_t)N_NODES * HEADS * 4);
  float* rs1v   = (float*)alloc((size_t)N_NODES * HEADS * 4);
  float* wself1 = (float*)alloc((size_t)N_NODES * HEADS * 4);
  float* m2v    = (float*)alloc((size_t)N_NODES * 4);
  float* rs2v   = (float*)alloc((size_t)N_NODES * 4);
  float* wself2 = (float*)alloc((size_t)N_NODES * 4);
  int* row_ptr  = (int*)alloc((size_t)(N_NODES + 1) * 4);
  int* cursor   = (int*)alloc((size_t)N_NODES * 4);
  int* cnt      = (int*)alloc((size_t)N_NODES * 4);
  int* blk_sum  = (int*)alloc((size_t)SCAN_NBLK * 4);
  int* blk_off  = (int*)alloc((size_t)SCAN_NBLK * 4);
  int* col      = (int*)alloc((size_t)N_EDGES * 4);

  hipMemsetAsync(cnt, 0, (size_t)N_NODES * 4, stream);
  hist_kernel<<<(N_EDGES + 255) / 256, 256, 0, stream>>>(ei, cnt);
  blksum_kernel<<<SCAN_NBLK, 256, 0, stream>>>(cnt, blk_sum);
  blkscan_kernel<<<1, 256, 0, stream>>>(blk_sum, blk_off, row_ptr);
  finalscan_kernel<<<SCAN_NBLK, 256, 0, stream>>>(cnt, blk_off, row_ptr, cursor);
  scatter_kernel<<<(N_EDGES + 255) / 256, 256, 0, stream>>>(ei, cursor, col);

  gemm1_kernel<<<dim3((N_NODES + BM - 1) / BM, F1 / BN), 256, 0, stream>>>(x, W1, h1b);
  alpha1_kernel<<<(N_NODES * HEADS + 255) / 256, 256, 0, stream>>>(h1b, a_src1, a_dst1, as1, ad1);
  ms1_kernel<<<N_NODES, 64, 0, stream>>>(as1, ad1, row_ptr, col, m1v, rs1v, wself1);
  gather1_kernel<<<N_NODES, 256, 0, stream>>>(h1b, as1, ad1, m1v, rs1v, wself1, b1, row_ptr, col, x2);

  gemm2_kernel<<<N_NODES, 64, 0, stream>>>(x2, W2, a_src2, a_dst2, h2b, as2, ad2);
  ms2_kernel<<<N_NODES, 64, 0, stream>>>(as2, ad2, row_ptr, col, m2v, rs2v, wself2);
  gather2_kernel<<<N_NODES, 256, 0, stream>>>(h2b, as2, ad2, m2v, rs2v, wself2, b2, row_ptr, col, out);
}

// Round 6
// 408.828 us; speedup vs baseline: 1.5652x; 1.1458x over previous
//
#include <hip/hip_runtime.h>
#include <math.h>

#define N_NODES 50000
#define N_EDGES 800000
#define IN_DIM  256
#define F1      128   // HEADS*HID
#define HEADS   4
#define OUT_DIM 40
#define NEG     0.2f

#define SCAN_CHUNK 256
#define SCAN_NBLK  ((N_NODES + SCAN_CHUNK - 1) / SCAN_CHUNK)   // 196

// ---- bf16 helpers (RNE pack, shift unpack) ----
__device__ __forceinline__ unsigned short f2bf(float f) {
  unsigned int u = __float_as_uint(f);
  u += 0x7FFF + ((u >> 16) & 1);
  return (unsigned short)(u >> 16);
}
__device__ __forceinline__ float bflo(unsigned int u) { return __uint_as_float(u << 16); }
__device__ __forceinline__ float bfhi(unsigned int u) { return __uint_as_float(u & 0xffff0000u); }

__device__ __forceinline__ float lrelu(float e) { return e > 0.f ? e : e * NEG; }

// ---------------- CSR build (by destination) ----------------
__global__ void hist_kernel(const int* __restrict__ ei, int* __restrict__ cnt) {
  int i = blockIdx.x * blockDim.x + threadIdx.x;
  if (i < N_EDGES) atomicAdd(&cnt[ei[N_EDGES + i]], 1);
}

__global__ __launch_bounds__(256) void blksum_kernel(const int* __restrict__ cnt,
                                                     int* __restrict__ blk_sum) {
  __shared__ int lds[256];
  int b = blockIdx.x;
  int tid = threadIdx.x;
  int i = b * SCAN_CHUNK + tid;
  lds[tid] = (i < N_NODES) ? cnt[i] : 0;
  __syncthreads();
#pragma unroll
  for (int off = 128; off > 0; off >>= 1) {
    if (tid < off) lds[tid] += lds[tid + off];
    __syncthreads();
  }
  if (tid == 0) blk_sum[b] = lds[0];
}

__global__ __launch_bounds__(256) void blkscan_kernel(const int* __restrict__ blk_sum,
                                                      int* __restrict__ blk_off,
                                                      int* __restrict__ row_ptr) {
  __shared__ int lds[256];
  int tid = threadIdx.x;
  int v = (tid < SCAN_NBLK) ? blk_sum[tid] : 0;
  lds[tid] = v;
  __syncthreads();
#pragma unroll
  for (int off = 1; off < 256; off <<= 1) {
    int t = (tid >= off) ? lds[tid - off] : 0;
    __syncthreads();
    lds[tid] += t;
    __syncthreads();
  }
  if (tid < SCAN_NBLK) blk_off[tid] = lds[tid] - v;
  if (tid == 255) row_ptr[N_NODES] = lds[255];
}

__global__ __launch_bounds__(256) void finalscan_kernel(const int* __restrict__ cnt,
                                                        const int* __restrict__ blk_off,
                                                        int* __restrict__ row_ptr,
                                                        int* __restrict__ cursor) {
  __shared__ int lds[256];
  int b = blockIdx.x;
  int tid = threadIdx.x;
  int i = b * SCAN_CHUNK + tid;
  int v = (i < N_NODES) ? cnt[i] : 0;
  lds[tid] = v;
  __syncthreads();
#pragma unroll
  for (int off = 1; off < 256; off <<= 1) {
    int t = (tid >= off) ? lds[tid - off] : 0;
    __syncthreads();
    lds[tid] += t;
    __syncthreads();
  }
  if (i < N_NODES) {
    int excl = lds[tid] - v + blk_off[b];
    row_ptr[i] = excl;
    cursor[i] = excl;
  }
}

__global__ void scatter_kernel(const int* __restrict__ ei, int* __restrict__ cursor,
                               int* __restrict__ col) {
  int i = blockIdx.x * blockDim.x + threadIdx.x;
  if (i < N_EDGES) {
    int d = ei[N_EDGES + i];
    int p = atomicAdd(&cursor[d], 1);
    col[p] = ei[i];
  }
}

// ---------------- GEMM1 + alpha1 fused: h1b = x@W1 (bf16), as1/ad1 ----------------
#define BM 64
#define BN 64
#define BK 32

__global__ __launch_bounds__(256) void gemm1_kernel(
    const float* __restrict__ A, const float* __restrict__ B,
    const float* __restrict__ a_src, const float* __restrict__ a_dst,
    unsigned short* __restrict__ Cb, float* __restrict__ as1, float* __restrict__ ad1) {
  __shared__ float As[BK][BM + 4];
  __shared__ float Bs[BK][BN + 4];
  int tid = threadIdx.x;
  int bm = blockIdx.x * BM;
  int bn = blockIdx.y * BN;
  int tx = tid & 15;
  int ty = tid >> 4;
  float acc[4][4] = {{0.f}};
  for (int k0 = 0; k0 < IN_DIM; k0 += BK) {
#pragma unroll
    for (int l = 0; l < 2; l++) {
      int idx = tid + l * 256;
      int r = idx >> 3;
      int c4 = (idx & 7) << 2;
      int grow = bm + r;
      float4 v = make_float4(0.f, 0.f, 0.f, 0.f);
      if (grow < N_NODES) v = *(const float4*)&A[(size_t)grow * IN_DIM + k0 + c4];
      As[c4 + 0][r] = v.x;
      As[c4 + 1][r] = v.y;
      As[c4 + 2][r] = v.z;
      As[c4 + 3][r] = v.w;
    }
#pragma unroll
    for (int l = 0; l < 2; l++) {
      int idx = tid + l * 256;
      int r = idx >> 4;
      int c4 = (idx & 15) << 2;
      *(float4*)&Bs[r][c4] = *(const float4*)&B[(size_t)(k0 + r) * F1 + bn + c4];
    }
    __syncthreads();
#pragma unroll
    for (int kk = 0; kk < BK; kk++) {
      float a[4], b[4];
      *(float4*)a = *(const float4*)&As[kk][ty * 4];
      *(float4*)b = *(const float4*)&Bs[kk][tx * 4];
#pragma unroll
      for (int i = 0; i < 4; i++)
#pragma unroll
        for (int j = 0; j < 4; j++)
          acc[i][j] += a[i] * b[j];
    }
    __syncthreads();
  }
  // write bf16 h1
#pragma unroll
  for (int i = 0; i < 4; i++) {
    int grow = bm + ty * 4 + i;
    if (grow < N_NODES) {
      unsigned int p0 = ((unsigned int)f2bf(acc[i][1]) << 16) | f2bf(acc[i][0]);
      unsigned int p1 = ((unsigned int)f2bf(acc[i][3]) << 16) | f2bf(acc[i][2]);
      *(uint2*)&Cb[(size_t)grow * F1 + bn + tx * 4] = make_uint2(p0, p1);
    }
  }
  // fused alpha: this block covers 2 whole heads (bn=0 -> heads 0,1; bn=64 -> 2,3)
  int head = (bn >> 5) + (tx >> 3);
  int cb = (tx & 7) * 4;   // within-head channel offset
  float asr[4], adr[4];
#pragma unroll
  for (int j = 0; j < 4; j++) {
    asr[j] = a_src[head * 32 + cb + j];
    adr[j] = a_dst[head * 32 + cb + j];
  }
#pragma unroll
  for (int i = 0; i < 4; i++) {
    float sa = acc[i][0] * asr[0] + acc[i][1] * asr[1] + acc[i][2] * asr[2] + acc[i][3] * asr[3];
    float sd = acc[i][0] * adr[0] + acc[i][1] * adr[1] + acc[i][2] * adr[2] + acc[i][3] * adr[3];
#pragma unroll
    for (int off = 1; off < 8; off <<= 1) {
      sa += __shfl_xor(sa, off);
      sd += __shfl_xor(sd, off);
    }
    int grow = bm + ty * 4 + i;
    if ((tx & 7) == 0 && grow < N_NODES) {
      as1[grow * 4 + head] = sa;
      ad1[grow * 4 + head] = sd;
    }
  }
}

// ---------------- layer-1: fused softmax-sum + gather (block per node) ----------------
// 256 thr = 16 edge-slots x 16 lanes; lane covers 8 channels via one 16B load
__global__ __launch_bounds__(256) void gather1_kernel(
    const unsigned short* __restrict__ h1b, const float* __restrict__ as1,
    const float* __restrict__ ad1, const float* __restrict__ b1,
    const int* __restrict__ row_ptr, const int* __restrict__ col,
    float* __restrict__ x2) {
  int n = blockIdx.x;
  int tid = threadIdx.x;
  int slot = tid >> 4;        // 0..15
  int lane16 = tid & 15;      // channel group: ch = lane16*8 .. +7
  int head = lane16 >> 2;
  int start = row_ptr[n];
  int deg = row_ptr[n + 1] - start;
  __shared__ float sred[16][4];
  __shared__ float sinv[4];
  // phase A: per-head sum of exp (no max subtraction; e in ~[-1,4])
  if (lane16 < 4) {
    float adl = ad1[n * 4 + lane16];
    float part = 0.f;
    for (int i = slot; i <= deg; i += 16) {
      int src = (i < deg) ? col[start + i] : n;
      part += __expf(lrelu(as1[src * 4 + lane16] + adl));
    }
    sred[slot][lane16] = part;
  }
  __syncthreads();
  if (tid < 4) {
    float s = 0.f;
#pragma unroll
    for (int k = 0; k < 16; k++) s += sred[k][tid];
    sinv[tid] = 1.f / (s + 1e-16f);
  }
  __syncthreads();
  float rsh = sinv[head];
  float adh = ad1[n * 4 + head];
  // phase B: weighted gather (as1/col loads are L1-warm from phase A)
  float4 accA = make_float4(0.f, 0.f, 0.f, 0.f);
  float4 accB = make_float4(0.f, 0.f, 0.f, 0.f);
  for (int i = slot; i <= deg; i += 16) {
    int src = (i < deg) ? col[start + i] : n;
    float w = __expf(lrelu(as1[src * 4 + head] + adh)) * rsh;
    uint4 u = *(const uint4*)(h1b + (size_t)src * F1 + lane16 * 8);
    accA.x += w * bflo(u.x); accA.y += w * bfhi(u.x);
    accA.z += w * bflo(u.y); accA.w += w * bfhi(u.y);
    accB.x += w * bflo(u.z); accB.y += w * bfhi(u.z);
    accB.z += w * bflo(u.w); accB.w += w * bfhi(u.w);
  }
  __shared__ float red[16][132];
  *(float4*)&red[slot][lane16 * 8] = accA;
  *(float4*)&red[slot][lane16 * 8 + 4] = accB;
  __syncthreads();
  if (tid < F1) {
    float v = 0.f;
#pragma unroll
    for (int s = 0; s < 16; s++) v += red[s][tid];
    v = fmaxf(v + b1[tid], 0.f);
    x2[(size_t)n * F1 + tid] = v;
  }
}

// ---------------- GEMM2 tiled + alpha2 fused: h2b = x2@W2 (bf16), as2/ad2 ----------------
// 64 rows/block, 256 thr: thread = (row = tid>>2, col chunk = (tid&3)*10)
__global__ __launch_bounds__(256) void gemm2_kernel(
    const float* __restrict__ x2, const float* __restrict__ W2,
    const float* __restrict__ asv, const float* __restrict__ adv,
    unsigned short* __restrict__ h2b, float* __restrict__ as2, float* __restrict__ ad2) {
  __shared__ float xs[64][132];
  __shared__ float W2s[128][44];
  __shared__ float asv_s[40], adv_s[40];
  int tid = threadIdx.x;
  int bm = blockIdx.x * 64;
  // stage x2 tile: 64 rows x 128 = 2048 float4 / 256 thr = 8 each
#pragma unroll
  for (int l = 0; l < 8; l++) {
    int idx = tid + l * 256;
    int r = idx >> 5;
    int c4 = (idx & 31) << 2;
    float4 v = make_float4(0.f, 0.f, 0.f, 0.f);
    if (bm + r < N_NODES) v = *(const float4*)&x2[(size_t)(bm + r) * F1 + c4];
    *(float4*)&xs[r][c4] = v;
  }
  // stage W2: 128x40 = 1280 float4 / 256 = 5 each
#pragma unroll
  for (int l = 0; l < 5; l++) {
    int idx = tid + l * 256;
    int k = idx / 10;
    int c4 = (idx - k * 10) * 4;
    *(float4*)&W2s[k][c4] = *(const float4*)&W2[k * OUT_DIM + c4];
  }
  if (tid < OUT_DIM) { asv_s[tid] = asv[tid]; adv_s[tid] = adv[tid]; }
  __syncthreads();
  int r = tid >> 2;
  int cb = (tid & 3) * 10;
  float acc[10] = {0.f};
  for (int k = 0; k < F1; k++) {
    float xv = xs[r][k];
#pragma unroll
    for (int c = 0; c < 10; c++) acc[c] += xv * W2s[k][cb + c];
  }
  int grow = bm + r;
  float sa = 0.f, sd = 0.f;
#pragma unroll
  for (int c = 0; c < 10; c++) {
    sa += acc[c] * asv_s[cb + c];
    sd += acc[c] * adv_s[cb + c];
  }
#pragma unroll
  for (int off = 1; off < 4; off <<= 1) {
    sa += __shfl_xor(sa, off);
    sd += __shfl_xor(sd, off);
  }
  if (grow < N_NODES) {
#pragma unroll
    for (int c = 0; c < 10; c += 2) {
      unsigned int p = ((unsigned int)f2bf(acc[c + 1]) << 16) | f2bf(acc[c]);
      *(unsigned int*)&h2b[(size_t)grow * OUT_DIM + cb + c] = p;
    }
    if ((tid & 3) == 0) { as2[grow] = sa; ad2[grow] = sd; }
  }
}

// ---------------- layer-2: fused softmax-sum + gather + log_softmax ----------------
// 256 thr; phase B: 4 waves x 12 edge-slots x 5 lanes (16B bf16x8, row=80B)
__global__ __launch_bounds__(256) void gather2_kernel(
    const unsigned short* __restrict__ h2b, const float* __restrict__ as2,
    const float* __restrict__ ad2, const float* __restrict__ b2,
    const int* __restrict__ row_ptr, const int* __restrict__ col,
    float* __restrict__ out) {
  int n = blockIdx.x;
  int tid = threadIdx.x;
  int start = row_ptr[n];
  int deg = row_ptr[n + 1] - start;
  float adh = ad2[n];
  __shared__ float wred[4];
  __shared__ float sinv;
  // phase A: sum of exp over all edges + self
  float part = 0.f;
  for (int i = tid; i <= deg; i += 256) {
    int src = (i < deg) ? col[start + i] : n;
    part += __expf(lrelu(as2[src] + adh));
  }
#pragma unroll
  for (int off = 32; off > 0; off >>= 1) part += __shfl_xor(part, off);
  if ((tid & 63) == 0) wred[tid >> 6] = part;
  __syncthreads();
  if (tid == 0) sinv = 1.f / (wred[0] + wred[1] + wred[2] + wred[3] + 1e-16f);
  __syncthreads();
  float rs = sinv;
  int w = tid >> 6;
  int lane = tid & 63;
  int e_loc = lane / 5;       // 0..12 (12 = idle lanes 60..63)
  int c = lane - e_loc * 5;   // 0..4, channels c*8..c*8+7
  float4 accA = make_float4(0.f, 0.f, 0.f, 0.f);
  float4 accB = make_float4(0.f, 0.f, 0.f, 0.f);
  int slot = w * 12 + e_loc;  // 0..47
  if (e_loc < 12) {
    for (int i = slot; i <= deg; i += 48) {
      int src = (i < deg) ? col[start + i] : n;
      float wgt = __expf(lrelu(as2[src] + adh)) * rs;
      uint4 u = *(const uint4*)(h2b + (size_t)src * OUT_DIM + c * 8);
      accA.x += wgt * bflo(u.x); accA.y += wgt * bfhi(u.x);
      accA.z += wgt * bflo(u.y); accA.w += wgt * bfhi(u.y);
      accB.x += wgt * bflo(u.z); accB.y += wgt * bfhi(u.z);
      accB.z += wgt * bflo(u.w); accB.w += wgt * bfhi(u.w);
    }
  }
  __shared__ float red[48][44];
  if (e_loc < 12) {
    *(float4*)&red[slot][c * 8] = accA;
    *(float4*)&red[slot][c * 8 + 4] = accB;
  }
  __syncthreads();
  if (tid < 64) {
    float val = 0.f;
    if (tid < OUT_DIM) {
#pragma unroll
      for (int s = 0; s < 48; s++) val += red[s][tid];
      val += b2[tid];
    } else {
      val = -1e30f;
    }
    float mx = val;
#pragma unroll
    for (int off = 32; off > 0; off >>= 1) mx = fmaxf(mx, __shfl_xor(mx, off));
    float ex = (tid < OUT_DIM) ? __expf(val - mx) : 0.f;
    float sum = ex;
#pragma unroll
    for (int off = 32; off > 0; off >>= 1) sum += __shfl_xor(sum, off);
    if (tid < OUT_DIM) out[(size_t)n * OUT_DIM + tid] = val - mx - __logf(sum);
  }
}

extern "C" void kernel_launch(void* const* d_in, const int* in_sizes, int n_in,
                              void* d_out, int out_size, void* d_ws, size_t ws_size,
                              hipStream_t stream) {
  const float* x      = (const float*)d_in[0];
  const int*   ei     = (const int*)d_in[1];
  const float* W1     = (const float*)d_in[2];
  const float* a_src1 = (const float*)d_in[3];
  const float* a_dst1 = (const float*)d_in[4];
  const float* b1     = (const float*)d_in[5];
  const float* W2     = (const float*)d_in[6];
  const float* a_src2 = (const float*)d_in[7];
  const float* a_dst2 = (const float*)d_in[8];
  const float* b2     = (const float*)d_in[9];
  float* out = (float*)d_out;

  char* ws = (char*)d_ws;
  size_t off = 0;
  auto alloc = [&](size_t bytes) -> void* {
    void* p = ws + off;
    off += (bytes + 255) & ~(size_t)255;
    return p;
  };
  unsigned short* h1b = (unsigned short*)alloc((size_t)N_NODES * F1 * 2);       // 12.8 MB
  unsigned short* h2b = (unsigned short*)alloc((size_t)N_NODES * OUT_DIM * 2);  // 4 MB
  float* as1    = (float*)alloc((size_t)N_NODES * HEADS * 4);
  float* ad1    = (float*)alloc((size_t)N_NODES * HEADS * 4);
  float* x2     = (float*)alloc((size_t)N_NODES * F1 * 4);
  float* as2    = (float*)alloc((size_t)N_NODES * 4);
  float* ad2    = (float*)alloc((size_t)N_NODES * 4);
  int* row_ptr  = (int*)alloc((size_t)(N_NODES + 1) * 4);
  int* cursor   = (int*)alloc((size_t)N_NODES * 4);
  int* cnt      = (int*)alloc((size_t)N_NODES * 4);
  int* blk_sum  = (int*)alloc((size_t)SCAN_NBLK * 4);
  int* blk_off  = (int*)alloc((size_t)SCAN_NBLK * 4);
  int* col      = (int*)alloc((size_t)N_EDGES * 4);

  hipMemsetAsync(cnt, 0, (size_t)N_NODES * 4, stream);
  hist_kernel<<<(N_EDGES + 255) / 256, 256, 0, stream>>>(ei, cnt);
  blksum_kernel<<<SCAN_NBLK, 256, 0, stream>>>(cnt, blk_sum);
  blkscan_kernel<<<1, 256, 0, stream>>>(blk_sum, blk_off, row_ptr);
  finalscan_kernel<<<SCAN_NBLK, 256, 0, stream>>>(cnt, blk_off, row_ptr, cursor);
  scatter_kernel<<<(N_EDGES + 255) / 256, 256, 0, stream>>>(ei, cursor, col);

  gemm1_kernel<<<dim3((N_NODES + BM - 1) / BM, F1 / BN), 256, 0, stream>>>(
      x, W1, a_src1, a_dst1, h1b, as1, ad1);
  gather1_kernel<<<N_NODES, 256, 0, stream>>>(h1b, as1, ad1, b1, row_ptr, col, x2);

  gemm2_kernel<<<(N_NODES + 63) / 64, 256, 0, stream>>>(x2, W2, a_src2, a_dst2, h2b, as2, ad2);
  gather2_kernel<<<N_NODES, 256, 0, stream>>>(h2b, as2, ad2, b2, row_ptr, col, out);
}

// Round 8
// 349.588 us; speedup vs baseline: 1.8305x; 1.1695x over previous
//
#include <hip/hip_runtime.h>
#include <math.h>

#define N_NODES 50000
#define N_EDGES 800000
#define IN_DIM  256
#define F1      128   // HEADS*HID
#define HEADS   4
#define OUT_DIM 40
#define NEG     0.2f

#define SCAN_CHUNK 256
#define SCAN_NBLK  ((N_NODES + SCAN_CHUNK - 1) / SCAN_CHUNK)   // 196

// ---- bf16 helpers (RNE pack, shift unpack) ----
__device__ __forceinline__ unsigned short f2bf(float f) {
  unsigned int u = __float_as_uint(f);
  u += 0x7FFF + ((u >> 16) & 1);
  return (unsigned short)(u >> 16);
}
__device__ __forceinline__ float bflo(unsigned int u) { return __uint_as_float(u << 16); }
__device__ __forceinline__ float bfhi(unsigned int u) { return __uint_as_float(u & 0xffff0000u); }

__device__ __forceinline__ float lrelu(float e) { return e > 0.f ? e : e * NEG; }

// ---------------- CSR build (by destination) ----------------
__global__ void hist_kernel(const int* __restrict__ ei, int* __restrict__ cnt) {
  int i = blockIdx.x * blockDim.x + threadIdx.x;
  if (i < N_EDGES) atomicAdd(&cnt[ei[N_EDGES + i]], 1);
}

__global__ __launch_bounds__(256) void blksum_kernel(const int* __restrict__ cnt,
                                                     int* __restrict__ blk_sum) {
  __shared__ int lds[256];
  int b = blockIdx.x;
  int tid = threadIdx.x;
  int i = b * SCAN_CHUNK + tid;
  lds[tid] = (i < N_NODES) ? cnt[i] : 0;
  __syncthreads();
#pragma unroll
  for (int off = 128; off > 0; off >>= 1) {
    if (tid < off) lds[tid] += lds[tid + off];
    __syncthreads();
  }
  if (tid == 0) blk_sum[b] = lds[0];
}

__global__ __launch_bounds__(256) void blkscan_kernel(const int* __restrict__ blk_sum,
                                                      int* __restrict__ blk_off,
                                                      int* __restrict__ row_ptr) {
  __shared__ int lds[256];
  int tid = threadIdx.x;
  int v = (tid < SCAN_NBLK) ? blk_sum[tid] : 0;
  lds[tid] = v;
  __syncthreads();
#pragma unroll
  for (int off = 1; off < 256; off <<= 1) {
    int t = (tid >= off) ? lds[tid - off] : 0;
    __syncthreads();
    lds[tid] += t;
    __syncthreads();
  }
  if (tid < SCAN_NBLK) blk_off[tid] = lds[tid] - v;
  if (tid == 255) row_ptr[N_NODES] = lds[255];
}

__global__ __launch_bounds__(256) void finalscan_kernel(const int* __restrict__ cnt,
                                                        const int* __restrict__ blk_off,
                                                        int* __restrict__ row_ptr,
                                                        int* __restrict__ cursor) {
  __shared__ int lds[256];
  int b = blockIdx.x;
  int tid = threadIdx.x;
  int i = b * SCAN_CHUNK + tid;
  int v = (i < N_NODES) ? cnt[i] : 0;
  lds[tid] = v;
  __syncthreads();
#pragma unroll
  for (int off = 1; off < 256; off <<= 1) {
    int t = (tid >= off) ? lds[tid - off] : 0;
    __syncthreads();
    lds[tid] += t;
    __syncthreads();
  }
  if (i < N_NODES) {
    int excl = lds[tid] - v + blk_off[b];
    row_ptr[i] = excl;
    cursor[i] = excl;
  }
}

__global__ void scatter_kernel(const int* __restrict__ ei, int* __restrict__ cursor,
                               int* __restrict__ col) {
  int i = blockIdx.x * blockDim.x + threadIdx.x;
  if (i < N_EDGES) {
    int d = ei[N_EDGES + i];
    int p = atomicAdd(&cursor[d], 1);
    col[p] = ei[i];
  }
}

// ---------------- GEMM1 + alpha1 fused: h1b = x@W1 (bf16), as1/ad1 ----------------
#define BM 64
#define BN 64
#define BK 32

__global__ __launch_bounds__(256) void gemm1_kernel(
    const float* __restrict__ A, const float* __restrict__ B,
    const float* __restrict__ a_src, const float* __restrict__ a_dst,
    unsigned short* __restrict__ Cb, float* __restrict__ as1, float* __restrict__ ad1) {
  __shared__ float As[BK][BM + 4];
  __shared__ float Bs[BK][BN + 4];
  int tid = threadIdx.x;
  int bm = blockIdx.x * BM;
  int bn = blockIdx.y * BN;
  int tx = tid & 15;
  int ty = tid >> 4;
  float acc[4][4] = {{0.f}};
  for (int k0 = 0; k0 < IN_DIM; k0 += BK) {
#pragma unroll
    for (int l = 0; l < 2; l++) {
      int idx = tid + l * 256;
      int r = idx >> 3;
      int c4 = (idx & 7) << 2;
      int grow = bm + r;
      float4 v = make_float4(0.f, 0.f, 0.f, 0.f);
      if (grow < N_NODES) v = *(const float4*)&A[(size_t)grow * IN_DIM + k0 + c4];
      As[c4 + 0][r] = v.x;
      As[c4 + 1][r] = v.y;
      As[c4 + 2][r] = v.z;
      As[c4 + 3][r] = v.w;
    }
#pragma unroll
    for (int l = 0; l < 2; l++) {
      int idx = tid + l * 256;
      int r = idx >> 4;
      int c4 = (idx & 15) << 2;
      *(float4*)&Bs[r][c4] = *(const float4*)&B[(size_t)(k0 + r) * F1 + bn + c4];
    }
    __syncthreads();
#pragma unroll
    for (int kk = 0; kk < BK; kk++) {
      float a[4], b[4];
      *(float4*)a = *(const float4*)&As[kk][ty * 4];
      *(float4*)b = *(const float4*)&Bs[kk][tx * 4];
#pragma unroll
      for (int i = 0; i < 4; i++)
#pragma unroll
        for (int j = 0; j < 4; j++)
          acc[i][j] += a[i] * b[j];
    }
    __syncthreads();
  }
  // write bf16 h1
#pragma unroll
  for (int i = 0; i < 4; i++) {
    int grow = bm + ty * 4 + i;
    if (grow < N_NODES) {
      unsigned int p0 = ((unsigned int)f2bf(acc[i][1]) << 16) | f2bf(acc[i][0]);
      unsigned int p1 = ((unsigned int)f2bf(acc[i][3]) << 16) | f2bf(acc[i][2]);
      *(uint2*)&Cb[(size_t)grow * F1 + bn + tx * 4] = make_uint2(p0, p1);
    }
  }
  // fused alpha: this block covers 2 whole heads (bn=0 -> heads 0,1; bn=64 -> 2,3)
  int head = (bn >> 5) + (tx >> 3);
  int cb = (tx & 7) * 4;   // within-head channel offset
  float asr[4], adr[4];
#pragma unroll
  for (int j = 0; j < 4; j++) {
    asr[j] = a_src[head * 32 + cb + j];
    adr[j] = a_dst[head * 32 + cb + j];
  }
#pragma unroll
  for (int i = 0; i < 4; i++) {
    float sa = acc[i][0] * asr[0] + acc[i][1] * asr[1] + acc[i][2] * asr[2] + acc[i][3] * asr[3];
    float sd = acc[i][0] * adr[0] + acc[i][1] * adr[1] + acc[i][2] * adr[2] + acc[i][3] * adr[3];
#pragma unroll
    for (int off = 1; off < 8; off <<= 1) {
      sa += __shfl_xor(sa, off);
      sd += __shfl_xor(sd, off);
    }
    int grow = bm + ty * 4 + i;
    if ((tx & 7) == 0 && grow < N_NODES) {
      as1[grow * 4 + head] = sa;
      ad1[grow * 4 + head] = sd;
    }
  }
}

// ---------------- layer-1: wave-per-node fused softmax-sum + gather ----------------
// 64 lanes/node: phase A all lanes; phase B 4 edge-slots x 16 channel-lanes (16B loads)
__global__ __launch_bounds__(256) void gather1_kernel(
    const unsigned short* __restrict__ h1b, const float* __restrict__ as1,
    const float* __restrict__ ad1, const float* __restrict__ b1,
    const int* __restrict__ row_ptr, const int* __restrict__ col,
    float* __restrict__ x2) {
  int n = blockIdx.x * 4 + (threadIdx.x >> 6);
  if (n >= N_NODES) return;
  int lane = threadIdx.x & 63;
  int start = row_ptr[n];
  int deg = row_ptr[n + 1] - start;
  float4 ad = *(const float4*)&ad1[n * 4];
  // phase A: sum of exp per head (no max subtraction: e bounded ~[-1,4])
  float s0 = 0.f, s1 = 0.f, s2 = 0.f, s3 = 0.f;
  for (int i = lane; i <= deg; i += 64) {
    int src = (i < deg) ? col[start + i] : n;
    float4 as = *(const float4*)&as1[src * 4];
    s0 += __expf(lrelu(as.x + ad.x));
    s1 += __expf(lrelu(as.y + ad.y));
    s2 += __expf(lrelu(as.z + ad.z));
    s3 += __expf(lrelu(as.w + ad.w));
  }
#pragma unroll
  for (int off = 32; off > 0; off >>= 1) {
    s0 += __shfl_xor(s0, off);
    s1 += __shfl_xor(s1, off);
    s2 += __shfl_xor(s2, off);
    s3 += __shfl_xor(s3, off);
  }
  int slot = lane >> 4;    // 0..3
  int lane16 = lane & 15;  // channels lane16*8 .. +7
  int head = lane16 >> 2;
  float rsh = (head == 0) ? s0 : (head == 1) ? s1 : (head == 2) ? s2 : s3;
  rsh = 1.f / (rsh + 1e-16f);
  float adh = (head == 0) ? ad.x : (head == 1) ? ad.y : (head == 2) ? ad.z : ad.w;
  // phase B: weighted gather (col/as1 L1-warm from phase A)
  float4 accA = make_float4(0.f, 0.f, 0.f, 0.f);
  float4 accB = make_float4(0.f, 0.f, 0.f, 0.f);
  for (int i = slot; i <= deg; i += 4) {
    int src = (i < deg) ? col[start + i] : n;
    float w = __expf(lrelu(as1[src * 4 + head] + adh)) * rsh;
    uint4 u = *(const uint4*)(h1b + (size_t)src * F1 + lane16 * 8);
    accA.x += w * bflo(u.x); accA.y += w * bfhi(u.x);
    accA.z += w * bflo(u.y); accA.w += w * bfhi(u.y);
    accB.x += w * bflo(u.z); accB.y += w * bfhi(u.z);
    accB.z += w * bflo(u.w); accB.w += w * bfhi(u.w);
  }
  // cross-slot reduce: slot bits are lane bits 4,5 (clean xor butterfly)
#pragma unroll
  for (int off = 16; off <= 32; off <<= 1) {
    accA.x += __shfl_xor(accA.x, off); accA.y += __shfl_xor(accA.y, off);
    accA.z += __shfl_xor(accA.z, off); accA.w += __shfl_xor(accA.w, off);
    accB.x += __shfl_xor(accB.x, off); accB.y += __shfl_xor(accB.y, off);
    accB.z += __shfl_xor(accB.z, off); accB.w += __shfl_xor(accB.w, off);
  }
  if (slot == 0) {
    float4 bA = *(const float4*)&b1[lane16 * 8];
    float4 bB = *(const float4*)&b1[lane16 * 8 + 4];
    float4 oA, oB;
    oA.x = fmaxf(accA.x + bA.x, 0.f); oA.y = fmaxf(accA.y + bA.y, 0.f);
    oA.z = fmaxf(accA.z + bA.z, 0.f); oA.w = fmaxf(accA.w + bA.w, 0.f);
    oB.x = fmaxf(accB.x + bB.x, 0.f); oB.y = fmaxf(accB.y + bB.y, 0.f);
    oB.z = fmaxf(accB.z + bB.z, 0.f); oB.w = fmaxf(accB.w + bB.w, 0.f);
    *(float4*)&x2[(size_t)n * F1 + lane16 * 8] = oA;
    *(float4*)&x2[(size_t)n * F1 + lane16 * 8 + 4] = oB;
  }
}

// ---------------- GEMM2 tiled + alpha2 fused: h2b = x2@W2 (bf16), as2/ad2 ----------------
__global__ __launch_bounds__(256) void gemm2_kernel(
    const float* __restrict__ x2, const float* __restrict__ W2,
    const float* __restrict__ asv, const float* __restrict__ adv,
    unsigned short* __restrict__ h2b, float* __restrict__ as2, float* __restrict__ ad2) {
  __shared__ float xs[64][132];
  __shared__ float W2s[128][44];
  __shared__ float asv_s[40], adv_s[40];
  int tid = threadIdx.x;
  int bm = blockIdx.x * 64;
#pragma unroll
  for (int l = 0; l < 8; l++) {
    int idx = tid + l * 256;
    int r = idx >> 5;
    int c4 = (idx & 31) << 2;
    float4 v = make_float4(0.f, 0.f, 0.f, 0.f);
    if (bm + r < N_NODES) v = *(const float4*)&x2[(size_t)(bm + r) * F1 + c4];
    *(float4*)&xs[r][c4] = v;
  }
#pragma unroll
  for (int l = 0; l < 5; l++) {
    int idx = tid + l * 256;
    int k = idx / 10;
    int c4 = (idx - k * 10) * 4;
    *(float4*)&W2s[k][c4] = *(const float4*)&W2[k * OUT_DIM + c4];
  }
  if (tid < OUT_DIM) { asv_s[tid] = asv[tid]; adv_s[tid] = adv[tid]; }
  __syncthreads();
  int r = tid >> 2;
  int cb = (tid & 3) * 10;
  float acc[10] = {0.f};
  for (int k = 0; k < F1; k++) {
    float xv = xs[r][k];
#pragma unroll
    for (int c = 0; c < 10; c++) acc[c] += xv * W2s[k][cb + c];
  }
  int grow = bm + r;
  float sa = 0.f, sd = 0.f;
#pragma unroll
  for (int c = 0; c < 10; c++) {
    sa += acc[c] * asv_s[cb + c];
    sd += acc[c] * adv_s[cb + c];
  }
#pragma unroll
  for (int off = 1; off < 4; off <<= 1) {
    sa += __shfl_xor(sa, off);
    sd += __shfl_xor(sd, off);
  }
  if (grow < N_NODES) {
#pragma unroll
    for (int c = 0; c < 10; c += 2) {
      unsigned int p = ((unsigned int)f2bf(acc[c + 1]) << 16) | f2bf(acc[c]);
      *(unsigned int*)&h2b[(size_t)grow * OUT_DIM + cb + c] = p;
    }
    if ((tid & 3) == 0) { as2[grow] = sa; ad2[grow] = sd; }
  }
}

// ---------------- layer-2: wave-per-node fused softmax + gather + log_softmax ----------------
// phase B: 12 edge-slots x 5 channel-lanes (16B bf16x8, row=80B); lanes 60..63 idle
__global__ __launch_bounds__(256) void gather2_kernel(
    const unsigned short* __restrict__ h2b, const float* __restrict__ as2,
    const float* __restrict__ ad2, const float* __restrict__ b2,
    const int* __restrict__ row_ptr, const int* __restrict__ col,
    float* __restrict__ out) {
  int n = blockIdx.x * 4 + (threadIdx.x >> 6);
  if (n >= N_NODES) return;
  int lane = threadIdx.x & 63;
  int start = row_ptr[n];
  int deg = row_ptr[n + 1] - start;
  float adh = ad2[n];
  // phase A: sum of exp
  float part = 0.f;
  for (int i = lane; i <= deg; i += 64) {
    int src = (i < deg) ? col[start + i] : n;
    part += __expf(lrelu(as2[src] + adh));
  }
#pragma unroll
  for (int off = 32; off > 0; off >>= 1) part += __shfl_xor(part, off);
  float rs = 1.f / (part + 1e-16f);
  // phase B
  int slot = lane / 5;        // 0..12 (>=12 idle)
  int c = lane - slot * 5;    // 0..4, channels c*8..+7
  float4 accA = make_float4(0.f, 0.f, 0.f, 0.f);
  float4 accB = make_float4(0.f, 0.f, 0.f, 0.f);
  if (slot < 12) {
    for (int i = slot; i <= deg; i += 12) {
      int src = (i < deg) ? col[start + i] : n;
      float wgt = __expf(lrelu(as2[src] + adh)) * rs;
      uint4 u = *(const uint4*)(h2b + (size_t)src * OUT_DIM + c * 8);
      accA.x += wgt * bflo(u.x); accA.y += wgt * bfhi(u.x);
      accA.z += wgt * bflo(u.y); accA.w += wgt * bfhi(u.y);
      accB.x += wgt * bflo(u.z); accB.y += wgt * bfhi(u.z);
      accB.z += wgt * bflo(u.w); accB.w += wgt * bfhi(u.w);
    }
  }
  // cross-slot reduce (12 slots, 5 lanes each).
  // step1 (+30): slot s += slot s+6   -> slots 0..5 hold pair sums
  // step2 (+15): slot s += slot s+3   -> slots 0..2 hold quad sums
  // step3: read BOTH slot1 (+5) and slot2 (+10) into temps BEFORE updating,
  //        then v += t1 + t2. (Sequential +5 then +10 is WRONG: the +5 step
  //        modifies slot2 before +10 reads it -- R7's correctness bug.)
  {
    float v[8] = {accA.x, accA.y, accA.z, accA.w, accB.x, accB.y, accB.z, accB.w};
#pragma unroll
    for (int k = 0; k < 8; k++) v[k] += __shfl(v[k], lane + 30);
#pragma unroll
    for (int k = 0; k < 8; k++) v[k] += __shfl(v[k], lane + 15);
    float t1[8], t2[8];
#pragma unroll
    for (int k = 0; k < 8; k++) t1[k] = __shfl(v[k], lane + 5);
#pragma unroll
    for (int k = 0; k < 8; k++) t2[k] = __shfl(v[k], lane + 10);
#pragma unroll
    for (int k = 0; k < 8; k++) v[k] += t1[k] + t2[k];
    accA.x = v[0]; accA.y = v[1]; accA.z = v[2]; accA.w = v[3];
    accB.x = v[4]; accB.y = v[5]; accB.z = v[6]; accB.w = v[7];
  }
  // lanes 0..4 (slot 0) hold final 8 channels each; log_softmax over 40 via wave butterfly
  bool owner = (slot == 0);   // lanes 0..4
  float vals[8] = {accA.x, accA.y, accA.z, accA.w, accB.x, accB.y, accB.z, accB.w};
  float lmax = -1e30f, lsum = 0.f;
  if (owner) {
#pragma unroll
    for (int k = 0; k < 8; k++) {
      vals[k] += b2[c * 8 + k];
      lmax = fmaxf(lmax, vals[k]);
    }
  }
  float gmax = lmax;
#pragma unroll
  for (int off = 32; off > 0; off >>= 1) gmax = fmaxf(gmax, __shfl_xor(gmax, off));
  if (owner) {
#pragma unroll
    for (int k = 0; k < 8; k++) lsum += __expf(vals[k] - gmax);
  }
#pragma unroll
  for (int off = 32; off > 0; off >>= 1) lsum += __shfl_xor(lsum, off);
  if (owner) {
    float lse = gmax + __logf(lsum);
    float4 oA = make_float4(vals[0] - lse, vals[1] - lse, vals[2] - lse, vals[3] - lse);
    float4 oB = make_float4(vals[4] - lse, vals[5] - lse, vals[6] - lse, vals[7] - lse);
    *(float4*)&out[(size_t)n * OUT_DIM + c * 8] = oA;
    *(float4*)&out[(size_t)n * OUT_DIM + c * 8 + 4] = oB;
  }
}

extern "C" void kernel_launch(void* const* d_in, const int* in_sizes, int n_in,
                              void* d_out, int out_size, void* d_ws, size_t ws_size,
                              hipStream_t stream) {
  const float* x      = (const float*)d_in[0];
  const int*   ei     = (const int*)d_in[1];
  const float* W1     = (const float*)d_in[2];
  const float* a_src1 = (const float*)d_in[3];
  const float* a_dst1 = (const float*)d_in[4];
  const float* b1     = (const float*)d_in[5];
  const float* W2     = (const float*)d_in[6];
  const float* a_src2 = (const float*)d_in[7];
  const float* a_dst2 = (const float*)d_in[8];
  const float* b2     = (const float*)d_in[9];
  float* out = (float*)d_out;

  char* ws = (char*)d_ws;
  size_t off = 0;
  auto alloc = [&](size_t bytes) -> void* {
    void* p = ws + off;
    off += (bytes + 255) & ~(size_t)255;
    return p;
  };
  unsigned short* h1b = (unsigned short*)alloc((size_t)N_NODES * F1 * 2);       // 12.8 MB
  unsigned short* h2b = (unsigned short*)alloc((size_t)N_NODES * OUT_DIM * 2);  // 4 MB
  float* as1    = (float*)alloc((size_t)N_NODES * HEADS * 4);
  float* ad1    = (float*)alloc((size_t)N_NODES * HEADS * 4);
  float* x2     = (float*)alloc((size_t)N_NODES * F1 * 4);
  float* as2    = (float*)alloc((size_t)N_NODES * 4);
  float* ad2    = (float*)alloc((size_t)N_NODES * 4);
  int* row_ptr  = (int*)alloc((size_t)(N_NODES + 1) * 4);
  int* cursor   = (int*)alloc((size_t)N_NODES * 4);
  int* cnt      = (int*)alloc((size_t)N_NODES * 4);
  int* blk_sum  = (int*)alloc((size_t)SCAN_NBLK * 4);
  int* blk_off  = (int*)alloc((size_t)SCAN_NBLK * 4);
  int* col      = (int*)alloc((size_t)N_EDGES * 4);

  hipMemsetAsync(cnt, 0, (size_t)N_NODES * 4, stream);
  hist_kernel<<<(N_EDGES + 255) / 256, 256, 0, stream>>>(ei, cnt);
  blksum_kernel<<<SCAN_NBLK, 256, 0, stream>>>(cnt, blk_sum);
  blkscan_kernel<<<1, 256, 0, stream>>>(blk_sum, blk_off, row_ptr);
  finalscan_kernel<<<SCAN_NBLK, 256, 0, stream>>>(cnt, blk_off, row_ptr, cursor);
  scatter_kernel<<<(N_EDGES + 255) / 256, 256, 0, stream>>>(ei, cursor, col);

  gemm1_kernel<<<dim3((N_NODES + BM - 1) / BM, F1 / BN), 256, 0, stream>>>(
      x, W1, a_src1, a_dst1, h1b, as1, ad1);
  gather1_kernel<<<(N_NODES + 3) / 4, 256, 0, stream>>>(h1b, as1, ad1, b1, row_ptr, col, x2);

  gemm2_kernel<<<(N_NODES + 63) / 64, 256, 0, stream>>>(x2, W2, a_src2, a_dst2, h2b, as2, ad2);
  gather2_kernel<<<(N_NODES + 3) / 4, 256, 0, stream>>>(h2b, as2, ad2, b2, row_ptr, col, out);
}

// Round 9
// 335.271 us; speedup vs baseline: 1.9086x; 1.0427x over previous
//
#include <hip/hip_runtime.h>
#include <math.h>

#define N_NODES 50000
#define N_EDGES 800000
#define IN_DIM  256
#define F1      128   // HEADS*HID
#define HEADS   4
#define OUT_DIM 40
#define NEG     0.2f

#define SCAN_CHUNK 256
#define SCAN_NBLK  ((N_NODES + SCAN_CHUNK - 1) / SCAN_CHUNK)   // 196

typedef __attribute__((ext_vector_type(8))) short short8;    // 8 bf16 in 4 VGPRs
typedef __attribute__((ext_vector_type(4))) float float4v;   // MFMA C/D

// ---- bf16 helpers (RNE pack, shift unpack) ----
__device__ __forceinline__ unsigned short f2bf(float f) {
  unsigned int u = __float_as_uint(f);
  u += 0x7FFF + ((u >> 16) & 1);
  return (unsigned short)(u >> 16);
}
__device__ __forceinline__ float bf2f(unsigned short h) {
  return __uint_as_float((unsigned int)h << 16);
}
__device__ __forceinline__ float bflo(unsigned int u) { return __uint_as_float(u << 16); }
__device__ __forceinline__ float bfhi(unsigned int u) { return __uint_as_float(u & 0xffff0000u); }

__device__ __forceinline__ float lrelu(float e) { return e > 0.f ? e : e * NEG; }

// ---------------- CSR build (by destination) ----------------
__global__ void hist_kernel(const int* __restrict__ ei, int* __restrict__ cnt) {
  int i = blockIdx.x * blockDim.x + threadIdx.x;
  if (i < N_EDGES) atomicAdd(&cnt[ei[N_EDGES + i]], 1);
}

__global__ __launch_bounds__(256) void blksum_kernel(const int* __restrict__ cnt,
                                                     int* __restrict__ blk_sum) {
  __shared__ int lds[256];
  int b = blockIdx.x;
  int tid = threadIdx.x;
  int i = b * SCAN_CHUNK + tid;
  lds[tid] = (i < N_NODES) ? cnt[i] : 0;
  __syncthreads();
#pragma unroll
  for (int off = 128; off > 0; off >>= 1) {
    if (tid < off) lds[tid] += lds[tid + off];
    __syncthreads();
  }
  if (tid == 0) blk_sum[b] = lds[0];
}

__global__ __launch_bounds__(256) void blkscan_kernel(const int* __restrict__ blk_sum,
                                                      int* __restrict__ blk_off,
                                                      int* __restrict__ row_ptr) {
  __shared__ int lds[256];
  int tid = threadIdx.x;
  int v = (tid < SCAN_NBLK) ? blk_sum[tid] : 0;
  lds[tid] = v;
  __syncthreads();
#pragma unroll
  for (int off = 1; off < 256; off <<= 1) {
    int t = (tid >= off) ? lds[tid - off] : 0;
    __syncthreads();
    lds[tid] += t;
    __syncthreads();
  }
  if (tid < SCAN_NBLK) blk_off[tid] = lds[tid] - v;
  if (tid == 255) row_ptr[N_NODES] = lds[255];
}

__global__ __launch_bounds__(256) void finalscan_kernel(const int* __restrict__ cnt,
                                                        const int* __restrict__ blk_off,
                                                        int* __restrict__ row_ptr,
                                                        int* __restrict__ cursor) {
  __shared__ int lds[256];
  int b = blockIdx.x;
  int tid = threadIdx.x;
  int i = b * SCAN_CHUNK + tid;
  int v = (i < N_NODES) ? cnt[i] : 0;
  lds[tid] = v;
  __syncthreads();
#pragma unroll
  for (int off = 1; off < 256; off <<= 1) {
    int t = (tid >= off) ? lds[tid - off] : 0;
    __syncthreads();
    lds[tid] += t;
    __syncthreads();
  }
  if (i < N_NODES) {
    int excl = lds[tid] - v + blk_off[b];
    row_ptr[i] = excl;
    cursor[i] = excl;
  }
}

__global__ void scatter_kernel(const int* __restrict__ ei, int* __restrict__ cursor,
                               int* __restrict__ col) {
  int i = blockIdx.x * blockDim.x + threadIdx.x;
  if (i < N_EDGES) {
    int d = ei[N_EDGES + i];
    int p = atomicAdd(&cursor[d], 1);
    col[p] = ei[i];
  }
}

// ---------------- W1 -> MFMA B-fragment packing (hi/lo split) ----------------
// frag index: ((kk*8 + t)*64 + lane)*8 + j  holds W1[kk*32 + (lane>>4)*8 + j][t*16 + (lane&15)]
__global__ __launch_bounds__(256) void w1pack_kernel(const float* __restrict__ W1,
                                                     unsigned short* __restrict__ wHi,
                                                     unsigned short* __restrict__ wLo) {
  int tid = blockIdx.x * 256 + threadIdx.x;   // 0..4095
  int kk = tid >> 9;
  int rest = tid & 511;
  int t = rest >> 6;
  int lane = rest & 63;
  int q = lane >> 4;
  int ln = lane & 15;
  int n = t * 16 + ln;
  unsigned int hi[4], lo[4];
#pragma unroll
  for (int jj = 0; jj < 4; jj++) {
    unsigned short h0, h1, l0, l1;
    {
      float v = W1[(kk * 32 + q * 8 + jj * 2) * F1 + n];
      h0 = f2bf(v); l0 = f2bf(v - bf2f(h0));
    }
    {
      float v = W1[(kk * 32 + q * 8 + jj * 2 + 1) * F1 + n];
      h1 = f2bf(v); l1 = f2bf(v - bf2f(h1));
    }
    hi[jj] = (unsigned int)h0 | ((unsigned int)h1 << 16);
    lo[jj] = (unsigned int)l0 | ((unsigned int)l1 << 16);
  }
  size_t base = (size_t)tid * 8;   // == ((kk*8+t)*64 + lane)*8
  *(uint4*)&wHi[base] = make_uint4(hi[0], hi[1], hi[2], hi[3]);
  *(uint4*)&wLo[base] = make_uint4(lo[0], lo[1], lo[2], lo[3]);
}

// ---------------- GEMM1 via bf16 MFMA (split precision) + fused alpha1 ----------------
// 782 blocks x 4 waves; wave = 16 rows x 128 cols; K handled in 8 steps of 32.
__global__ __launch_bounds__(256) void gemm1_mfma_kernel(
    const float* __restrict__ x, const unsigned short* __restrict__ wHi,
    const unsigned short* __restrict__ wLo,
    const float* __restrict__ a_src, const float* __restrict__ a_dst,
    unsigned short* __restrict__ h1b, float* __restrict__ as1, float* __restrict__ ad1) {
  int tid = threadIdx.x;
  int w = tid >> 6;
  int lane = tid & 63;
  int q = lane >> 4;
  int ln = lane & 15;
  int rowBase = blockIdx.x * 64 + w * 16;
  int rowA = rowBase + ln;
  int rowAc = rowA < N_NODES ? rowA : N_NODES - 1;   // clamp; garbage rows never stored
  float4v acc[8];
#pragma unroll
  for (int t = 0; t < 8; t++) acc[t] = (float4v){0.f, 0.f, 0.f, 0.f};
  const short8* bhp = (const short8*)wHi;
  const short8* blp = (const short8*)wLo;
  for (int kk = 0; kk < 8; kk++) {
    const float4* xp = (const float4*)(x + (size_t)rowAc * IN_DIM + kk * 32 + q * 8);
    float4 a0 = xp[0];
    float4 a1 = xp[1];
    float av[8] = {a0.x, a0.y, a0.z, a0.w, a1.x, a1.y, a1.z, a1.w};
    short8 ahi, alo;
#pragma unroll
    for (int j = 0; j < 8; j++) {
      unsigned short h = f2bf(av[j]);
      ahi[j] = (short)h;
      alo[j] = (short)f2bf(av[j] - bf2f(h));
    }
    int fbase = (kk * 8) * 64 + lane;
#pragma unroll
    for (int t = 0; t < 8; t++) {
      short8 bh = bhp[fbase + t * 64];
      short8 bl = blp[fbase + t * 64];
      acc[t] = __builtin_amdgcn_mfma_f32_16x16x32_bf16(ahi, bh, acc[t], 0, 0, 0);
      acc[t] = __builtin_amdgcn_mfma_f32_16x16x32_bf16(ahi, bl, acc[t], 0, 0, 0);
      acc[t] = __builtin_amdgcn_mfma_f32_16x16x32_bf16(alo, bh, acc[t], 0, 0, 0);
    }
  }
  // epilogue: C/D layout col = ln, row = q*4 + reg (verified gfx950 mapping)
  float asv[8], adv[8];
#pragma unroll
  for (int t = 0; t < 8; t++) {
    asv[t] = a_src[t * 16 + ln];
    adv[t] = a_dst[t * 16 + ln];
  }
#pragma unroll
  for (int reg = 0; reg < 4; reg++) {
    int r = rowBase + q * 4 + reg;
    bool valid = (r < N_NODES);
    if (valid) {
#pragma unroll
      for (int t = 0; t < 8; t++)
        h1b[(size_t)r * F1 + t * 16 + ln] = f2bf(acc[t][reg]);
    }
#pragma unroll
    for (int h = 0; h < 4; h++) {
      float sa = acc[2 * h][reg] * asv[2 * h] + acc[2 * h + 1][reg] * asv[2 * h + 1];
      float sd = acc[2 * h][reg] * adv[2 * h] + acc[2 * h + 1][reg] * adv[2 * h + 1];
#pragma unroll
      for (int off = 1; off < 16; off <<= 1) {
        sa += __shfl_xor(sa, off);
        sd += __shfl_xor(sd, off);
      }
      if (ln == 0 && valid) {
        as1[r * 4 + h] = sa;
        ad1[r * 4 + h] = sd;
      }
    }
  }
}

// ---------------- layer-1: wave-per-node fused softmax-sum + gather ----------------
__global__ __launch_bounds__(256) void gather1_kernel(
    const unsigned short* __restrict__ h1b, const float* __restrict__ as1,
    const float* __restrict__ ad1, const float* __restrict__ b1,
    const int* __restrict__ row_ptr, const int* __restrict__ col,
    float* __restrict__ x2) {
  int n = blockIdx.x * 4 + (threadIdx.x >> 6);
  if (n >= N_NODES) return;
  int lane = threadIdx.x & 63;
  int start = row_ptr[n];
  int deg = row_ptr[n + 1] - start;
  float4 ad = *(const float4*)&ad1[n * 4];
  // phase A: sum of exp per head (no max subtraction: e bounded ~[-1,4])
  float s0 = 0.f, s1 = 0.f, s2 = 0.f, s3 = 0.f;
  for (int i = lane; i <= deg; i += 64) {
    int src = (i < deg) ? col[start + i] : n;
    float4 as = *(const float4*)&as1[src * 4];
    s0 += __expf(lrelu(as.x + ad.x));
    s1 += __expf(lrelu(as.y + ad.y));
    s2 += __expf(lrelu(as.z + ad.z));
    s3 += __expf(lrelu(as.w + ad.w));
  }
#pragma unroll
  for (int off = 32; off > 0; off >>= 1) {
    s0 += __shfl_xor(s0, off);
    s1 += __shfl_xor(s1, off);
    s2 += __shfl_xor(s2, off);
    s3 += __shfl_xor(s3, off);
  }
  int slot = lane >> 4;    // 0..3
  int lane16 = lane & 15;  // channels lane16*8 .. +7
  int head = lane16 >> 2;
  float rsh = (head == 0) ? s0 : (head == 1) ? s1 : (head == 2) ? s2 : s3;
  rsh = 1.f / (rsh + 1e-16f);
  float adh = (head == 0) ? ad.x : (head == 1) ? ad.y : (head == 2) ? ad.z : ad.w;
  // phase B: weighted gather
  float4 accA = make_float4(0.f, 0.f, 0.f, 0.f);
  float4 accB = make_float4(0.f, 0.f, 0.f, 0.f);
  for (int i = slot; i <= deg; i += 4) {
    int src = (i < deg) ? col[start + i] : n;
    float w = __expf(lrelu(as1[src * 4 + head] + adh)) * rsh;
    uint4 u = *(const uint4*)(h1b + (size_t)src * F1 + lane16 * 8);
    accA.x += w * bflo(u.x); accA.y += w * bfhi(u.x);
    accA.z += w * bflo(u.y); accA.w += w * bfhi(u.y);
    accB.x += w * bflo(u.z); accB.y += w * bfhi(u.z);
    accB.z += w * bflo(u.w); accB.w += w * bfhi(u.w);
  }
  // cross-slot reduce: slot bits are lane bits 4,5 (clean xor butterfly)
#pragma unroll
  for (int off = 16; off <= 32; off <<= 1) {
    accA.x += __shfl_xor(accA.x, off); accA.y += __shfl_xor(accA.y, off);
    accA.z += __shfl_xor(accA.z, off); accA.w += __shfl_xor(accA.w, off);
    accB.x += __shfl_xor(accB.x, off); accB.y += __shfl_xor(accB.y, off);
    accB.z += __shfl_xor(accB.z, off); accB.w += __shfl_xor(accB.w, off);
  }
  if (slot == 0) {
    float4 bA = *(const float4*)&b1[lane16 * 8];
    float4 bB = *(const float4*)&b1[lane16 * 8 + 4];
    float4 oA, oB;
    oA.x = fmaxf(accA.x + bA.x, 0.f); oA.y = fmaxf(accA.y + bA.y, 0.f);
    oA.z = fmaxf(accA.z + bA.z, 0.f); oA.w = fmaxf(accA.w + bA.w, 0.f);
    oB.x = fmaxf(accB.x + bB.x, 0.f); oB.y = fmaxf(accB.y + bB.y, 0.f);
    oB.z = fmaxf(accB.z + bB.z, 0.f); oB.w = fmaxf(accB.w + bB.w, 0.f);
    *(float4*)&x2[(size_t)n * F1 + lane16 * 8] = oA;
    *(float4*)&x2[(size_t)n * F1 + lane16 * 8 + 4] = oB;
  }
}

// ---------------- GEMM2 tiled + alpha2 fused: h2b = x2@W2 (bf16), as2/ad2 ----------------
__global__ __launch_bounds__(256) void gemm2_kernel(
    const float* __restrict__ x2, const float* __restrict__ W2,
    const float* __restrict__ asv, const float* __restrict__ adv,
    unsigned short* __restrict__ h2b, float* __restrict__ as2, float* __restrict__ ad2) {
  __shared__ float xs[64][132];
  __shared__ float W2s[128][44];
  __shared__ float asv_s[40], adv_s[40];
  int tid = threadIdx.x;
  int bm = blockIdx.x * 64;
#pragma unroll
  for (int l = 0; l < 8; l++) {
    int idx = tid + l * 256;
    int r = idx >> 5;
    int c4 = (idx & 31) << 2;
    float4 v = make_float4(0.f, 0.f, 0.f, 0.f);
    if (bm + r < N_NODES) v = *(const float4*)&x2[(size_t)(bm + r) * F1 + c4];
    *(float4*)&xs[r][c4] = v;
  }
#pragma unroll
  for (int l = 0; l < 5; l++) {
    int idx = tid + l * 256;
    int k = idx / 10;
    int c4 = (idx - k * 10) * 4;
    *(float4*)&W2s[k][c4] = *(const float4*)&W2[k * OUT_DIM + c4];
  }
  if (tid < OUT_DIM) { asv_s[tid] = asv[tid]; adv_s[tid] = adv[tid]; }
  __syncthreads();
  int r = tid >> 2;
  int cb = (tid & 3) * 10;
  float acc[10] = {0.f};
  for (int k = 0; k < F1; k++) {
    float xv = xs[r][k];
#pragma unroll
    for (int c = 0; c < 10; c++) acc[c] += xv * W2s[k][cb + c];
  }
  int grow = bm + r;
  float sa = 0.f, sd = 0.f;
#pragma unroll
  for (int c = 0; c < 10; c++) {
    sa += acc[c] * asv_s[cb + c];
    sd += acc[c] * adv_s[cb + c];
  }
#pragma unroll
  for (int off = 1; off < 4; off <<= 1) {
    sa += __shfl_xor(sa, off);
    sd += __shfl_xor(sd, off);
  }
  if (grow < N_NODES) {
#pragma unroll
    for (int c = 0; c < 10; c += 2) {
      unsigned int p = ((unsigned int)f2bf(acc[c + 1]) << 16) | f2bf(acc[c]);
      *(unsigned int*)&h2b[(size_t)grow * OUT_DIM + cb + c] = p;
    }
    if ((tid & 3) == 0) { as2[grow] = sa; ad2[grow] = sd; }
  }
}

// ---------------- layer-2: wave-per-node fused softmax + gather + log_softmax ----------------
__global__ __launch_bounds__(256) void gather2_kernel(
    const unsigned short* __restrict__ h2b, const float* __restrict__ as2,
    const float* __restrict__ ad2, const float* __restrict__ b2,
    const int* __restrict__ row_ptr, const int* __restrict__ col,
    float* __restrict__ out) {
  int n = blockIdx.x * 4 + (threadIdx.x >> 6);
  if (n >= N_NODES) return;
  int lane = threadIdx.x & 63;
  int start = row_ptr[n];
  int deg = row_ptr[n + 1] - start;
  float adh = ad2[n];
  // phase A: sum of exp
  float part = 0.f;
  for (int i = lane; i <= deg; i += 64) {
    int src = (i < deg) ? col[start + i] : n;
    part += __expf(lrelu(as2[src] + adh));
  }
#pragma unroll
  for (int off = 32; off > 0; off >>= 1) part += __shfl_xor(part, off);
  float rs = 1.f / (part + 1e-16f);
  // phase B
  int slot = lane / 5;        // 0..12 (>=12 idle)
  int c = lane - slot * 5;    // 0..4, channels c*8..+7
  float4 accA = make_float4(0.f, 0.f, 0.f, 0.f);
  float4 accB = make_float4(0.f, 0.f, 0.f, 0.f);
  if (slot < 12) {
    for (int i = slot; i <= deg; i += 12) {
      int src = (i < deg) ? col[start + i] : n;
      float wgt = __expf(lrelu(as2[src] + adh)) * rs;
      uint4 u = *(const uint4*)(h2b + (size_t)src * OUT_DIM + c * 8);
      accA.x += wgt * bflo(u.x); accA.y += wgt * bfhi(u.x);
      accA.z += wgt * bflo(u.y); accA.w += wgt * bfhi(u.y);
      accB.x += wgt * bflo(u.z); accB.y += wgt * bfhi(u.z);
      accB.z += wgt * bflo(u.w); accB.w += wgt * bfhi(u.w);
    }
  }
  // cross-slot reduce (12 slots, 5 lanes each); temps read before update (R7 bugfix)
  {
    float v[8] = {accA.x, accA.y, accA.z, accA.w, accB.x, accB.y, accB.z, accB.w};
#pragma unroll
    for (int k = 0; k < 8; k++) v[k] += __shfl(v[k], lane + 30);
#pragma unroll
    for (int k = 0; k < 8; k++) v[k] += __shfl(v[k], lane + 15);
    float t1[8], t2[8];
#pragma unroll
    for (int k = 0; k < 8; k++) t1[k] = __shfl(v[k], lane + 5);
#pragma unroll
    for (int k = 0; k < 8; k++) t2[k] = __shfl(v[k], lane + 10);
#pragma unroll
    for (int k = 0; k < 8; k++) v[k] += t1[k] + t2[k];
    accA.x = v[0]; accA.y = v[1]; accA.z = v[2]; accA.w = v[3];
    accB.x = v[4]; accB.y = v[5]; accB.z = v[6]; accB.w = v[7];
  }
  bool owner = (slot == 0);   // lanes 0..4
  float vals[8] = {accA.x, accA.y, accA.z, accA.w, accB.x, accB.y, accB.z, accB.w};
  float lmax = -1e30f, lsum = 0.f;
  if (owner) {
#pragma unroll
    for (int k = 0; k < 8; k++) {
      vals[k] += b2[c * 8 + k];
      lmax = fmaxf(lmax, vals[k]);
    }
  }
  float gmax = lmax;
#pragma unroll
  for (int off = 32; off > 0; off >>= 1) gmax = fmaxf(gmax, __shfl_xor(gmax, off));
  if (owner) {
#pragma unroll
    for (int k = 0; k < 8; k++) lsum += __expf(vals[k] - gmax);
  }
#pragma unroll
  for (int off = 32; off > 0; off >>= 1) lsum += __shfl_xor(lsum, off);
  if (owner) {
    float lse = gmax + __logf(lsum);
    float4 oA = make_float4(vals[0] - lse, vals[1] - lse, vals[2] - lse, vals[3] - lse);
    float4 oB = make_float4(vals[4] - lse, vals[5] - lse, vals[6] - lse, vals[7] - lse);
    *(float4*)&out[(size_t)n * OUT_DIM + c * 8] = oA;
    *(float4*)&out[(size_t)n * OUT_DIM + c * 8 + 4] = oB;
  }
}

extern "C" void kernel_launch(void* const* d_in, const int* in_sizes, int n_in,
                              void* d_out, int out_size, void* d_ws, size_t ws_size,
                              hipStream_t stream) {
  const float* x      = (const float*)d_in[0];
  const int*   ei     = (const int*)d_in[1];
  const float* W1     = (const float*)d_in[2];
  const float* a_src1 = (const float*)d_in[3];
  const float* a_dst1 = (const float*)d_in[4];
  const float* b1     = (const float*)d_in[5];
  const float* W2     = (const float*)d_in[6];
  const float* a_src2 = (const float*)d_in[7];
  const float* a_dst2 = (const float*)d_in[8];
  const float* b2     = (const float*)d_in[9];
  float* out = (float*)d_out;

  char* ws = (char*)d_ws;
  size_t off = 0;
  auto alloc = [&](size_t bytes) -> void* {
    void* p = ws + off;
    off += (bytes + 255) & ~(size_t)255;
    return p;
  };
  unsigned short* h1b = (unsigned short*)alloc((size_t)N_NODES * F1 * 2);       // 12.8 MB
  unsigned short* h2b = (unsigned short*)alloc((size_t)N_NODES * OUT_DIM * 2);  // 4 MB
  unsigned short* wHi = (unsigned short*)alloc((size_t)IN_DIM * F1 * 2);        // 64 KB
  unsigned short* wLo = (unsigned short*)alloc((size_t)IN_DIM * F1 * 2);        // 64 KB
  float* as1    = (float*)alloc((size_t)N_NODES * HEADS * 4);
  float* ad1    = (float*)alloc((size_t)N_NODES * HEADS * 4);
  float* x2     = (float*)alloc((size_t)N_NODES * F1 * 4);
  float* as2    = (float*)alloc((size_t)N_NODES * 4);
  float* ad2    = (float*)alloc((size_t)N_NODES * 4);
  int* row_ptr  = (int*)alloc((size_t)(N_NODES + 1) * 4);
  int* cursor   = (int*)alloc((size_t)N_NODES * 4);
  int* cnt      = (int*)alloc((size_t)N_NODES * 4);
  int* blk_sum  = (int*)alloc((size_t)SCAN_NBLK * 4);
  int* blk_off  = (int*)alloc((size_t)SCAN_NBLK * 4);
  int* col      = (int*)alloc((size_t)N_EDGES * 4);

  hipMemsetAsync(cnt, 0, (size_t)N_NODES * 4, stream);
  hist_kernel<<<(N_EDGES + 255) / 256, 256, 0, stream>>>(ei, cnt);
  blksum_kernel<<<SCAN_NBLK, 256, 0, stream>>>(cnt, blk_sum);
  blkscan_kernel<<<1, 256, 0, stream>>>(blk_sum, blk_off, row_ptr);
  finalscan_kernel<<<SCAN_NBLK, 256, 0, stream>>>(cnt, blk_off, row_ptr, cursor);
  scatter_kernel<<<(N_EDGES + 255) / 256, 256, 0, stream>>>(ei, cursor, col);

  w1pack_kernel<<<16, 256, 0, stream>>>(W1, wHi, wLo);
  gemm1_mfma_kernel<<<(N_NODES + 63) / 64, 256, 0, stream>>>(
      x, wHi, wLo, a_src1, a_dst1, h1b, as1, ad1);
  gather1_kernel<<<(N_NODES + 3) / 4, 256, 0, stream>>>(h1b, as1, ad1, b1, row_ptr, col, x2);

  gemm2_kernel<<<(N_NODES + 63) / 64, 256, 0, stream>>>(x2, W2, a_src2, a_dst2, h2b, as2, ad2);
  gather2_kernel<<<(N_NODES + 3) / 4, 256, 0, stream>>>(h2b, as2, ad2, b2, row_ptr, col, out);
}

// Round 10
// 270.087 us; speedup vs baseline: 2.3693x; 1.2413x over previous
//
#include <hip/hip_runtime.h>
#include <math.h>

#define N_NODES 50000
#define N_EDGES 800000
#define IN_DIM  256
#define F1      128   // HEADS*HID
#define HEADS   4
#define OUT_DIM 40
#define NEG     0.2f

// CSR bucket sort params
#define NB   391     // buckets of 128 nodes: 50000/128 -> 391
#define CAP  3072    // per-bucket capacity (mean 2048, sigma ~45 -> >20 sigma margin)
#define EB   4096    // edges per bin block

typedef __attribute__((ext_vector_type(8))) short short8;    // 8 bf16 in 4 VGPRs
typedef __attribute__((ext_vector_type(4))) float float4v;   // MFMA C/D

// ---- bf16 helpers (RNE pack, shift unpack) ----
__device__ __forceinline__ unsigned short f2bf(float f) {
  unsigned int u = __float_as_uint(f);
  u += 0x7FFF + ((u >> 16) & 1);
  return (unsigned short)(u >> 16);
}
__device__ __forceinline__ float bf2f(unsigned short h) {
  return __uint_as_float((unsigned int)h << 16);
}
__device__ __forceinline__ float bflo(unsigned int u) { return __uint_as_float(u << 16); }
__device__ __forceinline__ float bfhi(unsigned int u) { return __uint_as_float(u & 0xffff0000u); }

__device__ __forceinline__ float lrelu(float e) { return e > 0.f ? e : e * NEG; }

// ---------------- CSR build: bucketed counting sort (line-local writes) ----------------
// Phase 1: bin edges into 391 coarse buckets (dst>>7), per-block LDS staging so
// each (block,bucket) pair appends a contiguous run -> minimal write amplification.
__global__ __launch_bounds__(256) void bin_kernel(const int* __restrict__ ei,
                                                  int* __restrict__ gcnt,
                                                  int2* __restrict__ gbucket) {
  __shared__ int ls[EB];
  __shared__ int ld[EB];
  __shared__ int lcnt[NB];
  __shared__ int lcur[NB];
  __shared__ int gbaseS[NB];
  int tid = threadIdx.x;
  size_t base = (size_t)blockIdx.x * EB;
  for (int t = tid; t < NB; t += 256) { lcnt[t] = 0; lcur[t] = 0; }
  __syncthreads();
#pragma unroll
  for (int l = 0; l < EB / 256; l++) {
    int li = l * 256 + tid;
    size_t idx = base + li;
    int s = 0, d = -1;
    if (idx < N_EDGES) {
      s = ei[idx];
      d = ei[N_EDGES + idx];
      atomicAdd(&lcnt[d >> 7], 1);
    }
    ls[li] = s;
    ld[li] = d;
  }
  __syncthreads();
  for (int t = tid; t < NB; t += 256) gbaseS[t] = atomicAdd(&gcnt[t], lcnt[t]);
  __syncthreads();
#pragma unroll
  for (int l = 0; l < EB / 256; l++) {
    int li = l * 256 + tid;
    int d = ld[li];
    if (d >= 0) {
      int b = d >> 7;
      int r = gbaseS[b] + atomicAdd(&lcur[b], 1);
      if (r >= CAP) r = CAP - 1;   // overflow guard (statistically impossible)
      gbucket[(size_t)b * CAP + r] = make_int2(ls[li], d);
    }
  }
}

// Phase 2: scan the 391 bucket counts -> bucket base offsets (row_ptr coarse grid)
__global__ __launch_bounds__(512) void bucketscan_kernel(const int* __restrict__ gcnt,
                                                         int* __restrict__ bbase,
                                                         int* __restrict__ row_ptr) {
  __shared__ int lds[512];
  int tid = threadIdx.x;
  int v = (tid < NB) ? gcnt[tid] : 0;
  lds[tid] = v;
  __syncthreads();
  for (int off = 1; off < 512; off <<= 1) {
    int t = (tid >= off) ? lds[tid - off] : 0;
    __syncthreads();
    lds[tid] += t;
    __syncthreads();
  }
  if (tid < NB) bbase[tid] = lds[tid] - v;
  if (tid == 0) row_ptr[N_NODES] = N_EDGES;
}

// Phase 3: per-bucket exact counting sort; col writes stay inside the block's
// private contiguous region -> no cross-XCD line sharing.
__global__ __launch_bounds__(256) void csr_kernel(const int2* __restrict__ gbucket,
                                                  const int* __restrict__ gcnt,
                                                  const int* __restrict__ bbase,
                                                  int* __restrict__ row_ptr,
                                                  int* __restrict__ col) {
  __shared__ int2 ent[CAP];
  __shared__ int hcnt[128];
  __shared__ int sc[128];
  __shared__ int cur[128];
  int b = blockIdx.x;
  int tid = threadIdx.x;
  int cnt = gcnt[b]; if (cnt > CAP) cnt = CAP;
  int base = bbase[b];
  if (tid < 128) hcnt[tid] = 0;
  __syncthreads();
  for (int i = tid; i < cnt; i += 256) {
    int2 e = gbucket[(size_t)b * CAP + i];
    ent[i] = e;
    atomicAdd(&hcnt[e.y & 127], 1);
  }
  __syncthreads();
  if (tid < 128) sc[tid] = hcnt[tid];
  __syncthreads();
  for (int off = 1; off < 128; off <<= 1) {
    int t = 0;
    if (tid < 128 && tid >= off) t = sc[tid - off];
    __syncthreads();
    if (tid < 128) sc[tid] += t;
    __syncthreads();
  }
  if (tid < 128) {
    int excl = sc[tid] - hcnt[tid];
    cur[tid] = excl;
    int node = (b << 7) + tid;
    if (node < N_NODES) row_ptr[node] = base + excl;
  }
  __syncthreads();
  for (int i = tid; i < cnt; i += 256) {
    int2 e = ent[i];
    int r = atomicAdd(&cur[e.y & 127], 1);
    col[base + r] = e.x;
  }
}

// ---------------- W1 -> MFMA B-fragment packing (hi/lo split) ----------------
__global__ __launch_bounds__(256) void w1pack_kernel(const float* __restrict__ W1,
                                                     unsigned short* __restrict__ wHi,
                                                     unsigned short* __restrict__ wLo) {
  int tid = blockIdx.x * 256 + threadIdx.x;   // 0..4095
  int kk = tid >> 9;
  int rest = tid & 511;
  int t = rest >> 6;
  int lane = rest & 63;
  int q = lane >> 4;
  int ln = lane & 15;
  int n = t * 16 + ln;
  unsigned int hi[4], lo[4];
#pragma unroll
  for (int jj = 0; jj < 4; jj++) {
    unsigned short h0, h1, l0, l1;
    {
      float v = W1[(kk * 32 + q * 8 + jj * 2) * F1 + n];
      h0 = f2bf(v); l0 = f2bf(v - bf2f(h0));
    }
    {
      float v = W1[(kk * 32 + q * 8 + jj * 2 + 1) * F1 + n];
      h1 = f2bf(v); l1 = f2bf(v - bf2f(h1));
    }
    hi[jj] = (unsigned int)h0 | ((unsigned int)h1 << 16);
    lo[jj] = (unsigned int)l0 | ((unsigned int)l1 << 16);
  }
  size_t base = (size_t)tid * 8;
  *(uint4*)&wHi[base] = make_uint4(hi[0], hi[1], hi[2], hi[3]);
  *(uint4*)&wLo[base] = make_uint4(lo[0], lo[1], lo[2], lo[3]);
}

// ---------------- GEMM1 via bf16 MFMA (split precision) + fused alpha1 ----------------
__global__ __launch_bounds__(256) void gemm1_mfma_kernel(
    const float* __restrict__ x, const unsigned short* __restrict__ wHi,
    const unsigned short* __restrict__ wLo,
    const float* __restrict__ a_src, const float* __restrict__ a_dst,
    unsigned short* __restrict__ h1b, float* __restrict__ as1, float* __restrict__ ad1) {
  int tid = threadIdx.x;
  int w = tid >> 6;
  int lane = tid & 63;
  int q = lane >> 4;
  int ln = lane & 15;
  int rowBase = blockIdx.x * 64 + w * 16;
  int rowA = rowBase + ln;
  int rowAc = rowA < N_NODES ? rowA : N_NODES - 1;
  float4v acc[8];
#pragma unroll
  for (int t = 0; t < 8; t++) acc[t] = (float4v){0.f, 0.f, 0.f, 0.f};
  const short8* bhp = (const short8*)wHi;
  const short8* blp = (const short8*)wLo;
  for (int kk = 0; kk < 8; kk++) {
    const float4* xp = (const float4*)(x + (size_t)rowAc * IN_DIM + kk * 32 + q * 8);
    float4 a0 = xp[0];
    float4 a1 = xp[1];
    float av[8] = {a0.x, a0.y, a0.z, a0.w, a1.x, a1.y, a1.z, a1.w};
    short8 ahi, alo;
#pragma unroll
    for (int j = 0; j < 8; j++) {
      unsigned short h = f2bf(av[j]);
      ahi[j] = (short)h;
      alo[j] = (short)f2bf(av[j] - bf2f(h));
    }
    int fbase = (kk * 8) * 64 + lane;
#pragma unroll
    for (int t = 0; t < 8; t++) {
      short8 bh = bhp[fbase + t * 64];
      short8 bl = blp[fbase + t * 64];
      acc[t] = __builtin_amdgcn_mfma_f32_16x16x32_bf16(ahi, bh, acc[t], 0, 0, 0);
      acc[t] = __builtin_amdgcn_mfma_f32_16x16x32_bf16(ahi, bl, acc[t], 0, 0, 0);
      acc[t] = __builtin_amdgcn_mfma_f32_16x16x32_bf16(alo, bh, acc[t], 0, 0, 0);
    }
  }
  float asv[8], adv[8];
#pragma unroll
  for (int t = 0; t < 8; t++) {
    asv[t] = a_src[t * 16 + ln];
    adv[t] = a_dst[t * 16 + ln];
  }
#pragma unroll
  for (int reg = 0; reg < 4; reg++) {
    int r = rowBase + q * 4 + reg;
    bool valid = (r < N_NODES);
    if (valid) {
#pragma unroll
      for (int t = 0; t < 8; t++)
        h1b[(size_t)r * F1 + t * 16 + ln] = f2bf(acc[t][reg]);
    }
#pragma unroll
    for (int h = 0; h < 4; h++) {
      float sa = acc[2 * h][reg] * asv[2 * h] + acc[2 * h + 1][reg] * asv[2 * h + 1];
      float sd = acc[2 * h][reg] * adv[2 * h] + acc[2 * h + 1][reg] * adv[2 * h + 1];
#pragma unroll
      for (int off = 1; off < 16; off <<= 1) {
        sa += __shfl_xor(sa, off);
        sd += __shfl_xor(sd, off);
      }
      if (ln == 0 && valid) {
        as1[r * 4 + h] = sa;
        ad1[r * 4 + h] = sd;
      }
    }
  }
}

// ---------------- layer-1: wave-per-node fused softmax-sum + gather ----------------
__global__ __launch_bounds__(256) void gather1_kernel(
    const unsigned short* __restrict__ h1b, const float* __restrict__ as1,
    const float* __restrict__ ad1, const float* __restrict__ b1,
    const int* __restrict__ row_ptr, const int* __restrict__ col,
    float* __restrict__ x2) {
  int n = blockIdx.x * 4 + (threadIdx.x >> 6);
  if (n >= N_NODES) return;
  int lane = threadIdx.x & 63;
  int start = row_ptr[n];
  int deg = row_ptr[n + 1] - start;
  float4 ad = *(const float4*)&ad1[n * 4];
  float s0 = 0.f, s1 = 0.f, s2 = 0.f, s3 = 0.f;
  for (int i = lane; i <= deg; i += 64) {
    int src = (i < deg) ? col[start + i] : n;
    float4 as = *(const float4*)&as1[src * 4];
    s0 += __expf(lrelu(as.x + ad.x));
    s1 += __expf(lrelu(as.y + ad.y));
    s2 += __expf(lrelu(as.z + ad.z));
    s3 += __expf(lrelu(as.w + ad.w));
  }
#pragma unroll
  for (int off = 32; off > 0; off >>= 1) {
    s0 += __shfl_xor(s0, off);
    s1 += __shfl_xor(s1, off);
    s2 += __shfl_xor(s2, off);
    s3 += __shfl_xor(s3, off);
  }
  int slot = lane >> 4;
  int lane16 = lane & 15;
  int head = lane16 >> 2;
  float rsh = (head == 0) ? s0 : (head == 1) ? s1 : (head == 2) ? s2 : s3;
  rsh = 1.f / (rsh + 1e-16f);
  float adh = (head == 0) ? ad.x : (head == 1) ? ad.y : (head == 2) ? ad.z : ad.w;
  float4 accA = make_float4(0.f, 0.f, 0.f, 0.f);
  float4 accB = make_float4(0.f, 0.f, 0.f, 0.f);
  for (int i = slot; i <= deg; i += 4) {
    int src = (i < deg) ? col[start + i] : n;
    float w = __expf(lrelu(as1[src * 4 + head] + adh)) * rsh;
    uint4 u = *(const uint4*)(h1b + (size_t)src * F1 + lane16 * 8);
    accA.x += w * bflo(u.x); accA.y += w * bfhi(u.x);
    accA.z += w * bflo(u.y); accA.w += w * bfhi(u.y);
    accB.x += w * bflo(u.z); accB.y += w * bfhi(u.z);
    accB.z += w * bflo(u.w); accB.w += w * bfhi(u.w);
  }
#pragma unroll
  for (int off = 16; off <= 32; off <<= 1) {
    accA.x += __shfl_xor(accA.x, off); accA.y += __shfl_xor(accA.y, off);
    accA.z += __shfl_xor(accA.z, off); accA.w += __shfl_xor(accA.w, off);
    accB.x += __shfl_xor(accB.x, off); accB.y += __shfl_xor(accB.y, off);
    accB.z += __shfl_xor(accB.z, off); accB.w += __shfl_xor(accB.w, off);
  }
  if (slot == 0) {
    float4 bA = *(const float4*)&b1[lane16 * 8];
    float4 bB = *(const float4*)&b1[lane16 * 8 + 4];
    float4 oA, oB;
    oA.x = fmaxf(accA.x + bA.x, 0.f); oA.y = fmaxf(accA.y + bA.y, 0.f);
    oA.z = fmaxf(accA.z + bA.z, 0.f); oA.w = fmaxf(accA.w + bA.w, 0.f);
    oB.x = fmaxf(accB.x + bB.x, 0.f); oB.y = fmaxf(accB.y + bB.y, 0.f);
    oB.z = fmaxf(accB.z + bB.z, 0.f); oB.w = fmaxf(accB.w + bB.w, 0.f);
    *(float4*)&x2[(size_t)n * F1 + lane16 * 8] = oA;
    *(float4*)&x2[(size_t)n * F1 + lane16 * 8 + 4] = oB;
  }
}

// ---------------- GEMM2 tiled + alpha2 fused: h2b = x2@W2 (bf16), as2/ad2 ----------------
__global__ __launch_bounds__(256) void gemm2_kernel(
    const float* __restrict__ x2, const float* __restrict__ W2,
    const float* __restrict__ asv, const float* __restrict__ adv,
    unsigned short* __restrict__ h2b, float* __restrict__ as2, float* __restrict__ ad2) {
  __shared__ float xs[64][132];
  __shared__ float W2s[128][44];
  __shared__ float asv_s[40], adv_s[40];
  int tid = threadIdx.x;
  int bm = blockIdx.x * 64;
#pragma unroll
  for (int l = 0; l < 8; l++) {
    int idx = tid + l * 256;
    int r = idx >> 5;
    int c4 = (idx & 31) << 2;
    float4 v = make_float4(0.f, 0.f, 0.f, 0.f);
    if (bm + r < N_NODES) v = *(const float4*)&x2[(size_t)(bm + r) * F1 + c4];
    *(float4*)&xs[r][c4] = v;
  }
#pragma unroll
  for (int l = 0; l < 5; l++) {
    int idx = tid + l * 256;
    int k = idx / 10;
    int c4 = (idx - k * 10) * 4;
    *(float4*)&W2s[k][c4] = *(const float4*)&W2[k * OUT_DIM + c4];
  }
  if (tid < OUT_DIM) { asv_s[tid] = asv[tid]; adv_s[tid] = adv[tid]; }
  __syncthreads();
  int r = tid >> 2;
  int cb = (tid & 3) * 10;
  float acc[10] = {0.f};
  for (int k = 0; k < F1; k++) {
    float xv = xs[r][k];
#pragma unroll
    for (int c = 0; c < 10; c++) acc[c] += xv * W2s[k][cb + c];
  }
  int grow = bm + r;
  float sa = 0.f, sd = 0.f;
#pragma unroll
  for (int c = 0; c < 10; c++) {
    sa += acc[c] * asv_s[cb + c];
    sd += acc[c] * adv_s[cb + c];
  }
#pragma unroll
  for (int off = 1; off < 4; off <<= 1) {
    sa += __shfl_xor(sa, off);
    sd += __shfl_xor(sd, off);
  }
  if (grow < N_NODES) {
#pragma unroll
    for (int c = 0; c < 10; c += 2) {
      unsigned int p = ((unsigned int)f2bf(acc[c + 1]) << 16) | f2bf(acc[c]);
      *(unsigned int*)&h2b[(size_t)grow * OUT_DIM + cb + c] = p;
    }
    if ((tid & 3) == 0) { as2[grow] = sa; ad2[grow] = sd; }
  }
}

// ---------------- layer-2: wave-per-node fused softmax + gather + log_softmax ----------------
__global__ __launch_bounds__(256) void gather2_kernel(
    const unsigned short* __restrict__ h2b, const float* __restrict__ as2,
    const float* __restrict__ ad2, const float* __restrict__ b2,
    const int* __restrict__ row_ptr, const int* __restrict__ col,
    float* __restrict__ out) {
  int n = blockIdx.x * 4 + (threadIdx.x >> 6);
  if (n >= N_NODES) return;
  int lane = threadIdx.x & 63;
  int start = row_ptr[n];
  int deg = row_ptr[n + 1] - start;
  float adh = ad2[n];
  float part = 0.f;
  for (int i = lane; i <= deg; i += 64) {
    int src = (i < deg) ? col[start + i] : n;
    part += __expf(lrelu(as2[src] + adh));
  }
#pragma unroll
  for (int off = 32; off > 0; off >>= 1) part += __shfl_xor(part, off);
  float rs = 1.f / (part + 1e-16f);
  int slot = lane / 5;
  int c = lane - slot * 5;
  float4 accA = make_float4(0.f, 0.f, 0.f, 0.f);
  float4 accB = make_float4(0.f, 0.f, 0.f, 0.f);
  if (slot < 12) {
    for (int i = slot; i <= deg; i += 12) {
      int src = (i < deg) ? col[start + i] : n;
      float wgt = __expf(lrelu(as2[src] + adh)) * rs;
      uint4 u = *(const uint4*)(h2b + (size_t)src * OUT_DIM + c * 8);
      accA.x += wgt * bflo(u.x); accA.y += wgt * bfhi(u.x);
      accA.z += wgt * bflo(u.y); accA.w += wgt * bfhi(u.y);
      accB.x += wgt * bflo(u.z); accB.y += wgt * bfhi(u.z);
      accB.z += wgt * bflo(u.w); accB.w += wgt * bfhi(u.w);
    }
  }
  {
    float v[8] = {accA.x, accA.y, accA.z, accA.w, accB.x, accB.y, accB.z, accB.w};
#pragma unroll
    for (int k = 0; k < 8; k++) v[k] += __shfl(v[k], lane + 30);
#pragma unroll
    for (int k = 0; k < 8; k++) v[k] += __shfl(v[k], lane + 15);
    float t1[8], t2[8];
#pragma unroll
    for (int k = 0; k < 8; k++) t1[k] = __shfl(v[k], lane + 5);
#pragma unroll
    for (int k = 0; k < 8; k++) t2[k] = __shfl(v[k], lane + 10);
#pragma unroll
    for (int k = 0; k < 8; k++) v[k] += t1[k] + t2[k];
    accA.x = v[0]; accA.y = v[1]; accA.z = v[2]; accA.w = v[3];
    accB.x = v[4]; accB.y = v[5]; accB.z = v[6]; accB.w = v[7];
  }
  bool owner = (slot == 0);
  float vals[8] = {accA.x, accA.y, accA.z, accA.w, accB.x, accB.y, accB.z, accB.w};
  float lmax = -1e30f, lsum = 0.f;
  if (owner) {
#pragma unroll
    for (int k = 0; k < 8; k++) {
      vals[k] += b2[c * 8 + k];
      lmax = fmaxf(lmax, vals[k]);
    }
  }
  float gmax = lmax;
#pragma unroll
  for (int off = 32; off > 0; off >>= 1) gmax = fmaxf(gmax, __shfl_xor(gmax, off));
  if (owner) {
#pragma unroll
    for (int k = 0; k < 8; k++) lsum += __expf(vals[k] - gmax);
  }
#pragma unroll
  for (int off = 32; off > 0; off >>= 1) lsum += __shfl_xor(lsum, off);
  if (owner) {
    float lse = gmax + __logf(lsum);
    float4 oA = make_float4(vals[0] - lse, vals[1] - lse, vals[2] - lse, vals[3] - lse);
    float4 oB = make_float4(vals[4] - lse, vals[5] - lse, vals[6] - lse, vals[7] - lse);
    *(float4*)&out[(size_t)n * OUT_DIM + c * 8] = oA;
    *(float4*)&out[(size_t)n * OUT_DIM + c * 8 + 4] = oB;
  }
}

extern "C" void kernel_launch(void* const* d_in, const int* in_sizes, int n_in,
                              void* d_out, int out_size, void* d_ws, size_t ws_size,
                              hipStream_t stream) {
  const float* x      = (const float*)d_in[0];
  const int*   ei     = (const int*)d_in[1];
  const float* W1     = (const float*)d_in[2];
  const float* a_src1 = (const float*)d_in[3];
  const float* a_dst1 = (const float*)d_in[4];
  const float* b1     = (const float*)d_in[5];
  const float* W2     = (const float*)d_in[6];
  const float* a_src2 = (const float*)d_in[7];
  const float* a_dst2 = (const float*)d_in[8];
  const float* b2     = (const float*)d_in[9];
  float* out = (float*)d_out;

  char* ws = (char*)d_ws;
  size_t off = 0;
  auto alloc = [&](size_t bytes) -> void* {
    void* p = ws + off;
    off += (bytes + 255) & ~(size_t)255;
    return p;
  };
  unsigned short* h1b = (unsigned short*)alloc((size_t)N_NODES * F1 * 2);       // 12.8 MB
  unsigned short* h2b = (unsigned short*)alloc((size_t)N_NODES * OUT_DIM * 2);  // 4 MB
  unsigned short* wHi = (unsigned short*)alloc((size_t)IN_DIM * F1 * 2);        // 64 KB
  unsigned short* wLo = (unsigned short*)alloc((size_t)IN_DIM * F1 * 2);        // 64 KB
  float* as1    = (float*)alloc((size_t)N_NODES * HEADS * 4);
  float* ad1    = (float*)alloc((size_t)N_NODES * HEADS * 4);
  float* x2     = (float*)alloc((size_t)N_NODES * F1 * 4);
  float* as2    = (float*)alloc((size_t)N_NODES * 4);
  float* ad2    = (float*)alloc((size_t)N_NODES * 4);
  int* row_ptr  = (int*)alloc((size_t)(N_NODES + 1) * 4);
  int* col      = (int*)alloc((size_t)N_EDGES * 4);
  int* gcnt     = (int*)alloc((size_t)NB * 4);
  int* bbase    = (int*)alloc((size_t)NB * 4);
  int2* gbucket = (int2*)alloc((size_t)NB * CAP * 8);                           // 9.6 MB

  hipMemsetAsync(gcnt, 0, (size_t)NB * 4, stream);
  bin_kernel<<<(N_EDGES + EB - 1) / EB, 256, 0, stream>>>(ei, gcnt, gbucket);
  bucketscan_kernel<<<1, 512, 0, stream>>>(gcnt, bbase, row_ptr);
  csr_kernel<<<NB, 256, 0, stream>>>(gbucket, gcnt, bbase, row_ptr, col);

  w1pack_kernel<<<16, 256, 0, stream>>>(W1, wHi, wLo);
  gemm1_mfma_kernel<<<(N_NODES + 63) / 64, 256, 0, stream>>>(
      x, wHi, wLo, a_src1, a_dst1, h1b, as1, ad1);
  gather1_kernel<<<(N_NODES + 3) / 4, 256, 0, stream>>>(h1b, as1, ad1, b1, row_ptr, col, x2);

  gemm2_kernel<<<(N_NODES + 63) / 64, 256, 0, stream>>>(x2, W2, a_src2, a_dst2, h2b, as2, ad2);
  gather2_kernel<<<(N_NODES + 3) / 4, 256, 0, stream>>>(h2b, as2, ad2, b2, row_ptr, col, out);
}

// Round 11
// 257.192 us; speedup vs baseline: 2.4881x; 1.0501x over previous
//
#include <hip/hip_runtime.h>
#include <math.h>

#define N_NODES 50000
#define N_EDGES 800000
#define IN_DIM  256
#define F1      128   // HEADS*HID
#define HEADS   4
#define OUT_DIM 40
#define NEG     0.2f

// CSR bucket sort params
#define NB   391     // buckets of 128 nodes: 50000/128 -> 391
#define CAP  3072    // per-bucket capacity (mean 2048, sigma ~45 -> >20 sigma margin)
#define EB   4096    // edges per bin block

#define DCAP 96      // per-node cached edge capacity (deg ~ Poisson(16); P(>95) ~ 1e-39)

typedef __attribute__((ext_vector_type(8))) short short8;    // 8 bf16 in 4 VGPRs
typedef __attribute__((ext_vector_type(4))) float float4v;   // MFMA C/D

// ---- bf16 helpers (RNE pack, shift unpack) ----
__device__ __forceinline__ unsigned short f2bf(float f) {
  unsigned int u = __float_as_uint(f);
  u += 0x7FFF + ((u >> 16) & 1);
  return (unsigned short)(u >> 16);
}
__device__ __forceinline__ float bf2f(unsigned short h) {
  return __uint_as_float((unsigned int)h << 16);
}
__device__ __forceinline__ float bflo(unsigned int u) { return __uint_as_float(u << 16); }
__device__ __forceinline__ float bfhi(unsigned int u) { return __uint_as_float(u & 0xffff0000u); }

__device__ __forceinline__ float lrelu(float e) { return e > 0.f ? e : e * NEG; }

// ---------------- CSR build: bucketed counting sort (line-local writes) ----------------
__global__ __launch_bounds__(256) void bin_kernel(const int* __restrict__ ei,
                                                  int* __restrict__ gcnt,
                                                  int2* __restrict__ gbucket) {
  __shared__ int ls[EB];
  __shared__ int ld[EB];
  __shared__ int lcnt[NB];
  __shared__ int lcur[NB];
  __shared__ int gbaseS[NB];
  int tid = threadIdx.x;
  size_t base = (size_t)blockIdx.x * EB;
  for (int t = tid; t < NB; t += 256) { lcnt[t] = 0; lcur[t] = 0; }
  __syncthreads();
#pragma unroll
  for (int l = 0; l < EB / 256; l++) {
    int li = l * 256 + tid;
    size_t idx = base + li;
    int s = 0, d = -1;
    if (idx < N_EDGES) {
      s = ei[idx];
      d = ei[N_EDGES + idx];
      atomicAdd(&lcnt[d >> 7], 1);
    }
    ls[li] = s;
    ld[li] = d;
  }
  __syncthreads();
  for (int t = tid; t < NB; t += 256) gbaseS[t] = atomicAdd(&gcnt[t], lcnt[t]);
  __syncthreads();
#pragma unroll
  for (int l = 0; l < EB / 256; l++) {
    int li = l * 256 + tid;
    int d = ld[li];
    if (d >= 0) {
      int b = d >> 7;
      int r = gbaseS[b] + atomicAdd(&lcur[b], 1);
      if (r >= CAP) r = CAP - 1;   // overflow guard (statistically impossible)
      gbucket[(size_t)b * CAP + r] = make_int2(ls[li], d);
    }
  }
}

__global__ __launch_bounds__(512) void bucketscan_kernel(const int* __restrict__ gcnt,
                                                         int* __restrict__ bbase,
                                                         int* __restrict__ row_ptr) {
  __shared__ int lds[512];
  int tid = threadIdx.x;
  int v = (tid < NB) ? gcnt[tid] : 0;
  lds[tid] = v;
  __syncthreads();
  for (int off = 1; off < 512; off <<= 1) {
    int t = (tid >= off) ? lds[tid - off] : 0;
    __syncthreads();
    lds[tid] += t;
    __syncthreads();
  }
  if (tid < NB) bbase[tid] = lds[tid] - v;
  if (tid == 0) row_ptr[N_NODES] = N_EDGES;
}

__global__ __launch_bounds__(256) void csr_kernel(const int2* __restrict__ gbucket,
                                                  const int* __restrict__ gcnt,
                                                  const int* __restrict__ bbase,
                                                  int* __restrict__ row_ptr,
                                                  int* __restrict__ col) {
  __shared__ int2 ent[CAP];
  __shared__ int hcnt[128];
  __shared__ int sc[128];
  __shared__ int cur[128];
  int b = blockIdx.x;
  int tid = threadIdx.x;
  int cnt = gcnt[b]; if (cnt > CAP) cnt = CAP;
  int base = bbase[b];
  if (tid < 128) hcnt[tid] = 0;
  __syncthreads();
  for (int i = tid; i < cnt; i += 256) {
    int2 e = gbucket[(size_t)b * CAP + i];
    ent[i] = e;
    atomicAdd(&hcnt[e.y & 127], 1);
  }
  __syncthreads();
  if (tid < 128) sc[tid] = hcnt[tid];
  __syncthreads();
  for (int off = 1; off < 128; off <<= 1) {
    int t = 0;
    if (tid < 128 && tid >= off) t = sc[tid - off];
    __syncthreads();
    if (tid < 128) sc[tid] += t;
    __syncthreads();
  }
  if (tid < 128) {
    int excl = sc[tid] - hcnt[tid];
    cur[tid] = excl;
    int node = (b << 7) + tid;
    if (node < N_NODES) row_ptr[node] = base + excl;
  }
  __syncthreads();
  for (int i = tid; i < cnt; i += 256) {
    int2 e = ent[i];
    int r = atomicAdd(&cur[e.y & 127], 1);
    col[base + r] = e.x;
  }
}

// ---------------- W1 -> MFMA B-fragment packing (hi/lo split) ----------------
__global__ __launch_bounds__(256) void w1pack_kernel(const float* __restrict__ W1,
                                                     unsigned short* __restrict__ wHi,
                                                     unsigned short* __restrict__ wLo) {
  int tid = blockIdx.x * 256 + threadIdx.x;   // 0..4095
  int kk = tid >> 9;
  int rest = tid & 511;
  int t = rest >> 6;
  int lane = rest & 63;
  int q = lane >> 4;
  int ln = lane & 15;
  int n = t * 16 + ln;
  unsigned int hi[4], lo[4];
#pragma unroll
  for (int jj = 0; jj < 4; jj++) {
    unsigned short h0, h1, l0, l1;
    {
      float v = W1[(kk * 32 + q * 8 + jj * 2) * F1 + n];
      h0 = f2bf(v); l0 = f2bf(v - bf2f(h0));
    }
    {
      float v = W1[(kk * 32 + q * 8 + jj * 2 + 1) * F1 + n];
      h1 = f2bf(v); l1 = f2bf(v - bf2f(h1));
    }
    hi[jj] = (unsigned int)h0 | ((unsigned int)h1 << 16);
    lo[jj] = (unsigned int)l0 | ((unsigned int)l1 << 16);
  }
  size_t base = (size_t)tid * 8;
  *(uint4*)&wHi[base] = make_uint4(hi[0], hi[1], hi[2], hi[3]);
  *(uint4*)&wLo[base] = make_uint4(lo[0], lo[1], lo[2], lo[3]);
}

// ---------------- GEMM1 via bf16 MFMA (split precision) + fused alpha1 ----------------
__global__ __launch_bounds__(256) void gemm1_mfma_kernel(
    const float* __restrict__ x, const unsigned short* __restrict__ wHi,
    const unsigned short* __restrict__ wLo,
    const float* __restrict__ a_src, const float* __restrict__ a_dst,
    unsigned short* __restrict__ h1b, float* __restrict__ as1, float* __restrict__ ad1) {
  int tid = threadIdx.x;
  int w = tid >> 6;
  int lane = tid & 63;
  int q = lane >> 4;
  int ln = lane & 15;
  int rowBase = blockIdx.x * 64 + w * 16;
  int rowA = rowBase + ln;
  int rowAc = rowA < N_NODES ? rowA : N_NODES - 1;
  float4v acc[8];
#pragma unroll
  for (int t = 0; t < 8; t++) acc[t] = (float4v){0.f, 0.f, 0.f, 0.f};
  const short8* bhp = (const short8*)wHi;
  const short8* blp = (const short8*)wLo;
  for (int kk = 0; kk < 8; kk++) {
    const float4* xp = (const float4*)(x + (size_t)rowAc * IN_DIM + kk * 32 + q * 8);
    float4 a0 = xp[0];
    float4 a1 = xp[1];
    float av[8] = {a0.x, a0.y, a0.z, a0.w, a1.x, a1.y, a1.z, a1.w};
    short8 ahi, alo;
#pragma unroll
    for (int j = 0; j < 8; j++) {
      unsigned short h = f2bf(av[j]);
      ahi[j] = (short)h;
      alo[j] = (short)f2bf(av[j] - bf2f(h));
    }
    int fbase = (kk * 8) * 64 + lane;
#pragma unroll
    for (int t = 0; t < 8; t++) {
      short8 bh = bhp[fbase + t * 64];
      short8 bl = blp[fbase + t * 64];
      acc[t] = __builtin_amdgcn_mfma_f32_16x16x32_bf16(ahi, bh, acc[t], 0, 0, 0);
      acc[t] = __builtin_amdgcn_mfma_f32_16x16x32_bf16(ahi, bl, acc[t], 0, 0, 0);
      acc[t] = __builtin_amdgcn_mfma_f32_16x16x32_bf16(alo, bh, acc[t], 0, 0, 0);
    }
  }
  float asv[8], adv[8];
#pragma unroll
  for (int t = 0; t < 8; t++) {
    asv[t] = a_src[t * 16 + ln];
    adv[t] = a_dst[t * 16 + ln];
  }
#pragma unroll
  for (int reg = 0; reg < 4; reg++) {
    int r = rowBase + q * 4 + reg;
    bool valid = (r < N_NODES);
    if (valid) {
#pragma unroll
      for (int t = 0; t < 8; t++)
        h1b[(size_t)r * F1 + t * 16 + ln] = f2bf(acc[t][reg]);
    }
#pragma unroll
    for (int h = 0; h < 4; h++) {
      float sa = acc[2 * h][reg] * asv[2 * h] + acc[2 * h + 1][reg] * asv[2 * h + 1];
      float sd = acc[2 * h][reg] * adv[2 * h] + acc[2 * h + 1][reg] * adv[2 * h + 1];
#pragma unroll
      for (int off = 1; off < 16; off <<= 1) {
        sa += __shfl_xor(sa, off);
        sd += __shfl_xor(sd, off);
      }
      if (ln == 0 && valid) {
        as1[r * 4 + h] = sa;
        ad1[r * 4 + h] = sd;
      }
    }
  }
}

// ---------------- layer-1: wave-per-node gather, LDS-cached weights ----------------
// phase A computes exp-sums AND stashes (src, exp x4) per edge in wave-private LDS;
// phase B (4 slots x 16 lanes) reads weights from LDS -- only h1b gather hits global.
__global__ __launch_bounds__(256) void gather1_kernel(
    const unsigned short* __restrict__ h1b, const float* __restrict__ as1,
    const float* __restrict__ ad1, const float* __restrict__ b1,
    const int* __restrict__ row_ptr, const int* __restrict__ col,
    float* __restrict__ x2) {
  __shared__ float4 wsh[4][DCAP];
  __shared__ int ssh[4][DCAP];
  int wv = threadIdx.x >> 6;
  int n = blockIdx.x * 4 + wv;
  if (n >= N_NODES) return;
  int lane = threadIdx.x & 63;
  int start = row_ptr[n];
  int deg = row_ptr[n + 1] - start;
  bool fast = (deg + 1) <= DCAP;
  float4 ad = *(const float4*)&ad1[n * 4];
  // phase A: per-head exp sums + LDS stash (no max subtraction; e bounded ~[-1,4])
  float s0 = 0.f, s1 = 0.f, s2 = 0.f, s3 = 0.f;
  for (int i = lane; i <= deg; i += 64) {
    int src = (i < deg) ? col[start + i] : n;
    float4 as = *(const float4*)&as1[src * 4];
    float e0 = __expf(lrelu(as.x + ad.x));
    float e1 = __expf(lrelu(as.y + ad.y));
    float e2 = __expf(lrelu(as.z + ad.z));
    float e3 = __expf(lrelu(as.w + ad.w));
    s0 += e0; s1 += e1; s2 += e2; s3 += e3;
    if (fast) {
      ssh[wv][i] = src;
      wsh[wv][i] = make_float4(e0, e1, e2, e3);
    }
  }
#pragma unroll
  for (int off = 32; off > 0; off >>= 1) {
    s0 += __shfl_xor(s0, off);
    s1 += __shfl_xor(s1, off);
    s2 += __shfl_xor(s2, off);
    s3 += __shfl_xor(s3, off);
  }
  int slot = lane >> 4;
  int lane16 = lane & 15;
  int head = lane16 >> 2;
  float rsh = (head == 0) ? s0 : (head == 1) ? s1 : (head == 2) ? s2 : s3;
  rsh = 1.f / (rsh + 1e-16f);
  float4 accA = make_float4(0.f, 0.f, 0.f, 0.f);
  float4 accB = make_float4(0.f, 0.f, 0.f, 0.f);
  if (fast) {
    const float* wp = (const float*)&wsh[wv][0];
    int i = slot;
    for (; i + 4 <= deg; i += 8) {   // unroll 2: two independent row loads in flight
      int sA = ssh[wv][i];
      int sB = ssh[wv][i + 4];
      float wA = wp[i * 4 + head] * rsh;
      float wB = wp[(i + 4) * 4 + head] * rsh;
      uint4 uA = *(const uint4*)(h1b + (size_t)sA * F1 + lane16 * 8);
      uint4 uB = *(const uint4*)(h1b + (size_t)sB * F1 + lane16 * 8);
      accA.x += wA * bflo(uA.x); accA.y += wA * bfhi(uA.x);
      accA.z += wA * bflo(uA.y); accA.w += wA * bfhi(uA.y);
      accB.x += wA * bflo(uA.z); accB.y += wA * bfhi(uA.z);
      accB.z += wA * bflo(uA.w); accB.w += wA * bfhi(uA.w);
      accA.x += wB * bflo(uB.x); accA.y += wB * bfhi(uB.x);
      accA.z += wB * bflo(uB.y); accA.w += wB * bfhi(uB.y);
      accB.x += wB * bflo(uB.z); accB.y += wB * bfhi(uB.z);
      accB.z += wB * bflo(uB.w); accB.w += wB * bfhi(uB.w);
    }
    if (i <= deg) {
      int s = ssh[wv][i];
      float w = wp[i * 4 + head] * rsh;
      uint4 u = *(const uint4*)(h1b + (size_t)s * F1 + lane16 * 8);
      accA.x += w * bflo(u.x); accA.y += w * bfhi(u.x);
      accA.z += w * bflo(u.y); accA.w += w * bfhi(u.y);
      accB.x += w * bflo(u.z); accB.y += w * bfhi(u.z);
      accB.z += w * bflo(u.w); accB.w += w * bfhi(u.w);
    }
  } else {
    float adh = (head == 0) ? ad.x : (head == 1) ? ad.y : (head == 2) ? ad.z : ad.w;
    for (int i = slot; i <= deg; i += 4) {
      int src = (i < deg) ? col[start + i] : n;
      float w = __expf(lrelu(as1[src * 4 + head] + adh)) * rsh;
      uint4 u = *(const uint4*)(h1b + (size_t)src * F1 + lane16 * 8);
      accA.x += w * bflo(u.x); accA.y += w * bfhi(u.x);
      accA.z += w * bflo(u.y); accA.w += w * bfhi(u.y);
      accB.x += w * bflo(u.z); accB.y += w * bfhi(u.z);
      accB.z += w * bflo(u.w); accB.w += w * bfhi(u.w);
    }
  }
  // cross-slot reduce: slot bits are lane bits 4,5 (clean xor butterfly)
#pragma unroll
  for (int off = 16; off <= 32; off <<= 1) {
    accA.x += __shfl_xor(accA.x, off); accA.y += __shfl_xor(accA.y, off);
    accA.z += __shfl_xor(accA.z, off); accA.w += __shfl_xor(accA.w, off);
    accB.x += __shfl_xor(accB.x, off); accB.y += __shfl_xor(accB.y, off);
    accB.z += __shfl_xor(accB.z, off); accB.w += __shfl_xor(accB.w, off);
  }
  if (slot == 0) {
    float4 bA = *(const float4*)&b1[lane16 * 8];
    float4 bB = *(const float4*)&b1[lane16 * 8 + 4];
    float4 oA, oB;
    oA.x = fmaxf(accA.x + bA.x, 0.f); oA.y = fmaxf(accA.y + bA.y, 0.f);
    oA.z = fmaxf(accA.z + bA.z, 0.f); oA.w = fmaxf(accA.w + bA.w, 0.f);
    oB.x = fmaxf(accB.x + bB.x, 0.f); oB.y = fmaxf(accB.y + bB.y, 0.f);
    oB.z = fmaxf(accB.z + bB.z, 0.f); oB.w = fmaxf(accB.w + bB.w, 0.f);
    *(float4*)&x2[(size_t)n * F1 + lane16 * 8] = oA;
    *(float4*)&x2[(size_t)n * F1 + lane16 * 8 + 4] = oB;
  }
}

// ---------------- GEMM2 tiled + alpha2 fused: h2b = x2@W2 (bf16), as2/ad2 ----------------
__global__ __launch_bounds__(256) void gemm2_kernel(
    const float* __restrict__ x2, const float* __restrict__ W2,
    const float* __restrict__ asv, const float* __restrict__ adv,
    unsigned short* __restrict__ h2b, float* __restrict__ as2, float* __restrict__ ad2) {
  __shared__ float xs[64][132];
  __shared__ float W2s[128][44];
  __shared__ float asv_s[40], adv_s[40];
  int tid = threadIdx.x;
  int bm = blockIdx.x * 64;
#pragma unroll
  for (int l = 0; l < 8; l++) {
    int idx = tid + l * 256;
    int r = idx >> 5;
    int c4 = (idx & 31) << 2;
    float4 v = make_float4(0.f, 0.f, 0.f, 0.f);
    if (bm + r < N_NODES) v = *(const float4*)&x2[(size_t)(bm + r) * F1 + c4];
    *(float4*)&xs[r][c4] = v;
  }
#pragma unroll
  for (int l = 0; l < 5; l++) {
    int idx = tid + l * 256;
    int k = idx / 10;
    int c4 = (idx - k * 10) * 4;
    *(float4*)&W2s[k][c4] = *(const float4*)&W2[k * OUT_DIM + c4];
  }
  if (tid < OUT_DIM) { asv_s[tid] = asv[tid]; adv_s[tid] = adv[tid]; }
  __syncthreads();
  int r = tid >> 2;
  int cb = (tid & 3) * 10;
  float acc[10] = {0.f};
  for (int k = 0; k < F1; k++) {
    float xv = xs[r][k];
#pragma unroll
    for (int c = 0; c < 10; c++) acc[c] += xv * W2s[k][cb + c];
  }
  int grow = bm + r;
  float sa = 0.f, sd = 0.f;
#pragma unroll
  for (int c = 0; c < 10; c++) {
    sa += acc[c] * asv_s[cb + c];
    sd += acc[c] * adv_s[cb + c];
  }
#pragma unroll
  for (int off = 1; off < 4; off <<= 1) {
    sa += __shfl_xor(sa, off);
    sd += __shfl_xor(sd, off);
  }
  if (grow < N_NODES) {
#pragma unroll
    for (int c = 0; c < 10; c += 2) {
      unsigned int p = ((unsigned int)f2bf(acc[c + 1]) << 16) | f2bf(acc[c]);
      *(unsigned int*)&h2b[(size_t)grow * OUT_DIM + cb + c] = p;
    }
    if ((tid & 3) == 0) { as2[grow] = sa; ad2[grow] = sd; }
  }
}

// ---------------- layer-2: wave-per-node gather + log_softmax, LDS-cached weights ----------------
__global__ __launch_bounds__(256) void gather2_kernel(
    const unsigned short* __restrict__ h2b, const float* __restrict__ as2,
    const float* __restrict__ ad2, const float* __restrict__ b2,
    const int* __restrict__ row_ptr, const int* __restrict__ col,
    float* __restrict__ out) {
  __shared__ float w2sh[4][DCAP];
  __shared__ int s2sh[4][DCAP];
  int wv = threadIdx.x >> 6;
  int n = blockIdx.x * 4 + wv;
  if (n >= N_NODES) return;
  int lane = threadIdx.x & 63;
  int start = row_ptr[n];
  int deg = row_ptr[n + 1] - start;
  bool fast = (deg + 1) <= DCAP;
  float adh = ad2[n];
  // phase A: exp sum + stash
  float part = 0.f;
  for (int i = lane; i <= deg; i += 64) {
    int src = (i < deg) ? col[start + i] : n;
    float e = __expf(lrelu(as2[src] + adh));
    part += e;
    if (fast) { s2sh[wv][i] = src; w2sh[wv][i] = e; }
  }
#pragma unroll
  for (int off = 32; off > 0; off >>= 1) part += __shfl_xor(part, off);
  float rs = 1.f / (part + 1e-16f);
  // phase B: 12 slots x 5 lanes (16B bf16x8, row=80B); lanes 60..63 idle
  int slot = lane / 5;
  int c = lane - slot * 5;
  float4 accA = make_float4(0.f, 0.f, 0.f, 0.f);
  float4 accB = make_float4(0.f, 0.f, 0.f, 0.f);
  if (slot < 12) {
    if (fast) {
      for (int i = slot; i <= deg; i += 12) {
        int src = s2sh[wv][i];
        float wgt = w2sh[wv][i] * rs;
        uint4 u = *(const uint4*)(h2b + (size_t)src * OUT_DIM + c * 8);
        accA.x += wgt * bflo(u.x); accA.y += wgt * bfhi(u.x);
        accA.z += wgt * bflo(u.y); accA.w += wgt * bfhi(u.y);
        accB.x += wgt * bflo(u.z); accB.y += wgt * bfhi(u.z);
        accB.z += wgt * bflo(u.w); accB.w += wgt * bfhi(u.w);
      }
    } else {
      for (int i = slot; i <= deg; i += 12) {
        int src = (i < deg) ? col[start + i] : n;
        float wgt = __expf(lrelu(as2[src] + adh)) * rs;
        uint4 u = *(const uint4*)(h2b + (size_t)src * OUT_DIM + c * 8);
        accA.x += wgt * bflo(u.x); accA.y += wgt * bfhi(u.x);
        accA.z += wgt * bflo(u.y); accA.w += wgt * bfhi(u.y);
        accB.x += wgt * bflo(u.z); accB.y += wgt * bfhi(u.z);
        accB.z += wgt * bflo(u.w); accB.w += wgt * bfhi(u.w);
      }
    }
  }
  // cross-slot reduce (12 slots); temps read before update (R7 bugfix)
  {
    float v[8] = {accA.x, accA.y, accA.z, accA.w, accB.x, accB.y, accB.z, accB.w};
#pragma unroll
    for (int k = 0; k < 8; k++) v[k] += __shfl(v[k], lane + 30);
#pragma unroll
    for (int k = 0; k < 8; k++) v[k] += __shfl(v[k], lane + 15);
    float t1[8], t2[8];
#pragma unroll
    for (int k = 0; k < 8; k++) t1[k] = __shfl(v[k], lane + 5);
#pragma unroll
    for (int k = 0; k < 8; k++) t2[k] = __shfl(v[k], lane + 10);
#pragma unroll
    for (int k = 0; k < 8; k++) v[k] += t1[k] + t2[k];
    accA.x = v[0]; accA.y = v[1]; accA.z = v[2]; accA.w = v[3];
    accB.x = v[4]; accB.y = v[5]; accB.z = v[6]; accB.w = v[7];
  }
  bool owner = (slot == 0);
  float vals[8] = {accA.x, accA.y, accA.z, accA.w, accB.x, accB.y, accB.z, accB.w};
  float lmax = -1e30f, lsum = 0.f;
  if (owner) {
#pragma unroll
    for (int k = 0; k < 8; k++) {
      vals[k] += b2[c * 8 + k];
      lmax = fmaxf(lmax, vals[k]);
    }
  }
  float gmax = lmax;
#pragma unroll
  for (int off = 32; off > 0; off >>= 1) gmax = fmaxf(gmax, __shfl_xor(gmax, off));
  if (owner) {
#pragma unroll
    for (int k = 0; k < 8; k++) lsum += __expf(vals[k] - gmax);
  }
#pragma unroll
  for (int off = 32; off > 0; off >>= 1) lsum += __shfl_xor(lsum, off);
  if (owner) {
    float lse = gmax + __logf(lsum);
    float4 oA = make_float4(vals[0] - lse, vals[1] - lse, vals[2] - lse, vals[3] - lse);
    float4 oB = make_float4(vals[4] - lse, vals[5] - lse, vals[6] - lse, vals[7] - lse);
    *(float4*)&out[(size_t)n * OUT_DIM + c * 8] = oA;
    *(float4*)&out[(size_t)n * OUT_DIM + c * 8 + 4] = oB;
  }
}

extern "C" void kernel_launch(void* const* d_in, const int* in_sizes, int n_in,
                              void* d_out, int out_size, void* d_ws, size_t ws_size,
                              hipStream_t stream) {
  const float* x      = (const float*)d_in[0];
  const int*   ei     = (const int*)d_in[1];
  const float* W1     = (const float*)d_in[2];
  const float* a_src1 = (const float*)d_in[3];
  const float* a_dst1 = (const float*)d_in[4];
  const float* b1     = (const float*)d_in[5];
  const float* W2     = (const float*)d_in[6];
  const float* a_src2 = (const float*)d_in[7];
  const float* a_dst2 = (const float*)d_in[8];
  const float* b2     = (const float*)d_in[9];
  float* out = (float*)d_out;

  char* ws = (char*)d_ws;
  size_t off = 0;
  auto alloc = [&](size_t bytes) -> void* {
    void* p = ws + off;
    off += (bytes + 255) & ~(size_t)255;
    return p;
  };
  unsigned short* h1b = (unsigned short*)alloc((size_t)N_NODES * F1 * 2);       // 12.8 MB
  unsigned short* h2b = (unsigned short*)alloc((size_t)N_NODES * OUT_DIM * 2);  // 4 MB
  unsigned short* wHi = (unsigned short*)alloc((size_t)IN_DIM * F1 * 2);        // 64 KB
  unsigned short* wLo = (unsigned short*)alloc((size_t)IN_DIM * F1 * 2);        // 64 KB
  float* as1    = (float*)alloc((size_t)N_NODES * HEADS * 4);
  float* ad1    = (float*)alloc((size_t)N_NODES * HEADS * 4);
  float* x2     = (float*)alloc((size_t)N_NODES * F1 * 4);
  float* as2    = (float*)alloc((size_t)N_NODES * 4);
  float* ad2    = (float*)alloc((size_t)N_NODES * 4);
  int* row_ptr  = (int*)alloc((size_t)(N_NODES + 1) * 4);
  int* col      = (int*)alloc((size_t)N_EDGES * 4);
  int* gcnt     = (int*)alloc((size_t)NB * 4);
  int* bbase    = (int*)alloc((size_t)NB * 4);
  int2* gbucket = (int2*)alloc((size_t)NB * CAP * 8);                           // 9.6 MB

  hipMemsetAsync(gcnt, 0, (size_t)NB * 4, stream);
  bin_kernel<<<(N_EDGES + EB - 1) / EB, 256, 0, stream>>>(ei, gcnt, gbucket);
  bucketscan_kernel<<<1, 512, 0, stream>>>(gcnt, bbase, row_ptr);
  csr_kernel<<<NB, 256, 0, stream>>>(gbucket, gcnt, bbase, row_ptr, col);

  w1pack_kernel<<<16, 256, 0, stream>>>(W1, wHi, wLo);
  gemm1_mfma_kernel<<<(N_NODES + 63) / 64, 256, 0, stream>>>(
      x, wHi, wLo, a_src1, a_dst1, h1b, as1, ad1);
  gather1_kernel<<<(N_NODES + 3) / 4, 256, 0, stream>>>(h1b, as1, ad1, b1, row_ptr, col, x2);

  gemm2_kernel<<<(N_NODES + 63) / 64, 256, 0, stream>>>(x2, W2, a_src2, a_dst2, h2b, as2, ad2);
  gather2_kernel<<<(N_NODES + 3) / 4, 256, 0, stream>>>(h2b, as2, ad2, b2, row_ptr, col, out);
}